// Round 6
// baseline (311.473 us; speedup 1.0000x reference)
//
#include <hip/hip_runtime.h>
#include <hip/hip_bf16.h>

// PairwiseAttention: z(1,256,256,128) -> LN -> QKV -> 4-head attn (over 2nd L axis)
// -> proj + residual.  Runtime dtype sniff (fp32 vs bf16).
//
// Round N+5: hoist token-side preprocessing (the round-5 counters showed attn
// is HBM-concurrency-bound: 104MB @ 620GB/s = its whole 166us, with z read 2x
// by each of 4 head-blocks and ~1K VALU ops/thread of LN+splitf between loads):
//   prep_z    : NEW. LN (bit-identical loop) + hi/lo split ONCE per token,
//               written as pre-swizzled per-(r,kc) LDS images in ws.
//   attn_mfma4: staging of zn AND w' is now pure linear uint4 copies
//               (LDS bytes provably byte-identical to round 5 -> flash/MFMA
//               untouched -> absmax bit-identical).
//   proj_mfma2: 512 -> 1024 blocks (64 tokens each) for more MLP.
// Fallback to round-1 attn_mfma + proj_res when ws is too small.

using ush = unsigned short;

__device__ __forceinline__ float bflo(unsigned int u) { return __uint_as_float(u << 16); }
__device__ __forceinline__ float bfhi(unsigned int u) { return __uint_as_float(u & 0xffff0000u); }
__device__ __forceinline__ float bf2f(unsigned short u) { return __uint_as_float(((unsigned int)u) << 16); }
__device__ __forceinline__ unsigned short f2bf(float f) {
    unsigned int i = __float_as_uint(f);
    i += 0x7fffu + ((i >> 16) & 1u);           // round-to-nearest-even
    return (unsigned short)(i >> 16);
}
__device__ __forceinline__ void splitf(float x, unsigned short& h, unsigned short& l) {
    h = f2bf(x);
    l = f2bf(x - bf2f(h));
}

__device__ bool sniff_is_f32(const unsigned int* z) {
    int n = 0;
    for (int i = 0; i < 64; ++i) {
        float a = fabsf(bflo(z[i]));
        n += (int)(a > 1e4f) | (int)(a > 0.f && a < 1e-6f);
    }
    return n > 16;
}

template<bool F32> __device__ __forceinline__ float ldel(const void* p, int i) {
    if constexpr (F32) return ((const float*)p)[i];
    else               return bf2f(((const unsigned short*)p)[i]);
}
template<bool F32> __device__ __forceinline__ void ld8(const void* p, int i8, float* v) {
    if constexpr (F32) {
        const float4* q = (const float4*)p;
        float4 a = q[2 * i8], b = q[2 * i8 + 1];
        v[0]=a.x; v[1]=a.y; v[2]=a.z; v[3]=a.w; v[4]=b.x; v[5]=b.y; v[6]=b.z; v[7]=b.w;
    } else {
        uint4 u = ((const uint4*)p)[i8];
        const unsigned int* pu = (const unsigned int*)&u;
        #pragma unroll
        for (int j = 0; j < 4; ++j) { v[2*j] = bflo(pu[j]); v[2*j+1] = bfhi(pu[j]); }
    }
}
template<bool F32> __device__ __forceinline__ void st8(void* p, int i8, const float* v) {
    if constexpr (F32) {
        float4 a, b;
        a.x=v[0]; a.y=v[1]; a.z=v[2]; a.w=v[3];
        b.x=v[4]; b.y=v[5]; b.z=v[6]; b.w=v[7];
        ((float4*)p)[2 * i8] = a; ((float4*)p)[2 * i8 + 1] = b;
    } else {
        uint4 u; unsigned int* pu = (unsigned int*)&u;
        #pragma unroll
        for (int j = 0; j < 4; ++j)
            pu[j] = (unsigned int)f2bf(v[2*j]) | ((unsigned int)f2bf(v[2*j+1]) << 16);
        ((uint4*)p)[i8] = u;
    }
}
template<bool F32> __device__ __forceinline__ const void* elptr(const void* p, size_t off) {
    if constexpr (F32) return (const void*)((const float*)p + off);
    else               return (const void*)((const unsigned short*)p + off);
}
template<bool F32> __device__ __forceinline__ void* elptrw(void* p, size_t off) {
    if constexpr (F32) return (void*)((float*)p + off);
    else               return (void*)((unsigned short*)p + off);
}

// ---------------- MFMA plumbing ----------------
using bf16x8 = __attribute__((ext_vector_type(8))) short;   // 8 bf16 bits, 4 VGPR
using f32x4  = __attribute__((ext_vector_type(4))) float;

__device__ __forceinline__ f32x4 mfma16(bf16x8 a, bf16x8 b, f32x4 c) {
    return __builtin_amdgcn_mfma_f32_16x16x32_bf16(a, b, c, 0, 0, 0);
}

// [R][32]-bf16 LDS matrices with XOR-granule swizzle (verified round-1):
// sw_frag(row,g)+e == sw_off(row, 8*g+e)  (slot consistency across A and B).
__device__ __forceinline__ int sw_off (int row, int k) {
    return row * 32 + ((((k >> 3) ^ (row >> 1)) & 3) << 3) + (k & 7);
}
__device__ __forceinline__ int sw_frag(int row, int g) {
    return row * 32 + (((g ^ (row >> 1)) & 3) << 3);
}
// Vt: [32 dims][256 keys] bf16, XOR key-granule by (dim&7).
__device__ __forceinline__ int vt_off(int dim, int key) {
    return dim * 256 + (key ^ ((dim & 7) << 3));
}

// ws layout (bytes):
//   wqSH 0        (98304)    swizzled w' hi images: [(h*4+kc)*3072 + sw_off(c,kl)]
//   wqSL 98304    (98304)
//   wpH  196608   (32768)    w_proj^T hi: [c*128+k]
//   wpL  229376   (32768)
//   biasG 262144  (1536)     float[4][96]
//   znSH 266240   (16777216) swizzled zn hi images: [(r*4+kc)*8192 + sw_off(t,kl)]
//   znSL 17043456 (16777216)
#define WS_NEED 33820672ull

// ---------------- prep_w: weight preprocessing, once (grid 64 x 256) ----------------
template<bool F32>
__global__ __launch_bounds__(256) void prep_w(
    const void* __restrict__ z, const void* __restrict__ ln_g, const void* __restrict__ ln_b,
    const void* __restrict__ w_qkv, const void* __restrict__ b_qkv, const void* __restrict__ w_proj,
    ush* __restrict__ wqSH, ush* __restrict__ wqSL,
    ush* __restrict__ wpH, ush* __restrict__ wpL, float* __restrict__ biasG)
{
    if (sniff_is_f32((const unsigned int*)z) != F32) return;
    const int gid = blockIdx.x * 256 + threadIdx.x;
    const int NT  = 64 * 256;

    // swizzled g.*W_qkv images: e = (h*4+kc)*3072 + c*32 + kl
    for (int e = gid; e < 49152; e += NT) {
        int kl = e & 31;
        int c  = (e >> 5) % 96;
        int hk = e / 3072;            // h*4+kc
        int h  = hk >> 2, kc = hk & 3;
        int k  = kc * 32 + kl;
        int gc = ((c >> 5) << 7) + (h << 5) + (c & 31);
        float wv = ldel<F32>(ln_g, k) * ldel<F32>(w_qkv, k * 384 + gc);
        ush hh, ll; splitf(wv, hh, ll);
        int o = hk * 3072 + sw_off(c, kl);
        wqSH[o] = hh; wqSL[o] = ll;
    }
    // w_proj transposed hi/lo: wp[c*128+k] = w_proj[k][c]
    for (int e = gid; e < 16384; e += NT) {
        int c = e >> 7, k = e & 127;
        float v = ldel<F32>(w_proj, k * 128 + c);
        ush hh, ll; splitf(v, hh, ll);
        wpH[e] = hh; wpL[e] = ll;
    }
    // bias_c = b_qkv[gc] + sum_k ln_b[k] * W[k][gc]   (exact round-1 loop, once per head)
    if (blockIdx.x < 4 && threadIdx.x < 96) {
        int h = blockIdx.x, c = threadIdx.x;
        int gc = ((c >> 5) << 7) + (h << 5) + (c & 31);
        float b0 = 0.f, b1 = 0.f;
        #pragma unroll 8
        for (int k = 0; k < 128; k += 2) {
            b0 += ldel<F32>(ln_b, k)     * ldel<F32>(w_qkv, k * 384 + gc);
            b1 += ldel<F32>(ln_b, k + 1) * ldel<F32>(w_qkv, (k + 1) * 384 + gc);
        }
        biasG[h * 96 + c] = ldel<F32>(b_qkv, gc) + b0 + b1;
    }
}

// ---------------- prep_z: LN + hi/lo split once per token (grid 256 x 256) ----------------
// Writes the pre-swizzled per-(r,kc) LDS images.  The stats loop, rsig/nb
// expressions, splitf, and sw_frag indices are verbatim round-5 attn code ->
// downstream bits identical.
template<bool F32>
__global__ __launch_bounds__(256) void prep_z(
    const void* __restrict__ z, ush* __restrict__ znSH, ush* __restrict__ znSL)
{
    if (sniff_is_f32((const unsigned int*)z) != F32) return;
    const int t = threadIdx.x;
    const int r = blockIdx.x;

    const void* zrow = elptr<F32>(z, ((size_t)r * 256 + t) << 7);
    float sum = 0.f, sumsq = 0.f;
    #pragma unroll 1
    for (int i = 0; i < 16; ++i) {
        float v[8]; ld8<F32>(zrow, i, v);
        #pragma unroll
        for (int j = 0; j < 8; ++j) { sum += v[j]; sumsq += v[j] * v[j]; }
    }
    const float mu   = sum * (1.f / 128.f);
    const float rsig = 1.0f / sqrtf(sumsq * (1.f / 128.f) - mu * mu + 1e-5f);
    const float nb   = -mu * rsig;

    #pragma unroll 1
    for (int kc = 0; kc < 4; ++kc) {
        #pragma unroll
        for (int i8 = 0; i8 < 4; ++i8) {
            float vv[8]; ld8<F32>(zrow, kc * 4 + i8, vv);
            union { ush s[8]; uint4 v4; } uh, ul;
            #pragma unroll
            for (int j = 0; j < 8; ++j) {
                float zh = fmaf(vv[j], rsig, nb);
                splitf(zh, uh.s[j], ul.s[j]);
            }
            const size_t base = ((size_t)(r * 4 + kc) << 13) + sw_frag(t, i8);
            *(uint4*)&znSH[base] = uh.v4;
            *(uint4*)&znSL[base] = ul.v4;
        }
    }
}

// ---------------- attn_mfma4: staging = pure linear copies; flash verbatim ----------------
// grid = 1024 (r*4+h), block = 256 (4 waves; wave w owns query rows w*64..w*64+63)
template<bool F32>
__global__ __launch_bounds__(256) void attn_mfma4(
    const void* __restrict__ z,
    const ush* __restrict__ znSH, const ush* __restrict__ znSL,
    const ush* __restrict__ wqSH, const ush* __restrict__ wqSL,
    const float* __restrict__ biasG, void* __restrict__ out)
{
    if (sniff_is_f32((const unsigned int*)z) != F32) return;

    __shared__ __align__(16) unsigned char smem[53248];
    ush* znH  = (ush*)smem;
    ush* znL  = (ush*)(smem + 16384);
    ush* wtH  = (ush*)(smem + 32768);
    ush* wtL  = (ush*)(smem + 38912);
    ush* kHs  = znH;
    ush* kLs  = znL;
    ush* vtH  = (ush*)(smem + 32768);

    const int t    = threadIdx.x;
    const int lane = t & 63;
    const int w    = t >> 6;
    const int g    = lane >> 4;
    const int c16  = lane & 15;
    const int r    = blockIdx.x >> 2;
    const int h    = blockIdx.x & 3;
    ush* ps = (ush*)(smem + 49152) + (w << 9);

    float bv[6];
    #pragma unroll
    for (int ct = 0; ct < 6; ++ct) bv[ct] = biasG[h * 96 + ct * 16 + c16];

    f32x4 acc[4][6];
    #pragma unroll
    for (int qt = 0; qt < 4; ++qt)
        #pragma unroll
        for (int ct = 0; ct < 6; ++ct)
            #pragma unroll
            for (int rr = 0; rr < 4; ++rr) acc[qt][ct][rr] = 0.f;

    #pragma unroll 1
    for (int kc = 0; kc < 4; ++kc) {
        {   // stage zn chunk: LINEAR copy of prepped swizzled image (byte-identical LDS)
            const uint4* srcH = (const uint4*)(znSH + ((size_t)(r * 4 + kc) << 13));
            const uint4* srcL = (const uint4*)(znSL + ((size_t)(r * 4 + kc) << 13));
            #pragma unroll
            for (int i = t; i < 1024; i += 256) {
                ((uint4*)znH)[i] = srcH[i];
                ((uint4*)znL)[i] = srcL[i];
            }
        }
        {   // stage w' chunk: LINEAR copy (round-5 verified)
            const uint4* srcH = (const uint4*)(wqSH + (h * 4 + kc) * 3072);
            const uint4* srcL = (const uint4*)(wqSL + (h * 4 + kc) * 3072);
            #pragma unroll
            for (int i = t; i < 768; i += 256) {
                if (i < 384) ((uint4*)wtH)[i]       = srcH[i];
                else         ((uint4*)wtL)[i - 384] = srcL[i - 384];
            }
        }
        __syncthreads();

        bf16x8 bH[6], bL[6];
        #pragma unroll
        for (int ct = 0; ct < 6; ++ct) {
            int brow = ct * 16 + c16;
            bH[ct] = *(const bf16x8*)&wtH[sw_frag(brow, g)];
            bL[ct] = *(const bf16x8*)&wtL[sw_frag(brow, g)];
        }
        #pragma unroll
        for (int qt = 0; qt < 4; ++qt) {
            int arow = (w << 6) + (qt << 4) + c16;
            bf16x8 aHf = *(const bf16x8*)&znH[sw_frag(arow, g)];
            bf16x8 aLf = *(const bf16x8*)&znL[sw_frag(arow, g)];
            #pragma unroll
            for (int ct = 0; ct < 6; ++ct) {
                acc[qt][ct] = mfma16(aHf, bH[ct], acc[qt][ct]);
                acc[qt][ct] = mfma16(aHf, bL[ct], acc[qt][ct]);
                acc[qt][ct] = mfma16(aLf, bH[ct], acc[qt][ct]);
            }
        }
        __syncthreads();
    }

    #pragma unroll
    for (int qt = 0; qt < 4; ++qt)
        #pragma unroll
        for (int ct = 0; ct < 6; ++ct)
            #pragma unroll
            for (int rr = 0; rr < 4; ++rr) acc[qt][ct][rr] += bv[ct];

    #pragma unroll
    for (int qt = 0; qt < 4; ++qt) {
        #pragma unroll
        for (int rr = 0; rr < 4; ++rr) {
            int key = (w << 6) + (qt << 4) + 4 * g + rr;
            ush hh, ll;
            splitf(acc[qt][2][rr], hh, ll);
            kHs[sw_off(key, c16)]      = hh; kLs[sw_off(key, c16)]      = ll;
            splitf(acc[qt][3][rr], hh, ll);
            kHs[sw_off(key, 16 + c16)] = hh; kLs[sw_off(key, 16 + c16)] = ll;
            vtH[vt_off(c16,      key)] = f2bf(acc[qt][4][rr]);
            vtH[vt_off(16 + c16, key)] = f2bf(acc[qt][5][rr]);
        }
    }

    const float SCALE = 0.17677669529663689f;
    bf16x8 qfH[4], qfL[4];
    #pragma unroll
    for (int qt = 0; qt < 4; ++qt) {
        #pragma unroll
        for (int rr = 0; rr < 4; ++rr) {
            int rw = 4 * g + rr;
            ps[sw_off(rw, c16)]      = f2bf(acc[qt][0][rr] * SCALE);
            ps[sw_off(rw, 16 + c16)] = f2bf(acc[qt][1][rr] * SCALE);
        }
        qfH[qt] = *(const bf16x8*)&ps[sw_frag(c16, g)];
        #pragma unroll
        for (int rr = 0; rr < 4; ++rr) {
            int rw = 4 * g + rr;
            float q0 = acc[qt][0][rr] * SCALE;
            float q1 = acc[qt][1][rr] * SCALE;
            ps[sw_off(rw, c16)]      = f2bf(q0 - bf2f(f2bf(q0)));
            ps[sw_off(rw, 16 + c16)] = f2bf(q1 - bf2f(f2bf(q1)));
        }
        qfL[qt] = *(const bf16x8*)&ps[sw_frag(c16, g)];
    }
    __syncthreads();

    float m[16], l[16];
    #pragma unroll
    for (int i = 0; i < 16; ++i) { m[i] = -3.0e38f; l[i] = 0.f; }
    f32x4 O[4][2];
    #pragma unroll
    for (int qt = 0; qt < 4; ++qt)
        #pragma unroll
        for (int dt = 0; dt < 2; ++dt)
            #pragma unroll
            for (int rr = 0; rr < 4; ++rr) O[qt][dt][rr] = 0.f;

    f32x4 zed; zed[0] = 0.f; zed[1] = 0.f; zed[2] = 0.f; zed[3] = 0.f;

    #pragma unroll 1
    for (int kb = 0; kb < 8; ++kb) {
        int key0 = kb * 32;
        bf16x8 kfH[2], kfL[2], vf[2];
        #pragma unroll
        for (int kt = 0; kt < 2; ++kt) {
            int krow = key0 + 16 * kt + c16;
            kfH[kt] = *(const bf16x8*)&kHs[sw_frag(krow, g)];
            kfL[kt] = *(const bf16x8*)&kLs[sw_frag(krow, g)];
        }
        #pragma unroll
        for (int dt = 0; dt < 2; ++dt)
            vf[dt] = *(const bf16x8*)&vtH[vt_off(16 * dt + c16, key0 + 8 * g)];

        #pragma unroll
        for (int qt = 0; qt < 4; ++qt) {
            f32x4 s0 = mfma16(qfH[qt], kfH[0], zed);
            s0 = mfma16(qfH[qt], kfL[0], s0);
            s0 = mfma16(qfL[qt], kfH[0], s0);
            f32x4 s1 = mfma16(qfH[qt], kfH[1], zed);
            s1 = mfma16(qfH[qt], kfL[1], s1);
            s1 = mfma16(qfL[qt], kfH[1], s1);

            #pragma unroll
            for (int rr = 0; rr < 4; ++rr) {
                float mx = fmaxf(s0[rr], s1[rr]);
                mx = fmaxf(mx, __shfl_xor(mx, 1));
                mx = fmaxf(mx, __shfl_xor(mx, 2));
                mx = fmaxf(mx, __shfl_xor(mx, 4));
                mx = fmaxf(mx, __shfl_xor(mx, 8));
                const int idx = qt * 4 + rr;
                float mo = m[idx];
                float mn = fmaxf(mo, mx);
                float al = __expf(fmaxf(mo - mn, -87.f));
                float p0 = __expf(s0[rr] - mn);
                float p1 = __expf(s1[rr] - mn);
                l[idx] = l[idx] * al + p0 + p1;
                m[idx] = mn;
                O[qt][0][rr] *= al;
                O[qt][1][rr] *= al;
                int rw = 4 * g + rr;
                ps[sw_off(rw, c16)]      = f2bf(p0);
                ps[sw_off(rw, 16 + c16)] = f2bf(p1);
            }
            bf16x8 pf = *(const bf16x8*)&ps[sw_frag(c16, g)];
            O[qt][0] = mfma16(pf, vf[0], O[qt][0]);
            O[qt][1] = mfma16(pf, vf[1], O[qt][1]);
        }
    }

    #pragma unroll
    for (int i = 0; i < 16; ++i) {
        float s = l[i];
        s += __shfl_xor(s, 1);
        s += __shfl_xor(s, 2);
        s += __shfl_xor(s, 4);
        s += __shfl_xor(s, 8);
        l[i] = s;
    }

    #pragma unroll
    for (int qt = 0; qt < 4; ++qt) {
        #pragma unroll
        for (int rr = 0; rr < 4; ++rr) {
            float rlv = 1.f / l[qt * 4 + rr];
            int grow = (r << 8) + (w << 6) + (qt << 4) + 4 * g + rr;
            size_t base = ((size_t)grow << 7) + (h << 5);
            if constexpr (F32) {
                float* po = (float*)out + base;
                po[c16]      = O[qt][0][rr] * rlv;
                po[16 + c16] = O[qt][1][rr] * rlv;
            } else {
                ush* po = (ush*)out + base;
                po[c16]      = f2bf(O[qt][0][rr] * rlv);
                po[16 + c16] = f2bf(O[qt][1][rr] * rlv);
            }
        }
    }
}

// ---------------- proj_mfma2: out = z + out @ w_proj + b_proj (in-place MFMA) ----------------
// grid 1024 (64 tokens each), block 256 (4 waves x 16 tokens, per-wave disjoint).
template<bool F32>
__global__ __launch_bounds__(256) void proj_mfma2(
    const void* __restrict__ z, const void* __restrict__ b_proj,
    const ush* __restrict__ wpH, const ush* __restrict__ wpL,
    void* __restrict__ out)
{
    if (sniff_is_f32((const unsigned int*)z) != F32) return;

    const int t    = threadIdx.x;
    const int lane = t & 63;
    const int w    = t >> 6;
    const int g    = lane >> 4;
    const int c16  = lane & 15;
    const int tok0 = blockIdx.x * 64 + w * 16;

    f32x4 acc[8];
    #pragma unroll
    for (int at = 0; at < 8; ++at)
        #pragma unroll
        for (int rr = 0; rr < 4; ++rr) acc[at][rr] = 0.f;

    #pragma unroll 1
    for (int kc = 0; kc < 4; ++kc) {
        const int token = tok0 + c16;
        float av[8];
        ld8<F32>(elptr<F32>((const void*)out, (size_t)token * 128 + kc * 32 + 8 * g), 0, av);
        union { ush s[8]; bf16x8 v; } hU, lU;
        #pragma unroll
        for (int j = 0; j < 8; ++j) splitf(av[j], hU.s[j], lU.s[j]);
        const bf16x8 btH = hU.v;
        const bf16x8 btL = lU.v;

        #pragma unroll
        for (int at = 0; at < 8; ++at) {
            const size_t wrow = (size_t)(at * 16 + c16) * 128 + kc * 32 + 8 * g;
            bf16x8 awH = *(const bf16x8*)&wpH[wrow];
            acc[at] = mfma16(awH, btH, acc[at]);
            if constexpr (F32) {
                bf16x8 awL = *(const bf16x8*)&wpL[wrow];
                acc[at] = mfma16(awH, btL, acc[at]);
                acc[at] = mfma16(awL, btH, acc[at]);
            }
        }
    }

    #pragma unroll
    for (int at = 0; at < 8; ++at) {
        const int c0 = at * 16 + 4 * g;
        float bp[4];
        #pragma unroll
        for (int rr = 0; rr < 4; ++rr) bp[rr] = ldel<F32>(b_proj, c0 + rr);
        const int n = tok0 + c16;
        const size_t ob = (size_t)n * 128 + c0;
        if constexpr (F32) {
            const float4 zv = *(const float4*)((const float*)z + ob);
            float4 o;
            o.x = acc[at][0] + bp[0] + zv.x;
            o.y = acc[at][1] + bp[1] + zv.y;
            o.z = acc[at][2] + bp[2] + zv.z;
            o.w = acc[at][3] + bp[3] + zv.w;
            *(float4*)((float*)out + ob) = o;
        } else {
            const uint2 zu = *(const uint2*)((const ush*)z + ob);
            float v0 = acc[at][0] + bp[0] + bflo(zu.x);
            float v1 = acc[at][1] + bp[1] + bfhi(zu.x);
            float v2 = acc[at][2] + bp[2] + bflo(zu.y);
            float v3 = acc[at][3] + bp[3] + bfhi(zu.y);
            uint2 u;
            u.x = (unsigned int)f2bf(v0) | ((unsigned int)f2bf(v1) << 16);
            u.y = (unsigned int)f2bf(v2) | ((unsigned int)f2bf(v3) << 16);
            *(uint2*)((ush*)out + ob) = u;
        }
    }
}

// ======================================================================
// ============   FALLBACK (ws too small): round-1 kernels   ============
// ======================================================================
template<bool F32>
__global__ __launch_bounds__(256) void attn_mfma(
    const void* __restrict__ z, const void* __restrict__ ln_g, const void* __restrict__ ln_b,
    const void* __restrict__ w_qkv, const void* __restrict__ b_qkv, void* __restrict__ out)
{
    if (sniff_is_f32((const unsigned int*)z) != F32) return;

    __shared__ __align__(16) unsigned char smem[53248];
    ush* znH  = (ush*)smem;
    ush* znL  = (ush*)(smem + 16384);
    ush* wtH  = (ush*)(smem + 32768);
    ush* wtL  = (ush*)(smem + 38912);
    float* biasm = (float*)(smem + 45056);
    ush* kHs  = znH;
    ush* kLs  = znL;
    ush* vtH  = (ush*)(smem + 32768);

    const int t    = threadIdx.x;
    const int lane = t & 63;
    const int w    = t >> 6;
    const int g    = lane >> 4;
    const int c16  = lane & 15;
    const int r    = blockIdx.x >> 2;
    const int h    = blockIdx.x & 3;
    ush* ps = (ush*)(smem + 49152) + (w << 9);

    if (t < 96) {
        int gc = ((t >> 5) << 7) + (h << 5) + (t & 31);
        float b0 = 0.f, b1 = 0.f;
        #pragma unroll 8
        for (int k = 0; k < 128; k += 2) {
            b0 += ldel<F32>(ln_b, k)     * ldel<F32>(w_qkv, k * 384 + gc);
            b1 += ldel<F32>(ln_b, k + 1) * ldel<F32>(w_qkv, (k + 1) * 384 + gc);
        }
        biasm[t] = ldel<F32>(b_qkv, gc) + b0 + b1;
    }

    const void* zrow = elptr<F32>(z, ((size_t)r * 256 + t) << 7);
    float sum = 0.f, sumsq = 0.f;
    #pragma unroll 1
    for (int i = 0; i < 16; ++i) {
        float v[8]; ld8<F32>(zrow, i, v);
        #pragma unroll
        for (int j = 0; j < 8; ++j) { sum += v[j]; sumsq += v[j] * v[j]; }
    }
    const float mu   = sum * (1.f / 128.f);
    const float rsig = 1.0f / sqrtf(sumsq * (1.f / 128.f) - mu * mu + 1e-5f);
    const float nb   = -mu * rsig;

    __syncthreads();

    float bv[6];
    #pragma unroll
    for (int ct = 0; ct < 6; ++ct) bv[ct] = biasm[ct * 16 + c16];

    f32x4 acc[4][6];
    #pragma unroll
    for (int qt = 0; qt < 4; ++qt)
        #pragma unroll
        for (int ct = 0; ct < 6; ++ct)
            #pragma unroll
            for (int rr = 0; rr < 4; ++rr) acc[qt][ct][rr] = 0.f;

    #pragma unroll 1
    for (int kc = 0; kc < 4; ++kc) {
        {
            float vv[8];
            #pragma unroll
            for (int i8 = 0; i8 < 4; ++i8) {
                ld8<F32>(zrow, kc * 4 + i8, vv);
                union { ush s[8]; uint4 v4; } uh, ul;
                #pragma unroll
                for (int j = 0; j < 8; ++j) {
                    float zh = fmaf(vv[j], rsig, nb);
                    splitf(zh, uh.s[j], ul.s[j]);
                }
                int b2 = sw_frag(t, i8);
                *(uint4*)&znH[b2] = uh.v4;
                *(uint4*)&znL[b2] = ul.v4;
            }
        }
        for (int idx = t; idx < 3072; idx += 256) {
            int c  = idx % 96;
            int kl = idx / 96;
            int kk = kc * 32 + kl;
            int gc = ((c >> 5) << 7) + (h << 5) + (c & 31);
            float wv = ldel<F32>(ln_g, kk) * ldel<F32>(w_qkv, kk * 384 + gc);
            ush hh, ll; splitf(wv, hh, ll);
            int o = sw_off(c, kl);
            wtH[o] = hh; wtL[o] = ll;
        }
        __syncthreads();

        bf16x8 bH[6], bL[6];
        #pragma unroll
        for (int ct = 0; ct < 6; ++ct) {
            int brow = ct * 16 + c16;
            bH[ct] = *(const bf16x8*)&wtH[sw_frag(brow, g)];
            bL[ct] = *(const bf16x8*)&wtL[sw_frag(brow, g)];
        }
        #pragma unroll
        for (int qt = 0; qt < 4; ++qt) {
            int arow = (w << 6) + (qt << 4) + c16;
            bf16x8 aHf = *(const bf16x8*)&znH[sw_frag(arow, g)];
            bf16x8 aLf = *(const bf16x8*)&znL[sw_frag(arow, g)];
            #pragma unroll
            for (int ct = 0; ct < 6; ++ct) {
                acc[qt][ct] = mfma16(aHf, bH[ct], acc[qt][ct]);
                acc[qt][ct] = mfma16(aHf, bL[ct], acc[qt][ct]);
                acc[qt][ct] = mfma16(aLf, bH[ct], acc[qt][ct]);
            }
        }
        __syncthreads();
    }

    #pragma unroll
    for (int qt = 0; qt < 4; ++qt)
        #pragma unroll
        for (int ct = 0; ct < 6; ++ct)
            #pragma unroll
            for (int rr = 0; rr < 4; ++rr) acc[qt][ct][rr] += bv[ct];

    #pragma unroll
    for (int qt = 0; qt < 4; ++qt) {
        #pragma unroll
        for (int rr = 0; rr < 4; ++rr) {
            int key = (w << 6) + (qt << 4) + 4 * g + rr;
            ush hh, ll;
            splitf(acc[qt][2][rr], hh, ll);
            kHs[sw_off(key, c16)]      = hh; kLs[sw_off(key, c16)]      = ll;
            splitf(acc[qt][3][rr], hh, ll);
            kHs[sw_off(key, 16 + c16)] = hh; kLs[sw_off(key, 16 + c16)] = ll;
            vtH[vt_off(c16,      key)] = f2bf(acc[qt][4][rr]);
            vtH[vt_off(16 + c16, key)] = f2bf(acc[qt][5][rr]);
        }
    }

    const float SCALE = 0.17677669529663689f;
    bf16x8 qfH[4], qfL[4];
    #pragma unroll
    for (int qt = 0; qt < 4; ++qt) {
        #pragma unroll
        for (int rr = 0; rr < 4; ++rr) {
            int rw = 4 * g + rr;
            ps[sw_off(rw, c16)]      = f2bf(acc[qt][0][rr] * SCALE);
            ps[sw_off(rw, 16 + c16)] = f2bf(acc[qt][1][rr] * SCALE);
        }
        qfH[qt] = *(const bf16x8*)&ps[sw_frag(c16, g)];
        #pragma unroll
        for (int rr = 0; rr < 4; ++rr) {
            int rw = 4 * g + rr;
            float q0 = acc[qt][0][rr] * SCALE;
            float q1 = acc[qt][1][rr] * SCALE;
            ps[sw_off(rw, c16)]      = f2bf(q0 - bf2f(f2bf(q0)));
            ps[sw_off(rw, 16 + c16)] = f2bf(q1 - bf2f(f2bf(q1)));
        }
        qfL[qt] = *(const bf16x8*)&ps[sw_frag(c16, g)];
    }
    __syncthreads();

    float m[16], l[16];
    #pragma unroll
    for (int i = 0; i < 16; ++i) { m[i] = -3.0e38f; l[i] = 0.f; }
    f32x4 O[4][2];
    #pragma unroll
    for (int qt = 0; qt < 4; ++qt)
        #pragma unroll
        for (int dt = 0; dt < 2; ++dt)
            #pragma unroll
            for (int rr = 0; rr < 4; ++rr) O[qt][dt][rr] = 0.f;

    f32x4 zed; zed[0] = 0.f; zed[1] = 0.f; zed[2] = 0.f; zed[3] = 0.f;

    #pragma unroll 1
    for (int kb = 0; kb < 8; ++kb) {
        int key0 = kb * 32;
        bf16x8 kfH[2], kfL[2], vf[2];
        #pragma unroll
        for (int kt = 0; kt < 2; ++kt) {
            int krow = key0 + 16 * kt + c16;
            kfH[kt] = *(const bf16x8*)&kHs[sw_frag(krow, g)];
            kfL[kt] = *(const bf16x8*)&kLs[sw_frag(krow, g)];
        }
        #pragma unroll
        for (int dt = 0; dt < 2; ++dt)
            vf[dt] = *(const bf16x8*)&vtH[vt_off(16 * dt + c16, key0 + 8 * g)];

        #pragma unroll
        for (int qt = 0; qt < 4; ++qt) {
            f32x4 s0 = mfma16(qfH[qt], kfH[0], zed);
            s0 = mfma16(qfH[qt], kfL[0], s0);
            s0 = mfma16(qfL[qt], kfH[0], s0);
            f32x4 s1 = mfma16(qfH[qt], kfH[1], zed);
            s1 = mfma16(qfH[qt], kfL[1], s1);
            s1 = mfma16(qfL[qt], kfH[1], s1);

            #pragma unroll
            for (int rr = 0; rr < 4; ++rr) {
                float mx = fmaxf(s0[rr], s1[rr]);
                mx = fmaxf(mx, __shfl_xor(mx, 1));
                mx = fmaxf(mx, __shfl_xor(mx, 2));
                mx = fmaxf(mx, __shfl_xor(mx, 4));
                mx = fmaxf(mx, __shfl_xor(mx, 8));
                const int idx = qt * 4 + rr;
                float mo = m[idx];
                float mn = fmaxf(mo, mx);
                float al = __expf(fmaxf(mo - mn, -87.f));
                float p0 = __expf(s0[rr] - mn);
                float p1 = __expf(s1[rr] - mn);
                l[idx] = l[idx] * al + p0 + p1;
                m[idx] = mn;
                O[qt][0][rr] *= al;
                O[qt][1][rr] *= al;
                int rw = 4 * g + rr;
                ps[sw_off(rw, c16)]      = f2bf(p0);
                ps[sw_off(rw, 16 + c16)] = f2bf(p1);
            }
            bf16x8 pf = *(const bf16x8*)&ps[sw_frag(c16, g)];
            O[qt][0] = mfma16(pf, vf[0], O[qt][0]);
            O[qt][1] = mfma16(pf, vf[1], O[qt][1]);
        }
    }

    #pragma unroll
    for (int i = 0; i < 16; ++i) {
        float s = l[i];
        s += __shfl_xor(s, 1);
        s += __shfl_xor(s, 2);
        s += __shfl_xor(s, 4);
        s += __shfl_xor(s, 8);
        l[i] = s;
    }

    #pragma unroll
    for (int qt = 0; qt < 4; ++qt) {
        #pragma unroll
        for (int rr = 0; rr < 4; ++rr) {
            float rlv = 1.f / l[qt * 4 + rr];
            int grow = (r << 8) + (w << 6) + (qt << 4) + 4 * g + rr;
            size_t base = ((size_t)grow << 7) + (h << 5);
            if constexpr (F32) {
                float* po = (float*)out + base;
                po[c16]      = O[qt][0][rr] * rlv;
                po[16 + c16] = O[qt][1][rr] * rlv;
            } else {
                ush* po = (ush*)out + base;
                po[c16]      = f2bf(O[qt][0][rr] * rlv);
                po[16 + c16] = f2bf(O[qt][1][rr] * rlv);
            }
        }
    }
}

template<bool F32>
__global__ __launch_bounds__(256) void proj_res(
    const void* __restrict__ z, const void* __restrict__ w_proj, const void* __restrict__ b_proj,
    void* __restrict__ out)
{
    if (sniff_is_f32((const unsigned int*)z) != F32) return;

    __shared__ unsigned int wu[8192];
    __shared__ float aT[128][20];

    const int t = threadIdx.x;
    const size_t row0 = (size_t)blockIdx.x * 16;

    if constexpr (!F32) {
        for (int idx = t; idx < 8192; idx += 256)
            wu[idx] = ((const unsigned int*)w_proj)[idx];
    }

    {
        const int rr = t >> 4;
        const int i8 = t & 15;
        float v[8];
        ld8<F32>(elptr<F32>((const void*)out, (row0 + rr) * 128), i8, v);
        #pragma unroll
        for (int j = 0; j < 8; ++j) aT[(i8 << 3) + j][rr] = v[j];
    }
    __syncthreads();

    const int c = t & 127;
    const int half = t >> 7;
    float acc8[8];
    const float bp = ldel<F32>(b_proj, c);
    #pragma unroll
    for (int rr = 0; rr < 8; ++rr) acc8[rr] = bp;

    #pragma unroll 1
    for (int k = 0; k < 128; ++k) {
        float wk;
        if constexpr (F32) {
            wk = ((const float*)w_proj)[k * 128 + c];
        } else {
            unsigned int u = wu[(k << 6) + (c >> 1)];
            wk = (c & 1) ? bfhi(u) : bflo(u);
        }
        const float4 a0 = *(const float4*)&aT[k][half * 8];
        const float4 a1 = *(const float4*)&aT[k][half * 8 + 4];
        acc8[0] = fmaf(a0.x, wk, acc8[0]);
        acc8[1] = fmaf(a0.y, wk, acc8[1]);
        acc8[2] = fmaf(a0.z, wk, acc8[2]);
        acc8[3] = fmaf(a0.w, wk, acc8[3]);
        acc8[4] = fmaf(a1.x, wk, acc8[4]);
        acc8[5] = fmaf(a1.y, wk, acc8[5]);
        acc8[6] = fmaf(a1.z, wk, acc8[6]);
        acc8[7] = fmaf(a1.w, wk, acc8[7]);
    }
    __syncthreads();
    float* ot = (float*)aT;
    #pragma unroll
    for (int rr = 0; rr < 8; ++rr)
        ot[(half * 8 + rr) * 128 + c] = acc8[rr];
    __syncthreads();

    {
        const int rr = t >> 4;
        const int i8 = t & 15;
        float zv[8], v[8];
        ld8<F32>(elptr<F32>(z, (row0 + rr) * 128), i8, zv);
        const float* po = &ot[rr * 128 + (i8 << 3)];
        #pragma unroll
        for (int j = 0; j < 8; ++j) v[j] = po[j] + zv[j];
        st8<F32>(elptrw<F32>(out, (row0 + rr) * 128), i8, v);
    }
}

extern "C" void kernel_launch(void* const* d_in, const int* in_sizes, int n_in,
                              void* d_out, int out_size, void* d_ws, size_t ws_size,
                              hipStream_t stream) {
    const void* z      = d_in[0];
    const void* ln_g   = d_in[1];
    const void* ln_b   = d_in[2];
    const void* w_qkv  = d_in[3];
    const void* b_qkv  = d_in[4];
    const void* w_proj = d_in[5];
    const void* b_proj = d_in[6];
    void* out = d_out;

    if (ws_size >= WS_NEED && d_ws != nullptr) {
        unsigned char* W = (unsigned char*)d_ws;
        ush*   wqSH  = (ush*)(W + 0);
        ush*   wqSL  = (ush*)(W + 98304);
        ush*   wpH   = (ush*)(W + 196608);
        ush*   wpL   = (ush*)(W + 229376);
        float* biasG = (float*)(W + 262144);
        ush*   znSH  = (ush*)(W + 266240);
        ush*   znSL  = (ush*)(W + 17043456);

        prep_w<false><<<64, 256, 0, stream>>>(z, ln_g, ln_b, w_qkv, b_qkv, w_proj, wqSH, wqSL, wpH, wpL, biasG);
        prep_w<true ><<<64, 256, 0, stream>>>(z, ln_g, ln_b, w_qkv, b_qkv, w_proj, wqSH, wqSL, wpH, wpL, biasG);
        prep_z<false><<<256, 256, 0, stream>>>(z, znSH, znSL);
        prep_z<true ><<<256, 256, 0, stream>>>(z, znSH, znSL);
        attn_mfma4<false><<<1024, 256, 0, stream>>>(z, znSH, znSL, wqSH, wqSL, biasG, out);
        attn_mfma4<true ><<<1024, 256, 0, stream>>>(z, znSH, znSL, wqSH, wqSL, biasG, out);
        proj_mfma2<false><<<1024, 256, 0, stream>>>(z, b_proj, wpH, wpL, out);
        proj_mfma2<true ><<<1024, 256, 0, stream>>>(z, b_proj, wpH, wpL, out);
    } else {
        attn_mfma<false><<<1024, 256, 0, stream>>>(z, ln_g, ln_b, w_qkv, b_qkv, out);
        attn_mfma<true ><<<1024, 256, 0, stream>>>(z, ln_g, ln_b, w_qkv, b_qkv, out);
        proj_res<false><<<4096, 256, 0, stream>>>(z, w_proj, b_proj, out);
        proj_res<true ><<<4096, 256, 0, stream>>>(z, w_proj, b_proj, out);
    }
}

// Round 8
// 300.833 us; speedup vs baseline: 1.0354x; 1.0354x over previous
//
#include <hip/hip_runtime.h>
#include <hip/hip_bf16.h>

// PairwiseAttention: z(1,256,256,128) -> LN -> QKV -> 4-head attn (over 2nd L axis)
// -> proj + residual.  Runtime dtype sniff (fp32 vs bf16).
//
// Round N+7 (re-run of N+6; previous bench died on container infra, no signal):
// (a) REVERT prep_z (round-6 net loss: relocated traffic, didn't remove it).
// (b) XCD-grouping block remap in attn: the 4 head-blocks sharing one r's
// token data now land on the SAME XCD L2 (bid%8 round-robin heuristic; remap
// is a bijection so correctness-neutral regardless). (c) prep_w bias loop
// parallelized (serial 128-dot -> 64-lane shfl reduce).
//   prep_w     : swizzled w' images + w_proj^T hi/lo + biasG (wave-parallel).
//   attn_mfma2 : round-5-VERIFIED (in-kernel LN; linear w' copy) + remap.
//   proj_mfma2 : round-6 1024-block version (measured neutral).
// Fallback to round-1 attn_mfma + proj_res when ws is too small.

using ush = unsigned short;

__device__ __forceinline__ float bflo(unsigned int u) { return __uint_as_float(u << 16); }
__device__ __forceinline__ float bfhi(unsigned int u) { return __uint_as_float(u & 0xffff0000u); }
__device__ __forceinline__ float bf2f(unsigned short u) { return __uint_as_float(((unsigned int)u) << 16); }
__device__ __forceinline__ unsigned short f2bf(float f) {
    unsigned int i = __float_as_uint(f);
    i += 0x7fffu + ((i >> 16) & 1u);           // round-to-nearest-even
    return (unsigned short)(i >> 16);
}
__device__ __forceinline__ void splitf(float x, unsigned short& h, unsigned short& l) {
    h = f2bf(x);
    l = f2bf(x - bf2f(h));
}

__device__ bool sniff_is_f32(const unsigned int* z) {
    int n = 0;
    for (int i = 0; i < 64; ++i) {
        float a = fabsf(bflo(z[i]));
        n += (int)(a > 1e4f) | (int)(a > 0.f && a < 1e-6f);
    }
    return n > 16;
}

template<bool F32> __device__ __forceinline__ float ldel(const void* p, int i) {
    if constexpr (F32) return ((const float*)p)[i];
    else               return bf2f(((const unsigned short*)p)[i]);
}
template<bool F32> __device__ __forceinline__ void ld8(const void* p, int i8, float* v) {
    if constexpr (F32) {
        const float4* q = (const float4*)p;
        float4 a = q[2 * i8], b = q[2 * i8 + 1];
        v[0]=a.x; v[1]=a.y; v[2]=a.z; v[3]=a.w; v[4]=b.x; v[5]=b.y; v[6]=b.z; v[7]=b.w;
    } else {
        uint4 u = ((const uint4*)p)[i8];
        const unsigned int* pu = (const unsigned int*)&u;
        #pragma unroll
        for (int j = 0; j < 4; ++j) { v[2*j] = bflo(pu[j]); v[2*j+1] = bfhi(pu[j]); }
    }
}
template<bool F32> __device__ __forceinline__ void st8(void* p, int i8, const float* v) {
    if constexpr (F32) {
        float4 a, b;
        a.x=v[0]; a.y=v[1]; a.z=v[2]; a.w=v[3];
        b.x=v[4]; b.y=v[5]; b.z=v[6]; b.w=v[7];
        ((float4*)p)[2 * i8] = a; ((float4*)p)[2 * i8 + 1] = b;
    } else {
        uint4 u; unsigned int* pu = (unsigned int*)&u;
        #pragma unroll
        for (int j = 0; j < 4; ++j)
            pu[j] = (unsigned int)f2bf(v[2*j]) | ((unsigned int)f2bf(v[2*j+1]) << 16);
        ((uint4*)p)[i8] = u;
    }
}
template<bool F32> __device__ __forceinline__ const void* elptr(const void* p, size_t off) {
    if constexpr (F32) return (const void*)((const float*)p + off);
    else               return (const void*)((const unsigned short*)p + off);
}
template<bool F32> __device__ __forceinline__ void* elptrw(void* p, size_t off) {
    if constexpr (F32) return (void*)((float*)p + off);
    else               return (void*)((unsigned short*)p + off);
}

// ---------------- MFMA plumbing ----------------
using bf16x8 = __attribute__((ext_vector_type(8))) short;   // 8 bf16 bits, 4 VGPR
using f32x4  = __attribute__((ext_vector_type(4))) float;

__device__ __forceinline__ f32x4 mfma16(bf16x8 a, bf16x8 b, f32x4 c) {
    return __builtin_amdgcn_mfma_f32_16x16x32_bf16(a, b, c, 0, 0, 0);
}

// [R][32]-bf16 LDS matrices with XOR-granule swizzle (verified round-1):
// sw_frag(row,g)+e == sw_off(row, 8*g+e)  (slot consistency across A and B).
__device__ __forceinline__ int sw_off (int row, int k) {
    return row * 32 + ((((k >> 3) ^ (row >> 1)) & 3) << 3) + (k & 7);
}
__device__ __forceinline__ int sw_frag(int row, int g) {
    return row * 32 + (((g ^ (row >> 1)) & 3) << 3);
}
// Vt: [32 dims][256 keys] bf16, XOR key-granule by (dim&7).
__device__ __forceinline__ int vt_off(int dim, int key) {
    return dim * 256 + (key ^ ((dim & 7) << 3));
}

// ws layout (bytes):
//   wqSH 0       (98304)   swizzled w' hi images: [(h*4+kc)*3072 + sw_off(c,kl)]
//   wqSL 98304   (98304)
//   wpH  196608  (32768)   w_proj^T hi: [c*128+k]
//   wpL  229376  (32768)
//   biasG 262144 (1536)    float[4][96]
#define WS_NEED 263680ull

// ---------------- prep_w: weight preprocessing, once (grid 96 x 256) ----------------
template<bool F32>
__global__ __launch_bounds__(256) void prep_w(
    const void* __restrict__ z, const void* __restrict__ ln_g, const void* __restrict__ ln_b,
    const void* __restrict__ w_qkv, const void* __restrict__ b_qkv, const void* __restrict__ w_proj,
    ush* __restrict__ wqSH, ush* __restrict__ wqSL,
    ush* __restrict__ wpH, ush* __restrict__ wpL, float* __restrict__ biasG)
{
    if (sniff_is_f32((const unsigned int*)z) != F32) return;
    const int gid = blockIdx.x * 256 + threadIdx.x;
    const int NT  = 96 * 256;

    // swizzled g.*W_qkv images: e = (h*4+kc)*3072 + c*32 + kl
    for (int e = gid; e < 49152; e += NT) {
        int kl = e & 31;
        int c  = (e >> 5) % 96;
        int hk = e / 3072;            // h*4+kc
        int h  = hk >> 2, kc = hk & 3;
        int k  = kc * 32 + kl;
        int gc = ((c >> 5) << 7) + (h << 5) + (c & 31);
        float wv = ldel<F32>(ln_g, k) * ldel<F32>(w_qkv, k * 384 + gc);
        ush hh, ll; splitf(wv, hh, ll);
        int o = hk * 3072 + sw_off(c, kl);
        wqSH[o] = hh; wqSL[o] = ll;
    }
    // w_proj transposed hi/lo: wp[c*128+k] = w_proj[k][c]
    for (int e = gid; e < 16384; e += NT) {
        int c = e >> 7, k = e & 127;
        float v = ldel<F32>(w_proj, k * 128 + c);
        ush hh, ll; splitf(v, hh, ll);
        wpH[e] = hh; wpL[e] = ll;
    }
    // bias[pair] = b_qkv[gc] + sum_k ln_b[k]*W[k][gc], wave-parallel:
    // pair = gid>>6 in [0,384) (h*96+c), lane covers k = lane, lane+64.
    if (gid < 384 * 64) {
        const int pair = gid >> 6;
        const int lane = gid & 63;
        const int h = pair / 96, c = pair % 96;
        const int gc = ((c >> 5) << 7) + (h << 5) + (c & 31);
        float s = ldel<F32>(ln_b, lane)      * ldel<F32>(w_qkv, lane * 384 + gc)
                + ldel<F32>(ln_b, lane + 64) * ldel<F32>(w_qkv, (lane + 64) * 384 + gc);
        #pragma unroll
        for (int d = 1; d < 64; d <<= 1) s += __shfl_xor(s, d);
        if (lane == 0) biasG[pair] = ldel<F32>(b_qkv, gc) + s;
    }
}

// ---------------- attn_mfma2: round-5-verified attn + XCD-grouping remap ----------------
// grid = 1024, block = 256 (4 waves; wave w owns query rows w*64..w*64+63).
// Remap: x=bid&7 (XCD under bid%8 round-robin), j=bid>>3, r=x*32+(j&31), h=j>>5
// -> the 4 blocks of one r share an XCD L2; bijection over (r,h).
template<bool F32>
__global__ __launch_bounds__(256) void attn_mfma2(
    const void* __restrict__ z, const ush* __restrict__ wqSH, const ush* __restrict__ wqSL,
    const float* __restrict__ biasG, void* __restrict__ out)
{
    if (sniff_is_f32((const unsigned int*)z) != F32) return;

    __shared__ __align__(16) unsigned char smem[53248];
    ush* znH  = (ush*)smem;
    ush* znL  = (ush*)(smem + 16384);
    ush* wtH  = (ush*)(smem + 32768);
    ush* wtL  = (ush*)(smem + 38912);
    ush* kHs  = znH;
    ush* kLs  = znL;
    ush* vtH  = (ush*)(smem + 32768);

    const int t    = threadIdx.x;
    const int lane = t & 63;
    const int w    = t >> 6;
    const int g    = lane >> 4;
    const int c16  = lane & 15;
    const int xcd  = blockIdx.x & 7;
    const int jj   = blockIdx.x >> 3;
    const int r    = (xcd << 5) | (jj & 31);
    const int h    = jj >> 5;
    ush* ps = (ush*)(smem + 49152) + (w << 9);

    const void* zrow = elptr<F32>(z, ((size_t)r * 256 + t) << 7);
    float sum = 0.f, sumsq = 0.f;
    #pragma unroll 1
    for (int i = 0; i < 16; ++i) {
        float v[8]; ld8<F32>(zrow, i, v);
        #pragma unroll
        for (int j = 0; j < 8; ++j) { sum += v[j]; sumsq += v[j] * v[j]; }
    }
    const float mu   = sum * (1.f / 128.f);
    const float rsig = 1.0f / sqrtf(sumsq * (1.f / 128.f) - mu * mu + 1e-5f);
    const float nb   = -mu * rsig;

    float bv[6];
    #pragma unroll
    for (int ct = 0; ct < 6; ++ct) bv[ct] = biasG[h * 96 + ct * 16 + c16];

    f32x4 acc[4][6];
    #pragma unroll
    for (int qt = 0; qt < 4; ++qt)
        #pragma unroll
        for (int ct = 0; ct < 6; ++ct)
            #pragma unroll
            for (int rr = 0; rr < 4; ++rr) acc[qt][ct][rr] = 0.f;

    #pragma unroll 1
    for (int kc = 0; kc < 4; ++kc) {
        {   // stage zn chunk (hi/lo split, swizzled) — verified round-1/5
            float vv[8];
            #pragma unroll
            for (int i8 = 0; i8 < 4; ++i8) {
                ld8<F32>(zrow, kc * 4 + i8, vv);
                union { ush s[8]; uint4 v4; } uh, ul;
                #pragma unroll
                for (int j = 0; j < 8; ++j) {
                    float zh = fmaf(vv[j], rsig, nb);
                    splitf(zh, uh.s[j], ul.s[j]);
                }
                int b2 = sw_frag(t, i8);
                *(uint4*)&znH[b2] = uh.v4;
                *(uint4*)&znL[b2] = ul.v4;
            }
        }
        {   // stage w' chunk: LINEAR copy of prepped swizzled image (round-5 verified)
            const uint4* srcH = (const uint4*)(wqSH + (h * 4 + kc) * 3072);
            const uint4* srcL = (const uint4*)(wqSL + (h * 4 + kc) * 3072);
            #pragma unroll
            for (int i = t; i < 768; i += 256) {
                if (i < 384) ((uint4*)wtH)[i]       = srcH[i];
                else         ((uint4*)wtL)[i - 384] = srcL[i - 384];
            }
        }
        __syncthreads();

        bf16x8 bH[6], bL[6];
        #pragma unroll
        for (int ct = 0; ct < 6; ++ct) {
            int brow = ct * 16 + c16;
            bH[ct] = *(const bf16x8*)&wtH[sw_frag(brow, g)];
            bL[ct] = *(const bf16x8*)&wtL[sw_frag(brow, g)];
        }
        #pragma unroll
        for (int qt = 0; qt < 4; ++qt) {
            int arow = (w << 6) + (qt << 4) + c16;
            bf16x8 aHf = *(const bf16x8*)&znH[sw_frag(arow, g)];
            bf16x8 aLf = *(const bf16x8*)&znL[sw_frag(arow, g)];
            #pragma unroll
            for (int ct = 0; ct < 6; ++ct) {
                acc[qt][ct] = mfma16(aHf, bH[ct], acc[qt][ct]);
                acc[qt][ct] = mfma16(aHf, bL[ct], acc[qt][ct]);
                acc[qt][ct] = mfma16(aLf, bH[ct], acc[qt][ct]);
            }
        }
        __syncthreads();
    }

    #pragma unroll
    for (int qt = 0; qt < 4; ++qt)
        #pragma unroll
        for (int ct = 0; ct < 6; ++ct)
            #pragma unroll
            for (int rr = 0; rr < 4; ++rr) acc[qt][ct][rr] += bv[ct];

    #pragma unroll
    for (int qt = 0; qt < 4; ++qt) {
        #pragma unroll
        for (int rr = 0; rr < 4; ++rr) {
            int key = (w << 6) + (qt << 4) + 4 * g + rr;
            ush hh, ll;
            splitf(acc[qt][2][rr], hh, ll);
            kHs[sw_off(key, c16)]      = hh; kLs[sw_off(key, c16)]      = ll;
            splitf(acc[qt][3][rr], hh, ll);
            kHs[sw_off(key, 16 + c16)] = hh; kLs[sw_off(key, 16 + c16)] = ll;
            vtH[vt_off(c16,      key)] = f2bf(acc[qt][4][rr]);
            vtH[vt_off(16 + c16, key)] = f2bf(acc[qt][5][rr]);
        }
    }

    const float SCALE = 0.17677669529663689f;
    bf16x8 qfH[4], qfL[4];
    #pragma unroll
    for (int qt = 0; qt < 4; ++qt) {
        #pragma unroll
        for (int rr = 0; rr < 4; ++rr) {
            int rw = 4 * g + rr;
            ps[sw_off(rw, c16)]      = f2bf(acc[qt][0][rr] * SCALE);
            ps[sw_off(rw, 16 + c16)] = f2bf(acc[qt][1][rr] * SCALE);
        }
        qfH[qt] = *(const bf16x8*)&ps[sw_frag(c16, g)];
        #pragma unroll
        for (int rr = 0; rr < 4; ++rr) {
            int rw = 4 * g + rr;
            float q0 = acc[qt][0][rr] * SCALE;
            float q1 = acc[qt][1][rr] * SCALE;
            ps[sw_off(rw, c16)]      = f2bf(q0 - bf2f(f2bf(q0)));
            ps[sw_off(rw, 16 + c16)] = f2bf(q1 - bf2f(f2bf(q1)));
        }
        qfL[qt] = *(const bf16x8*)&ps[sw_frag(c16, g)];
    }
    __syncthreads();

    float m[16], l[16];
    #pragma unroll
    for (int i = 0; i < 16; ++i) { m[i] = -3.0e38f; l[i] = 0.f; }
    f32x4 O[4][2];
    #pragma unroll
    for (int qt = 0; qt < 4; ++qt)
        #pragma unroll
        for (int dt = 0; dt < 2; ++dt)
            #pragma unroll
            for (int rr = 0; rr < 4; ++rr) O[qt][dt][rr] = 0.f;

    f32x4 zed; zed[0] = 0.f; zed[1] = 0.f; zed[2] = 0.f; zed[3] = 0.f;

    #pragma unroll 1
    for (int kb = 0; kb < 8; ++kb) {
        int key0 = kb * 32;
        bf16x8 kfH[2], kfL[2], vf[2];
        #pragma unroll
        for (int kt = 0; kt < 2; ++kt) {
            int krow = key0 + 16 * kt + c16;
            kfH[kt] = *(const bf16x8*)&kHs[sw_frag(krow, g)];
            kfL[kt] = *(const bf16x8*)&kLs[sw_frag(krow, g)];
        }
        #pragma unroll
        for (int dt = 0; dt < 2; ++dt)
            vf[dt] = *(const bf16x8*)&vtH[vt_off(16 * dt + c16, key0 + 8 * g)];

        #pragma unroll
        for (int qt = 0; qt < 4; ++qt) {
            f32x4 s0 = mfma16(qfH[qt], kfH[0], zed);
            s0 = mfma16(qfH[qt], kfL[0], s0);
            s0 = mfma16(qfL[qt], kfH[0], s0);
            f32x4 s1 = mfma16(qfH[qt], kfH[1], zed);
            s1 = mfma16(qfH[qt], kfL[1], s1);
            s1 = mfma16(qfL[qt], kfH[1], s1);

            #pragma unroll
            for (int rr = 0; rr < 4; ++rr) {
                float mx = fmaxf(s0[rr], s1[rr]);
                mx = fmaxf(mx, __shfl_xor(mx, 1));
                mx = fmaxf(mx, __shfl_xor(mx, 2));
                mx = fmaxf(mx, __shfl_xor(mx, 4));
                mx = fmaxf(mx, __shfl_xor(mx, 8));
                const int idx = qt * 4 + rr;
                float mo = m[idx];
                float mn = fmaxf(mo, mx);
                float al = __expf(fmaxf(mo - mn, -87.f));
                float p0 = __expf(s0[rr] - mn);
                float p1 = __expf(s1[rr] - mn);
                l[idx] = l[idx] * al + p0 + p1;
                m[idx] = mn;
                O[qt][0][rr] *= al;
                O[qt][1][rr] *= al;
                int rw = 4 * g + rr;
                ps[sw_off(rw, c16)]      = f2bf(p0);
                ps[sw_off(rw, 16 + c16)] = f2bf(p1);
            }
            bf16x8 pf = *(const bf16x8*)&ps[sw_frag(c16, g)];
            O[qt][0] = mfma16(pf, vf[0], O[qt][0]);
            O[qt][1] = mfma16(pf, vf[1], O[qt][1]);
        }
    }

    #pragma unroll
    for (int i = 0; i < 16; ++i) {
        float s = l[i];
        s += __shfl_xor(s, 1);
        s += __shfl_xor(s, 2);
        s += __shfl_xor(s, 4);
        s += __shfl_xor(s, 8);
        l[i] = s;
    }

    #pragma unroll
    for (int qt = 0; qt < 4; ++qt) {
        #pragma unroll
        for (int rr = 0; rr < 4; ++rr) {
            float rlv = 1.f / l[qt * 4 + rr];
            int grow = (r << 8) + (w << 6) + (qt << 4) + 4 * g + rr;
            size_t base = ((size_t)grow << 7) + (h << 5);
            if constexpr (F32) {
                float* po = (float*)out + base;
                po[c16]      = O[qt][0][rr] * rlv;
                po[16 + c16] = O[qt][1][rr] * rlv;
            } else {
                ush* po = (ush*)out + base;
                po[c16]      = f2bf(O[qt][0][rr] * rlv);
                po[16 + c16] = f2bf(O[qt][1][rr] * rlv);
            }
        }
    }
}

// ---------------- proj_mfma2: out = z + out @ w_proj + b_proj (in-place MFMA) ----------------
// grid 1024 (64 tokens each), block 256 (4 waves x 16 tokens, per-wave disjoint).
template<bool F32>
__global__ __launch_bounds__(256) void proj_mfma2(
    const void* __restrict__ z, const void* __restrict__ b_proj,
    const ush* __restrict__ wpH, const ush* __restrict__ wpL,
    void* __restrict__ out)
{
    if (sniff_is_f32((const unsigned int*)z) != F32) return;

    const int t    = threadIdx.x;
    const int lane = t & 63;
    const int w    = t >> 6;
    const int g    = lane >> 4;
    const int c16  = lane & 15;
    const int tok0 = blockIdx.x * 64 + w * 16;

    f32x4 acc[8];
    #pragma unroll
    for (int at = 0; at < 8; ++at)
        #pragma unroll
        for (int rr = 0; rr < 4; ++rr) acc[at][rr] = 0.f;

    #pragma unroll 1
    for (int kc = 0; kc < 4; ++kc) {
        const int token = tok0 + c16;
        float av[8];
        ld8<F32>(elptr<F32>((const void*)out, (size_t)token * 128 + kc * 32 + 8 * g), 0, av);
        union { ush s[8]; bf16x8 v; } hU, lU;
        #pragma unroll
        for (int j = 0; j < 8; ++j) splitf(av[j], hU.s[j], lU.s[j]);
        const bf16x8 btH = hU.v;
        const bf16x8 btL = lU.v;

        #pragma unroll
        for (int at = 0; at < 8; ++at) {
            const size_t wrow = (size_t)(at * 16 + c16) * 128 + kc * 32 + 8 * g;
            bf16x8 awH = *(const bf16x8*)&wpH[wrow];
            acc[at] = mfma16(awH, btH, acc[at]);
            if constexpr (F32) {
                bf16x8 awL = *(const bf16x8*)&wpL[wrow];
                acc[at] = mfma16(awH, btL, acc[at]);
                acc[at] = mfma16(awL, btH, acc[at]);
            }
        }
    }

    #pragma unroll
    for (int at = 0; at < 8; ++at) {
        const int c0 = at * 16 + 4 * g;
        float bp[4];
        #pragma unroll
        for (int rr = 0; rr < 4; ++rr) bp[rr] = ldel<F32>(b_proj, c0 + rr);
        const int n = tok0 + c16;
        const size_t ob = (size_t)n * 128 + c0;
        if constexpr (F32) {
            const float4 zv = *(const float4*)((const float*)z + ob);
            float4 o;
            o.x = acc[at][0] + bp[0] + zv.x;
            o.y = acc[at][1] + bp[1] + zv.y;
            o.z = acc[at][2] + bp[2] + zv.z;
            o.w = acc[at][3] + bp[3] + zv.w;
            *(float4*)((float*)out + ob) = o;
        } else {
            const uint2 zu = *(const uint2*)((const ush*)z + ob);
            float v0 = acc[at][0] + bp[0] + bflo(zu.x);
            float v1 = acc[at][1] + bp[1] + bfhi(zu.x);
            float v2 = acc[at][2] + bp[2] + bflo(zu.y);
            float v3 = acc[at][3] + bp[3] + bfhi(zu.y);
            uint2 u;
            u.x = (unsigned int)f2bf(v0) | ((unsigned int)f2bf(v1) << 16);
            u.y = (unsigned int)f2bf(v2) | ((unsigned int)f2bf(v3) << 16);
            *(uint2*)((ush*)out + ob) = u;
        }
    }
}

// ======================================================================
// ============   FALLBACK (ws too small): round-1 kernels   ============
// ======================================================================
template<bool F32>
__global__ __launch_bounds__(256) void attn_mfma(
    const void* __restrict__ z, const void* __restrict__ ln_g, const void* __restrict__ ln_b,
    const void* __restrict__ w_qkv, const void* __restrict__ b_qkv, void* __restrict__ out)
{
    if (sniff_is_f32((const unsigned int*)z) != F32) return;

    __shared__ __align__(16) unsigned char smem[53248];
    ush* znH  = (ush*)smem;
    ush* znL  = (ush*)(smem + 16384);
    ush* wtH  = (ush*)(smem + 32768);
    ush* wtL  = (ush*)(smem + 38912);
    float* biasm = (float*)(smem + 45056);
    ush* kHs  = znH;
    ush* kLs  = znL;
    ush* vtH  = (ush*)(smem + 32768);

    const int t    = threadIdx.x;
    const int lane = t & 63;
    const int w    = t >> 6;
    const int g    = lane >> 4;
    const int c16  = lane & 15;
    const int r    = blockIdx.x >> 2;
    const int h    = blockIdx.x & 3;
    ush* ps = (ush*)(smem + 49152) + (w << 9);

    if (t < 96) {
        int gc = ((t >> 5) << 7) + (h << 5) + (t & 31);
        float b0 = 0.f, b1 = 0.f;
        #pragma unroll 8
        for (int k = 0; k < 128; k += 2) {
            b0 += ldel<F32>(ln_b, k)     * ldel<F32>(w_qkv, k * 384 + gc);
            b1 += ldel<F32>(ln_b, k + 1) * ldel<F32>(w_qkv, (k + 1) * 384 + gc);
        }
        biasm[t] = ldel<F32>(b_qkv, gc) + b0 + b1;
    }

    const void* zrow = elptr<F32>(z, ((size_t)r * 256 + t) << 7);
    float sum = 0.f, sumsq = 0.f;
    #pragma unroll 1
    for (int i = 0; i < 16; ++i) {
        float v[8]; ld8<F32>(zrow, i, v);
        #pragma unroll
        for (int j = 0; j < 8; ++j) { sum += v[j]; sumsq += v[j] * v[j]; }
    }
    const float mu   = sum * (1.f / 128.f);
    const float rsig = 1.0f / sqrtf(sumsq * (1.f / 128.f) - mu * mu + 1e-5f);
    const float nb   = -mu * rsig;

    __syncthreads();

    float bv[6];
    #pragma unroll
    for (int ct = 0; ct < 6; ++ct) bv[ct] = biasm[ct * 16 + c16];

    f32x4 acc[4][6];
    #pragma unroll
    for (int qt = 0; qt < 4; ++qt)
        #pragma unroll
        for (int ct = 0; ct < 6; ++ct)
            #pragma unroll
            for (int rr = 0; rr < 4; ++rr) acc[qt][ct][rr] = 0.f;

    #pragma unroll 1
    for (int kc = 0; kc < 4; ++kc) {
        {
            float vv[8];
            #pragma unroll
            for (int i8 = 0; i8 < 4; ++i8) {
                ld8<F32>(zrow, kc * 4 + i8, vv);
                union { ush s[8]; uint4 v4; } uh, ul;
                #pragma unroll
                for (int j = 0; j < 8; ++j) {
                    float zh = fmaf(vv[j], rsig, nb);
                    splitf(zh, uh.s[j], ul.s[j]);
                }
                int b2 = sw_frag(t, i8);
                *(uint4*)&znH[b2] = uh.v4;
                *(uint4*)&znL[b2] = ul.v4;
            }
        }
        for (int idx = t; idx < 3072; idx += 256) {
            int c  = idx % 96;
            int kl = idx / 96;
            int kk = kc * 32 + kl;
            int gc = ((c >> 5) << 7) + (h << 5) + (c & 31);
            float wv = ldel<F32>(ln_g, kk) * ldel<F32>(w_qkv, kk * 384 + gc);
            ush hh, ll; splitf(wv, hh, ll);
            int o = sw_off(c, kl);
            wtH[o] = hh; wtL[o] = ll;
        }
        __syncthreads();

        bf16x8 bH[6], bL[6];
        #pragma unroll
        for (int ct = 0; ct < 6; ++ct) {
            int brow = ct * 16 + c16;
            bH[ct] = *(const bf16x8*)&wtH[sw_frag(brow, g)];
            bL[ct] = *(const bf16x8*)&wtL[sw_frag(brow, g)];
        }
        #pragma unroll
        for (int qt = 0; qt < 4; ++qt) {
            int arow = (w << 6) + (qt << 4) + c16;
            bf16x8 aHf = *(const bf16x8*)&znH[sw_frag(arow, g)];
            bf16x8 aLf = *(const bf16x8*)&znL[sw_frag(arow, g)];
            #pragma unroll
            for (int ct = 0; ct < 6; ++ct) {
                acc[qt][ct] = mfma16(aHf, bH[ct], acc[qt][ct]);
                acc[qt][ct] = mfma16(aHf, bL[ct], acc[qt][ct]);
                acc[qt][ct] = mfma16(aLf, bH[ct], acc[qt][ct]);
            }
        }
        __syncthreads();
    }

    #pragma unroll
    for (int qt = 0; qt < 4; ++qt)
        #pragma unroll
        for (int ct = 0; ct < 6; ++ct)
            #pragma unroll
            for (int rr = 0; rr < 4; ++rr) acc[qt][ct][rr] += bv[ct];

    #pragma unroll
    for (int qt = 0; qt < 4; ++qt) {
        #pragma unroll
        for (int rr = 0; rr < 4; ++rr) {
            int key = (w << 6) + (qt << 4) + 4 * g + rr;
            ush hh, ll;
            splitf(acc[qt][2][rr], hh, ll);
            kHs[sw_off(key, c16)]      = hh; kLs[sw_off(key, c16)]      = ll;
            splitf(acc[qt][3][rr], hh, ll);
            kHs[sw_off(key, 16 + c16)] = hh; kLs[sw_off(key, 16 + c16)] = ll;
            vtH[vt_off(c16,      key)] = f2bf(acc[qt][4][rr]);
            vtH[vt_off(16 + c16, key)] = f2bf(acc[qt][5][rr]);
        }
    }

    const float SCALE = 0.17677669529663689f;
    bf16x8 qfH[4], qfL[4];
    #pragma unroll
    for (int qt = 0; qt < 4; ++qt) {
        #pragma unroll
        for (int rr = 0; rr < 4; ++rr) {
            int rw = 4 * g + rr;
            ps[sw_off(rw, c16)]      = f2bf(acc[qt][0][rr] * SCALE);
            ps[sw_off(rw, 16 + c16)] = f2bf(acc[qt][1][rr] * SCALE);
        }
        qfH[qt] = *(const bf16x8*)&ps[sw_frag(c16, g)];
        #pragma unroll
        for (int rr = 0; rr < 4; ++rr) {
            int rw = 4 * g + rr;
            float q0 = acc[qt][0][rr] * SCALE;
            float q1 = acc[qt][1][rr] * SCALE;
            ps[sw_off(rw, c16)]      = f2bf(q0 - bf2f(f2bf(q0)));
            ps[sw_off(rw, 16 + c16)] = f2bf(q1 - bf2f(f2bf(q1)));
        }
        qfL[qt] = *(const bf16x8*)&ps[sw_frag(c16, g)];
    }
    __syncthreads();

    float m[16], l[16];
    #pragma unroll
    for (int i = 0; i < 16; ++i) { m[i] = -3.0e38f; l[i] = 0.f; }
    f32x4 O[4][2];
    #pragma unroll
    for (int qt = 0; qt < 4; ++qt)
        #pragma unroll
        for (int dt = 0; dt < 2; ++dt)
            #pragma unroll
            for (int rr = 0; rr < 4; ++rr) O[qt][dt][rr] = 0.f;

    f32x4 zed; zed[0] = 0.f; zed[1] = 0.f; zed[2] = 0.f; zed[3] = 0.f;

    #pragma unroll 1
    for (int kb = 0; kb < 8; ++kb) {
        int key0 = kb * 32;
        bf16x8 kfH[2], kfL[2], vf[2];
        #pragma unroll
        for (int kt = 0; kt < 2; ++kt) {
            int krow = key0 + 16 * kt + c16;
            kfH[kt] = *(const bf16x8*)&kHs[sw_frag(krow, g)];
            kfL[kt] = *(const bf16x8*)&kLs[sw_frag(krow, g)];
        }
        #pragma unroll
        for (int dt = 0; dt < 2; ++dt)
            vf[dt] = *(const bf16x8*)&vtH[vt_off(16 * dt + c16, key0 + 8 * g)];

        #pragma unroll
        for (int qt = 0; qt < 4; ++qt) {
            f32x4 s0 = mfma16(qfH[qt], kfH[0], zed);
            s0 = mfma16(qfH[qt], kfL[0], s0);
            s0 = mfma16(qfL[qt], kfH[0], s0);
            f32x4 s1 = mfma16(qfH[qt], kfH[1], zed);
            s1 = mfma16(qfH[qt], kfL[1], s1);
            s1 = mfma16(qfL[qt], kfH[1], s1);

            #pragma unroll
            for (int rr = 0; rr < 4; ++rr) {
                float mx = fmaxf(s0[rr], s1[rr]);
                mx = fmaxf(mx, __shfl_xor(mx, 1));
                mx = fmaxf(mx, __shfl_xor(mx, 2));
                mx = fmaxf(mx, __shfl_xor(mx, 4));
                mx = fmaxf(mx, __shfl_xor(mx, 8));
                const int idx = qt * 4 + rr;
                float mo = m[idx];
                float mn = fmaxf(mo, mx);
                float al = __expf(fmaxf(mo - mn, -87.f));
                float p0 = __expf(s0[rr] - mn);
                float p1 = __expf(s1[rr] - mn);
                l[idx] = l[idx] * al + p0 + p1;
                m[idx] = mn;
                O[qt][0][rr] *= al;
                O[qt][1][rr] *= al;
                int rw = 4 * g + rr;
                ps[sw_off(rw, c16)]      = f2bf(p0);
                ps[sw_off(rw, 16 + c16)] = f2bf(p1);
            }
            bf16x8 pf = *(const bf16x8*)&ps[sw_frag(c16, g)];
            O[qt][0] = mfma16(pf, vf[0], O[qt][0]);
            O[qt][1] = mfma16(pf, vf[1], O[qt][1]);
        }
    }

    #pragma unroll
    for (int i = 0; i < 16; ++i) {
        float s = l[i];
        s += __shfl_xor(s, 1);
        s += __shfl_xor(s, 2);
        s += __shfl_xor(s, 4);
        s += __shfl_xor(s, 8);
        l[i] = s;
    }

    #pragma unroll
    for (int qt = 0; qt < 4; ++qt) {
        #pragma unroll
        for (int rr = 0; rr < 4; ++rr) {
            float rlv = 1.f / l[qt * 4 + rr];
            int grow = (r << 8) + (w << 6) + (qt << 4) + 4 * g + rr;
            size_t base = ((size_t)grow << 7) + (h << 5);
            if constexpr (F32) {
                float* po = (float*)out + base;
                po[c16]      = O[qt][0][rr] * rlv;
                po[16 + c16] = O[qt][1][rr] * rlv;
            } else {
                ush* po = (ush*)out + base;
                po[c16]      = f2bf(O[qt][0][rr] * rlv);
                po[16 + c16] = f2bf(O[qt][1][rr] * rlv);
            }
        }
    }
}

template<bool F32>
__global__ __launch_bounds__(256) void proj_res(
    const void* __restrict__ z, const void* __restrict__ w_proj, const void* __restrict__ b_proj,
    void* __restrict__ out)
{
    if (sniff_is_f32((const unsigned int*)z) != F32) return;

    __shared__ unsigned int wu[8192];
    __shared__ float aT[128][20];

    const int t = threadIdx.x;
    const size_t row0 = (size_t)blockIdx.x * 16;

    if constexpr (!F32) {
        for (int idx = t; idx < 8192; idx += 256)
            wu[idx] = ((const unsigned int*)w_proj)[idx];
    }

    {
        const int rr = t >> 4;
        const int i8 = t & 15;
        float v[8];
        ld8<F32>(elptr<F32>((const void*)out, (row0 + rr) * 128), i8, v);
        #pragma unroll
        for (int j = 0; j < 8; ++j) aT[(i8 << 3) + j][rr] = v[j];
    }
    __syncthreads();

    const int c = t & 127;
    const int half = t >> 7;
    float acc8[8];
    const float bp = ldel<F32>(b_proj, c);
    #pragma unroll
    for (int rr = 0; rr < 8; ++rr) acc8[rr] = bp;

    #pragma unroll 1
    for (int k = 0; k < 128; ++k) {
        float wk;
        if constexpr (F32) {
            wk = ((const float*)w_proj)[k * 128 + c];
        } else {
            unsigned int u = wu[(k << 6) + (c >> 1)];
            wk = (c & 1) ? bfhi(u) : bflo(u);
        }
        const float4 a0 = *(const float4*)&aT[k][half * 8];
        const float4 a1 = *(const float4*)&aT[k][half * 8 + 4];
        acc8[0] = fmaf(a0.x, wk, acc8[0]);
        acc8[1] = fmaf(a0.y, wk, acc8[1]);
        acc8[2] = fmaf(a0.z, wk, acc8[2]);
        acc8[3] = fmaf(a0.w, wk, acc8[3]);
        acc8[4] = fmaf(a1.x, wk, acc8[4]);
        acc8[5] = fmaf(a1.y, wk, acc8[5]);
        acc8[6] = fmaf(a1.z, wk, acc8[6]);
        acc8[7] = fmaf(a1.w, wk, acc8[7]);
    }
    __syncthreads();
    float* ot = (float*)aT;
    #pragma unroll
    for (int rr = 0; rr < 8; ++rr)
        ot[(half * 8 + rr) * 128 + c] = acc8[rr];
    __syncthreads();

    {
        const int rr = t >> 4;
        const int i8 = t & 15;
        float zv[8], v[8];
        ld8<F32>(elptr<F32>(z, (row0 + rr) * 128), i8, zv);
        const float* po = &ot[rr * 128 + (i8 << 3)];
        #pragma unroll
        for (int j = 0; j < 8; ++j) v[j] = po[j] + zv[j];
        st8<F32>(elptrw<F32>(out, (row0 + rr) * 128), i8, v);
    }
}

extern "C" void kernel_launch(void* const* d_in, const int* in_sizes, int n_in,
                              void* d_out, int out_size, void* d_ws, size_t ws_size,
                              hipStream_t stream) {
    const void* z      = d_in[0];
    const void* ln_g   = d_in[1];
    const void* ln_b   = d_in[2];
    const void* w_qkv  = d_in[3];
    const void* b_qkv  = d_in[4];
    const void* w_proj = d_in[5];
    const void* b_proj = d_in[6];
    void* out = d_out;

    if (ws_size >= WS_NEED && d_ws != nullptr) {
        unsigned char* W = (unsigned char*)d_ws;
        ush*   wqSH  = (ush*)(W + 0);
        ush*   wqSL  = (ush*)(W + 98304);
        ush*   wpH   = (ush*)(W + 196608);
        ush*   wpL   = (ush*)(W + 229376);
        float* biasG = (float*)(W + 262144);

        prep_w<false><<<96, 256, 0, stream>>>(z, ln_g, ln_b, w_qkv, b_qkv, w_proj, wqSH, wqSL, wpH, wpL, biasG);
        prep_w<true ><<<96, 256, 0, stream>>>(z, ln_g, ln_b, w_qkv, b_qkv, w_proj, wqSH, wqSL, wpH, wpL, biasG);
        attn_mfma2<false><<<1024, 256, 0, stream>>>(z, wqSH, wqSL, biasG, out);
        attn_mfma2<true ><<<1024, 256, 0, stream>>>(z, wqSH, wqSL, biasG, out);
        proj_mfma2<false><<<1024, 256, 0, stream>>>(z, b_proj, wpH, wpL, out);
        proj_mfma2<true ><<<1024, 256, 0, stream>>>(z, b_proj, wpH, wpL, out);
    } else {
        attn_mfma<false><<<1024, 256, 0, stream>>>(z, ln_g, ln_b, w_qkv, b_qkv, out);
        attn_mfma<true ><<<1024, 256, 0, stream>>>(z, ln_g, ln_b, w_qkv, b_qkv, out);
        proj_res<false><<<4096, 256, 0, stream>>>(z, w_proj, b_proj, out);
        proj_res<true ><<<4096, 256, 0, stream>>>(z, w_proj, b_proj, out);
    }
}

// Round 9
// 281.392 us; speedup vs baseline: 1.1069x; 1.0691x over previous
//
#include <hip/hip_runtime.h>
#include <hip/hip_bf16.h>

// PairwiseAttention: z(1,256,256,128) -> LN -> QKV -> 4-head attn (over 2nd L axis)
// -> proj + residual.  Runtime dtype sniff (fp32 vs bf16).
//
// Round N+8: LN AFFINE FOLDING.  zn@W = rsig*(z@W) + nb*colsum(W), so the GEMM
// consumes RAW z: the LN-stats pre-pass is deleted (z read ONCE per block, was
// the structural 2x fetch), stats accumulate during the single staging pass,
// and rsig/nb fold into the epilogue (per-wave LDS bounce; C rows are
// wave-local).  bf16-input bonus: raw z is exactly bf16 -> z-lo term == 0 ->
// 2-term MFMA (skip 1/3 of QKV MFMAs, bit-identical skip).
// Remap v2: same-r head-blocks at bids {b,b+8,b+16,b+24} -> same XCD AND
// temporally adjacent (round-8's h-in-high-bits remap was neutral: sharers
// were 256 bids apart, z evicted from 4MB L2 before reuse).
//   prep_w     : + csumG[h*96+c] = sum_k g[k]W[k][gc] (same wave-reduce as bias).
//   attn_mfma3 : folded-LN attn (flash phase verbatim round-5).
//   proj_mfma2 : unchanged (round-6 1024-block version).
// Fallback to round-1 attn_mfma + proj_res when ws is too small.

using ush = unsigned short;

__device__ __forceinline__ float bflo(unsigned int u) { return __uint_as_float(u << 16); }
__device__ __forceinline__ float bfhi(unsigned int u) { return __uint_as_float(u & 0xffff0000u); }
__device__ __forceinline__ float bf2f(unsigned short u) { return __uint_as_float(((unsigned int)u) << 16); }
__device__ __forceinline__ unsigned short f2bf(float f) {
    unsigned int i = __float_as_uint(f);
    i += 0x7fffu + ((i >> 16) & 1u);           // round-to-nearest-even
    return (unsigned short)(i >> 16);
}
__device__ __forceinline__ void splitf(float x, unsigned short& h, unsigned short& l) {
    h = f2bf(x);
    l = f2bf(x - bf2f(h));
}

__device__ bool sniff_is_f32(const unsigned int* z) {
    int n = 0;
    for (int i = 0; i < 64; ++i) {
        float a = fabsf(bflo(z[i]));
        n += (int)(a > 1e4f) | (int)(a > 0.f && a < 1e-6f);
    }
    return n > 16;
}

template<bool F32> __device__ __forceinline__ float ldel(const void* p, int i) {
    if constexpr (F32) return ((const float*)p)[i];
    else               return bf2f(((const unsigned short*)p)[i]);
}
template<bool F32> __device__ __forceinline__ void ld8(const void* p, int i8, float* v) {
    if constexpr (F32) {
        const float4* q = (const float4*)p;
        float4 a = q[2 * i8], b = q[2 * i8 + 1];
        v[0]=a.x; v[1]=a.y; v[2]=a.z; v[3]=a.w; v[4]=b.x; v[5]=b.y; v[6]=b.z; v[7]=b.w;
    } else {
        uint4 u = ((const uint4*)p)[i8];
        const unsigned int* pu = (const unsigned int*)&u;
        #pragma unroll
        for (int j = 0; j < 4; ++j) { v[2*j] = bflo(pu[j]); v[2*j+1] = bfhi(pu[j]); }
    }
}
template<bool F32> __device__ __forceinline__ void st8(void* p, int i8, const float* v) {
    if constexpr (F32) {
        float4 a, b;
        a.x=v[0]; a.y=v[1]; a.z=v[2]; a.w=v[3];
        b.x=v[4]; b.y=v[5]; b.z=v[6]; b.w=v[7];
        ((float4*)p)[2 * i8] = a; ((float4*)p)[2 * i8 + 1] = b;
    } else {
        uint4 u; unsigned int* pu = (unsigned int*)&u;
        #pragma unroll
        for (int j = 0; j < 4; ++j)
            pu[j] = (unsigned int)f2bf(v[2*j]) | ((unsigned int)f2bf(v[2*j+1]) << 16);
        ((uint4*)p)[i8] = u;
    }
}
template<bool F32> __device__ __forceinline__ const void* elptr(const void* p, size_t off) {
    if constexpr (F32) return (const void*)((const float*)p + off);
    else               return (const void*)((const unsigned short*)p + off);
}
template<bool F32> __device__ __forceinline__ void* elptrw(void* p, size_t off) {
    if constexpr (F32) return (void*)((float*)p + off);
    else               return (void*)((unsigned short*)p + off);
}

// ---------------- MFMA plumbing ----------------
using bf16x8 = __attribute__((ext_vector_type(8))) short;   // 8 bf16 bits, 4 VGPR
using f32x4  = __attribute__((ext_vector_type(4))) float;

__device__ __forceinline__ f32x4 mfma16(bf16x8 a, bf16x8 b, f32x4 c) {
    return __builtin_amdgcn_mfma_f32_16x16x32_bf16(a, b, c, 0, 0, 0);
}

// [R][32]-bf16 LDS matrices with XOR-granule swizzle (verified round-1):
// sw_frag(row,g)+e == sw_off(row, 8*g+e)  (slot consistency across A and B).
__device__ __forceinline__ int sw_off (int row, int k) {
    return row * 32 + ((((k >> 3) ^ (row >> 1)) & 3) << 3) + (k & 7);
}
__device__ __forceinline__ int sw_frag(int row, int g) {
    return row * 32 + (((g ^ (row >> 1)) & 3) << 3);
}
// Vt: [32 dims][256 keys] bf16, XOR key-granule by (dim&7).
__device__ __forceinline__ int vt_off(int dim, int key) {
    return dim * 256 + (key ^ ((dim & 7) << 3));
}

// ws layout (bytes):
//   wqSH 0       (98304)   swizzled w' hi images: [(h*4+kc)*3072 + sw_off(c,kl)]
//   wqSL 98304   (98304)
//   wpH  196608  (32768)   w_proj^T hi: [c*128+k]
//   wpL  229376  (32768)
//   biasG 262144 (1536)    float[4][96]
//   csumG 263680 (1536)    float[4][96]: sum_k g[k]*W[k][gc]
#define WS_NEED 265216ull

// ---------------- prep_w: weight preprocessing, once (grid 96 x 256) ----------------
template<bool F32>
__global__ __launch_bounds__(256) void prep_w(
    const void* __restrict__ z, const void* __restrict__ ln_g, const void* __restrict__ ln_b,
    const void* __restrict__ w_qkv, const void* __restrict__ b_qkv, const void* __restrict__ w_proj,
    ush* __restrict__ wqSH, ush* __restrict__ wqSL,
    ush* __restrict__ wpH, ush* __restrict__ wpL,
    float* __restrict__ biasG, float* __restrict__ csumG)
{
    if (sniff_is_f32((const unsigned int*)z) != F32) return;
    const int gid = blockIdx.x * 256 + threadIdx.x;
    const int NT  = 96 * 256;

    // swizzled g.*W_qkv images: e = (h*4+kc)*3072 + c*32 + kl
    for (int e = gid; e < 49152; e += NT) {
        int kl = e & 31;
        int c  = (e >> 5) % 96;
        int hk = e / 3072;            // h*4+kc
        int h  = hk >> 2, kc = hk & 3;
        int k  = kc * 32 + kl;
        int gc = ((c >> 5) << 7) + (h << 5) + (c & 31);
        float wv = ldel<F32>(ln_g, k) * ldel<F32>(w_qkv, k * 384 + gc);
        ush hh, ll; splitf(wv, hh, ll);
        int o = hk * 3072 + sw_off(c, kl);
        wqSH[o] = hh; wqSL[o] = ll;
    }
    // w_proj transposed hi/lo: wp[c*128+k] = w_proj[k][c]
    for (int e = gid; e < 16384; e += NT) {
        int c = e >> 7, k = e & 127;
        float v = ldel<F32>(w_proj, k * 128 + c);
        ush hh, ll; splitf(v, hh, ll);
        wpH[e] = hh; wpL[e] = ll;
    }
    // bias[pair] = b_qkv[gc] + sum_k ln_b[k]*W[k][gc]
    // csum[pair] =             sum_k ln_g[k]*W[k][gc]   (wave-parallel dual reduce)
    if (gid < 384 * 64) {
        const int pair = gid >> 6;
        const int lane = gid & 63;
        const int h = pair / 96, c = pair % 96;
        const int gc = ((c >> 5) << 7) + (h << 5) + (c & 31);
        const float w0 = ldel<F32>(w_qkv, lane * 384 + gc);
        const float w1 = ldel<F32>(w_qkv, (lane + 64) * 384 + gc);
        float s  = ldel<F32>(ln_b, lane) * w0 + ldel<F32>(ln_b, lane + 64) * w1;
        float s2 = ldel<F32>(ln_g, lane) * w0 + ldel<F32>(ln_g, lane + 64) * w1;
        #pragma unroll
        for (int d = 1; d < 64; d <<= 1) { s += __shfl_xor(s, d); s2 += __shfl_xor(s2, d); }
        if (lane == 0) { biasG[pair] = ldel<F32>(b_qkv, gc) + s; csumG[pair] = s2; }
    }
}

// ---------------- attn_mfma3: folded-LN attn (single z pass) ----------------
// grid = 1024, block = 256 (4 waves; wave w owns query rows w*64..w*64+63).
// Remap v2: xcd=bid&7, jj=bid>>3, r=(xcd<<5)|(jj>>2), h=jj&3 — same-r sharers
// at bids {b,b+8,b+16,b+24}: same XCD, temporally adjacent. Bijection.
template<bool F32>
__global__ __launch_bounds__(256) void attn_mfma3(
    const void* __restrict__ z, const ush* __restrict__ wqSH, const ush* __restrict__ wqSL,
    const float* __restrict__ biasG, const float* __restrict__ csumG, void* __restrict__ out)
{
    if (sniff_is_f32((const unsigned int*)z) != F32) return;

    __shared__ __align__(16) unsigned char smem[53248];
    ush* znH  = (ush*)smem;
    ush* znL  = (ush*)(smem + 16384);
    ush* wtH  = (ush*)(smem + 32768);
    ush* wtL  = (ush*)(smem + 38912);
    ush* kHs  = znH;
    ush* kLs  = znL;
    ush* vtH  = (ush*)(smem + 32768);

    const int t    = threadIdx.x;
    const int lane = t & 63;
    const int w    = t >> 6;
    const int g    = lane >> 4;
    const int c16  = lane & 15;
    const int xcd  = blockIdx.x & 7;
    const int jj   = blockIdx.x >> 3;
    const int r    = (xcd << 5) | (jj >> 2);
    const int h    = jj & 3;
    ush* ps = (ush*)(smem + 49152) + (w << 9);

    const void* zrow = elptr<F32>(z, ((size_t)r * 256 + t) << 7);

    float bv[6], cs[6];
    #pragma unroll
    for (int ct = 0; ct < 6; ++ct) {
        bv[ct] = biasG[h * 96 + ct * 16 + c16];
        cs[ct] = csumG[h * 96 + ct * 16 + c16];
    }

    f32x4 acc[4][6];
    #pragma unroll
    for (int qt = 0; qt < 4; ++qt)
        #pragma unroll
        for (int ct = 0; ct < 6; ++ct)
            #pragma unroll
            for (int rr = 0; rr < 4; ++rr) acc[qt][ct][rr] = 0.f;

    // single z pass: stage RAW z (hi/lo) + accumulate LN stats on the fly.
    float sum = 0.f, sumsq = 0.f;

    #pragma unroll 1
    for (int kc = 0; kc < 4; ++kc) {
        if constexpr (!F32) {
            // raw z IS bf16: hi image = raw bits (exact), lo == 0 (skip).
            #pragma unroll
            for (int i8 = 0; i8 < 4; ++i8) {
                uint4 u = ((const uint4*)zrow)[kc * 4 + i8];
                *(uint4*)&znH[sw_frag(t, i8)] = u;
                const unsigned int* pu = (const unsigned int*)&u;
                #pragma unroll
                for (int j = 0; j < 4; ++j) {
                    float a = bflo(pu[j]), b = bfhi(pu[j]);
                    sum += a + b; sumsq += a * a + b * b;
                }
            }
        } else {
            float vv[8];
            #pragma unroll
            for (int i8 = 0; i8 < 4; ++i8) {
                ld8<F32>(zrow, kc * 4 + i8, vv);
                union { ush s[8]; uint4 v4; } uh, ul;
                #pragma unroll
                for (int j = 0; j < 8; ++j) {
                    splitf(vv[j], uh.s[j], ul.s[j]);
                    sum += vv[j]; sumsq += vv[j] * vv[j];
                }
                int b2 = sw_frag(t, i8);
                *(uint4*)&znH[b2] = uh.v4;
                *(uint4*)&znL[b2] = ul.v4;
            }
        }
        {   // stage w' chunk: LINEAR copy of prepped swizzled image (round-5 verified)
            const uint4* srcH = (const uint4*)(wqSH + (h * 4 + kc) * 3072);
            const uint4* srcL = (const uint4*)(wqSL + (h * 4 + kc) * 3072);
            #pragma unroll
            for (int i = t; i < 768; i += 256) {
                if (i < 384) ((uint4*)wtH)[i]       = srcH[i];
                else         ((uint4*)wtL)[i - 384] = srcL[i - 384];
            }
        }
        __syncthreads();

        bf16x8 bH[6], bL[6];
        #pragma unroll
        for (int ct = 0; ct < 6; ++ct) {
            int brow = ct * 16 + c16;
            bH[ct] = *(const bf16x8*)&wtH[sw_frag(brow, g)];
            bL[ct] = *(const bf16x8*)&wtL[sw_frag(brow, g)];
        }
        #pragma unroll
        for (int qt = 0; qt < 4; ++qt) {
            int arow = (w << 6) + (qt << 4) + c16;
            bf16x8 aHf = *(const bf16x8*)&znH[sw_frag(arow, g)];
            if constexpr (!F32) {
                #pragma unroll
                for (int ct = 0; ct < 6; ++ct) {
                    acc[qt][ct] = mfma16(aHf, bH[ct], acc[qt][ct]);
                    acc[qt][ct] = mfma16(aHf, bL[ct], acc[qt][ct]);
                }
            } else {
                bf16x8 aLf = *(const bf16x8*)&znL[sw_frag(arow, g)];
                #pragma unroll
                for (int ct = 0; ct < 6; ++ct) {
                    acc[qt][ct] = mfma16(aHf, bH[ct], acc[qt][ct]);
                    acc[qt][ct] = mfma16(aHf, bL[ct], acc[qt][ct]);
                    acc[qt][ct] = mfma16(aLf, bH[ct], acc[qt][ct]);
                }
            }
        }
        __syncthreads();
    }

    // LN stats finalize (same accumulation order as before -> identical stats)
    const float mu   = sum * (1.f / 128.f);
    const float rsig = 1.0f / sqrtf(sumsq * (1.f / 128.f) - mu * mu + 1e-5f);
    const float nb   = -mu * rsig;

    // wave-local rsig/nb exchange (C rows are this wave's own 64 tokens)
    float* pf = (float*)ps;              // 1KB per-wave scratch; need 512B
    pf[lane] = rsig; pf[64 + lane] = nb;
    __asm__ volatile("" ::: "memory");

    // epilogue fold: acc = rsig[row]*acc + nb[row]*csum[col] + bias[col]
    #pragma unroll
    for (int qt = 0; qt < 4; ++qt) {
        #pragma unroll
        for (int rr = 0; rr < 4; ++rr) {
            const int j = (qt << 4) + 4 * g + rr;
            const float rs = pf[j];
            const float nv = pf[64 + j];
            #pragma unroll
            for (int ct = 0; ct < 6; ++ct)
                acc[qt][ct][rr] = fmaf(rs, acc[qt][ct][rr], fmaf(nv, cs[ct], bv[ct]));
        }
    }
    __asm__ volatile("" ::: "memory");   // ps reused below (wave-synchronous)

    #pragma unroll
    for (int qt = 0; qt < 4; ++qt) {
        #pragma unroll
        for (int rr = 0; rr < 4; ++rr) {
            int key = (w << 6) + (qt << 4) + 4 * g + rr;
            ush hh, ll;
            splitf(acc[qt][2][rr], hh, ll);
            kHs[sw_off(key, c16)]      = hh; kLs[sw_off(key, c16)]      = ll;
            splitf(acc[qt][3][rr], hh, ll);
            kHs[sw_off(key, 16 + c16)] = hh; kLs[sw_off(key, 16 + c16)] = ll;
            vtH[vt_off(c16,      key)] = f2bf(acc[qt][4][rr]);
            vtH[vt_off(16 + c16, key)] = f2bf(acc[qt][5][rr]);
        }
    }

    const float SCALE = 0.17677669529663689f;
    bf16x8 qfH[4], qfL[4];
    #pragma unroll
    for (int qt = 0; qt < 4; ++qt) {
        #pragma unroll
        for (int rr = 0; rr < 4; ++rr) {
            int rw = 4 * g + rr;
            ps[sw_off(rw, c16)]      = f2bf(acc[qt][0][rr] * SCALE);
            ps[sw_off(rw, 16 + c16)] = f2bf(acc[qt][1][rr] * SCALE);
        }
        qfH[qt] = *(const bf16x8*)&ps[sw_frag(c16, g)];
        #pragma unroll
        for (int rr = 0; rr < 4; ++rr) {
            int rw = 4 * g + rr;
            float q0 = acc[qt][0][rr] * SCALE;
            float q1 = acc[qt][1][rr] * SCALE;
            ps[sw_off(rw, c16)]      = f2bf(q0 - bf2f(f2bf(q0)));
            ps[sw_off(rw, 16 + c16)] = f2bf(q1 - bf2f(f2bf(q1)));
        }
        qfL[qt] = *(const bf16x8*)&ps[sw_frag(c16, g)];
    }
    __syncthreads();

    float m[16], l[16];
    #pragma unroll
    for (int i = 0; i < 16; ++i) { m[i] = -3.0e38f; l[i] = 0.f; }
    f32x4 O[4][2];
    #pragma unroll
    for (int qt = 0; qt < 4; ++qt)
        #pragma unroll
        for (int dt = 0; dt < 2; ++dt)
            #pragma unroll
            for (int rr = 0; rr < 4; ++rr) O[qt][dt][rr] = 0.f;

    f32x4 zed; zed[0] = 0.f; zed[1] = 0.f; zed[2] = 0.f; zed[3] = 0.f;

    #pragma unroll 1
    for (int kb = 0; kb < 8; ++kb) {
        int key0 = kb * 32;
        bf16x8 kfH[2], kfL[2], vf[2];
        #pragma unroll
        for (int kt = 0; kt < 2; ++kt) {
            int krow = key0 + 16 * kt + c16;
            kfH[kt] = *(const bf16x8*)&kHs[sw_frag(krow, g)];
            kfL[kt] = *(const bf16x8*)&kLs[sw_frag(krow, g)];
        }
        #pragma unroll
        for (int dt = 0; dt < 2; ++dt)
            vf[dt] = *(const bf16x8*)&vtH[vt_off(16 * dt + c16, key0 + 8 * g)];

        #pragma unroll
        for (int qt = 0; qt < 4; ++qt) {
            f32x4 s0 = mfma16(qfH[qt], kfH[0], zed);
            s0 = mfma16(qfH[qt], kfL[0], s0);
            s0 = mfma16(qfL[qt], kfH[0], s0);
            f32x4 s1 = mfma16(qfH[qt], kfH[1], zed);
            s1 = mfma16(qfH[qt], kfL[1], s1);
            s1 = mfma16(qfL[qt], kfH[1], s1);

            #pragma unroll
            for (int rr = 0; rr < 4; ++rr) {
                float mx = fmaxf(s0[rr], s1[rr]);
                mx = fmaxf(mx, __shfl_xor(mx, 1));
                mx = fmaxf(mx, __shfl_xor(mx, 2));
                mx = fmaxf(mx, __shfl_xor(mx, 4));
                mx = fmaxf(mx, __shfl_xor(mx, 8));
                const int idx = qt * 4 + rr;
                float mo = m[idx];
                float mn = fmaxf(mo, mx);
                float al = __expf(fmaxf(mo - mn, -87.f));
                float p0 = __expf(s0[rr] - mn);
                float p1 = __expf(s1[rr] - mn);
                l[idx] = l[idx] * al + p0 + p1;
                m[idx] = mn;
                O[qt][0][rr] *= al;
                O[qt][1][rr] *= al;
                int rw = 4 * g + rr;
                ps[sw_off(rw, c16)]      = f2bf(p0);
                ps[sw_off(rw, 16 + c16)] = f2bf(p1);
            }
            bf16x8 pf2 = *(const bf16x8*)&ps[sw_frag(c16, g)];
            O[qt][0] = mfma16(pf2, vf[0], O[qt][0]);
            O[qt][1] = mfma16(pf2, vf[1], O[qt][1]);
        }
    }

    #pragma unroll
    for (int i = 0; i < 16; ++i) {
        float s = l[i];
        s += __shfl_xor(s, 1);
        s += __shfl_xor(s, 2);
        s += __shfl_xor(s, 4);
        s += __shfl_xor(s, 8);
        l[i] = s;
    }

    #pragma unroll
    for (int qt = 0; qt < 4; ++qt) {
        #pragma unroll
        for (int rr = 0; rr < 4; ++rr) {
            float rlv = 1.f / l[qt * 4 + rr];
            int grow = (r << 8) + (w << 6) + (qt << 4) + 4 * g + rr;
            size_t base = ((size_t)grow << 7) + (h << 5);
            if constexpr (F32) {
                float* po = (float*)out + base;
                po[c16]      = O[qt][0][rr] * rlv;
                po[16 + c16] = O[qt][1][rr] * rlv;
            } else {
                ush* po = (ush*)out + base;
                po[c16]      = f2bf(O[qt][0][rr] * rlv);
                po[16 + c16] = f2bf(O[qt][1][rr] * rlv);
            }
        }
    }
}

// ---------------- proj_mfma2: out = z + out @ w_proj + b_proj (in-place MFMA) ----------------
// grid 1024 (64 tokens each), block 256 (4 waves x 16 tokens, per-wave disjoint).
template<bool F32>
__global__ __launch_bounds__(256) void proj_mfma2(
    const void* __restrict__ z, const void* __restrict__ b_proj,
    const ush* __restrict__ wpH, const ush* __restrict__ wpL,
    void* __restrict__ out)
{
    if (sniff_is_f32((const unsigned int*)z) != F32) return;

    const int t    = threadIdx.x;
    const int lane = t & 63;
    const int w    = t >> 6;
    const int g    = lane >> 4;
    const int c16  = lane & 15;
    const int tok0 = blockIdx.x * 64 + w * 16;

    f32x4 acc[8];
    #pragma unroll
    for (int at = 0; at < 8; ++at)
        #pragma unroll
        for (int rr = 0; rr < 4; ++rr) acc[at][rr] = 0.f;

    #pragma unroll 1
    for (int kc = 0; kc < 4; ++kc) {
        const int token = tok0 + c16;
        float av[8];
        ld8<F32>(elptr<F32>((const void*)out, (size_t)token * 128 + kc * 32 + 8 * g), 0, av);
        union { ush s[8]; bf16x8 v; } hU, lU;
        #pragma unroll
        for (int j = 0; j < 8; ++j) splitf(av[j], hU.s[j], lU.s[j]);
        const bf16x8 btH = hU.v;
        const bf16x8 btL = lU.v;

        #pragma unroll
        for (int at = 0; at < 8; ++at) {
            const size_t wrow = (size_t)(at * 16 + c16) * 128 + kc * 32 + 8 * g;
            bf16x8 awH = *(const bf16x8*)&wpH[wrow];
            acc[at] = mfma16(awH, btH, acc[at]);
            if constexpr (F32) {
                bf16x8 awL = *(const bf16x8*)&wpL[wrow];
                acc[at] = mfma16(awH, btL, acc[at]);
                acc[at] = mfma16(awL, btH, acc[at]);
            }
        }
    }

    #pragma unroll
    for (int at = 0; at < 8; ++at) {
        const int c0 = at * 16 + 4 * g;
        float bp[4];
        #pragma unroll
        for (int rr = 0; rr < 4; ++rr) bp[rr] = ldel<F32>(b_proj, c0 + rr);
        const int n = tok0 + c16;
        const size_t ob = (size_t)n * 128 + c0;
        if constexpr (F32) {
            const float4 zv = *(const float4*)((const float*)z + ob);
            float4 o;
            o.x = acc[at][0] + bp[0] + zv.x;
            o.y = acc[at][1] + bp[1] + zv.y;
            o.z = acc[at][2] + bp[2] + zv.z;
            o.w = acc[at][3] + bp[3] + zv.w;
            *(float4*)((float*)out + ob) = o;
        } else {
            const uint2 zu = *(const uint2*)((const ush*)z + ob);
            float v0 = acc[at][0] + bp[0] + bflo(zu.x);
            float v1 = acc[at][1] + bp[1] + bfhi(zu.x);
            float v2 = acc[at][2] + bp[2] + bflo(zu.y);
            float v3 = acc[at][3] + bp[3] + bfhi(zu.y);
            uint2 u;
            u.x = (unsigned int)f2bf(v0) | ((unsigned int)f2bf(v1) << 16);
            u.y = (unsigned int)f2bf(v2) | ((unsigned int)f2bf(v3) << 16);
            *(uint2*)((ush*)out + ob) = u;
        }
    }
}

// ======================================================================
// ============   FALLBACK (ws too small): round-1 kernels   ============
// ======================================================================
template<bool F32>
__global__ __launch_bounds__(256) void attn_mfma(
    const void* __restrict__ z, const void* __restrict__ ln_g, const void* __restrict__ ln_b,
    const void* __restrict__ w_qkv, const void* __restrict__ b_qkv, void* __restrict__ out)
{
    if (sniff_is_f32((const unsigned int*)z) != F32) return;

    __shared__ __align__(16) unsigned char smem[53248];
    ush* znH  = (ush*)smem;
    ush* znL  = (ush*)(smem + 16384);
    ush* wtH  = (ush*)(smem + 32768);
    ush* wtL  = (ush*)(smem + 38912);
    float* biasm = (float*)(smem + 45056);
    ush* kHs  = znH;
    ush* kLs  = znL;
    ush* vtH  = (ush*)(smem + 32768);

    const int t    = threadIdx.x;
    const int lane = t & 63;
    const int w    = t >> 6;
    const int g    = lane >> 4;
    const int c16  = lane & 15;
    const int r    = blockIdx.x >> 2;
    const int h    = blockIdx.x & 3;
    ush* ps = (ush*)(smem + 49152) + (w << 9);

    if (t < 96) {
        int gc = ((t >> 5) << 7) + (h << 5) + (t & 31);
        float b0 = 0.f, b1 = 0.f;
        #pragma unroll 8
        for (int k = 0; k < 128; k += 2) {
            b0 += ldel<F32>(ln_b, k)     * ldel<F32>(w_qkv, k * 384 + gc);
            b1 += ldel<F32>(ln_b, k + 1) * ldel<F32>(w_qkv, (k + 1) * 384 + gc);
        }
        biasm[t] = ldel<F32>(b_qkv, gc) + b0 + b1;
    }

    const void* zrow = elptr<F32>(z, ((size_t)r * 256 + t) << 7);
    float sum = 0.f, sumsq = 0.f;
    #pragma unroll 1
    for (int i = 0; i < 16; ++i) {
        float v[8]; ld8<F32>(zrow, i, v);
        #pragma unroll
        for (int j = 0; j < 8; ++j) { sum += v[j]; sumsq += v[j] * v[j]; }
    }
    const float mu   = sum * (1.f / 128.f);
    const float rsig = 1.0f / sqrtf(sumsq * (1.f / 128.f) - mu * mu + 1e-5f);
    const float nb   = -mu * rsig;

    __syncthreads();

    float bv[6];
    #pragma unroll
    for (int ct = 0; ct < 6; ++ct) bv[ct] = biasm[ct * 16 + c16];

    f32x4 acc[4][6];
    #pragma unroll
    for (int qt = 0; qt < 4; ++qt)
        #pragma unroll
        for (int ct = 0; ct < 6; ++ct)
            #pragma unroll
            for (int rr = 0; rr < 4; ++rr) acc[qt][ct][rr] = 0.f;

    #pragma unroll 1
    for (int kc = 0; kc < 4; ++kc) {
        {
            float vv[8];
            #pragma unroll
            for (int i8 = 0; i8 < 4; ++i8) {
                ld8<F32>(zrow, kc * 4 + i8, vv);
                union { ush s[8]; uint4 v4; } uh, ul;
                #pragma unroll
                for (int j = 0; j < 8; ++j) {
                    float zh = fmaf(vv[j], rsig, nb);
                    splitf(zh, uh.s[j], ul.s[j]);
                }
                int b2 = sw_frag(t, i8);
                *(uint4*)&znH[b2] = uh.v4;
                *(uint4*)&znL[b2] = ul.v4;
            }
        }
        for (int idx = t; idx < 3072; idx += 256) {
            int c  = idx % 96;
            int kl = idx / 96;
            int kk = kc * 32 + kl;
            int gc = ((c >> 5) << 7) + (h << 5) + (c & 31);
            float wv = ldel<F32>(ln_g, kk) * ldel<F32>(w_qkv, kk * 384 + gc);
            ush hh, ll; splitf(wv, hh, ll);
            int o = sw_off(c, kl);
            wtH[o] = hh; wtL[o] = ll;
        }
        __syncthreads();

        bf16x8 bH[6], bL[6];
        #pragma unroll
        for (int ct = 0; ct < 6; ++ct) {
            int brow = ct * 16 + c16;
            bH[ct] = *(const bf16x8*)&wtH[sw_frag(brow, g)];
            bL[ct] = *(const bf16x8*)&wtL[sw_frag(brow, g)];
        }
        #pragma unroll
        for (int qt = 0; qt < 4; ++qt) {
            int arow = (w << 6) + (qt << 4) + c16;
            bf16x8 aHf = *(const bf16x8*)&znH[sw_frag(arow, g)];
            bf16x8 aLf = *(const bf16x8*)&znL[sw_frag(arow, g)];
            #pragma unroll
            for (int ct = 0; ct < 6; ++ct) {
                acc[qt][ct] = mfma16(aHf, bH[ct], acc[qt][ct]);
                acc[qt][ct] = mfma16(aHf, bL[ct], acc[qt][ct]);
                acc[qt][ct] = mfma16(aLf, bH[ct], acc[qt][ct]);
            }
        }
        __syncthreads();
    }

    #pragma unroll
    for (int qt = 0; qt < 4; ++qt)
        #pragma unroll
        for (int ct = 0; ct < 6; ++ct)
            #pragma unroll
            for (int rr = 0; rr < 4; ++rr) acc[qt][ct][rr] += bv[ct];

    #pragma unroll
    for (int qt = 0; qt < 4; ++qt) {
        #pragma unroll
        for (int rr = 0; rr < 4; ++rr) {
            int key = (w << 6) + (qt << 4) + 4 * g + rr;
            ush hh, ll;
            splitf(acc[qt][2][rr], hh, ll);
            kHs[sw_off(key, c16)]      = hh; kLs[sw_off(key, c16)]      = ll;
            splitf(acc[qt][3][rr], hh, ll);
            kHs[sw_off(key, 16 + c16)] = hh; kLs[sw_off(key, 16 + c16)] = ll;
            vtH[vt_off(c16,      key)] = f2bf(acc[qt][4][rr]);
            vtH[vt_off(16 + c16, key)] = f2bf(acc[qt][5][rr]);
        }
    }

    const float SCALE = 0.17677669529663689f;
    bf16x8 qfH[4], qfL[4];
    #pragma unroll
    for (int qt = 0; qt < 4; ++qt) {
        #pragma unroll
        for (int rr = 0; rr < 4; ++rr) {
            int rw = 4 * g + rr;
            ps[sw_off(rw, c16)]      = f2bf(acc[qt][0][rr] * SCALE);
            ps[sw_off(rw, 16 + c16)] = f2bf(acc[qt][1][rr] * SCALE);
        }
        qfH[qt] = *(const bf16x8*)&ps[sw_frag(c16, g)];
        #pragma unroll
        for (int rr = 0; rr < 4; ++rr) {
            int rw = 4 * g + rr;
            float q0 = acc[qt][0][rr] * SCALE;
            float q1 = acc[qt][1][rr] * SCALE;
            ps[sw_off(rw, c16)]      = f2bf(q0 - bf2f(f2bf(q0)));
            ps[sw_off(rw, 16 + c16)] = f2bf(q1 - bf2f(f2bf(q1)));
        }
        qfL[qt] = *(const bf16x8*)&ps[sw_frag(c16, g)];
    }
    __syncthreads();

    float m[16], l[16];
    #pragma unroll
    for (int i = 0; i < 16; ++i) { m[i] = -3.0e38f; l[i] = 0.f; }
    f32x4 O[4][2];
    #pragma unroll
    for (int qt = 0; qt < 4; ++qt)
        #pragma unroll
        for (int dt = 0; dt < 2; ++dt)
            #pragma unroll
            for (int rr = 0; rr < 4; ++rr) O[qt][dt][rr] = 0.f;

    f32x4 zed; zed[0] = 0.f; zed[1] = 0.f; zed[2] = 0.f; zed[3] = 0.f;

    #pragma unroll 1
    for (int kb = 0; kb < 8; ++kb) {
        int key0 = kb * 32;
        bf16x8 kfH[2], kfL[2], vf[2];
        #pragma unroll
        for (int kt = 0; kt < 2; ++kt) {
            int krow = key0 + 16 * kt + c16;
            kfH[kt] = *(const bf16x8*)&kHs[sw_frag(krow, g)];
            kfL[kt] = *(const bf16x8*)&kLs[sw_frag(krow, g)];
        }
        #pragma unroll
        for (int dt = 0; dt < 2; ++dt)
            vf[dt] = *(const bf16x8*)&vtH[vt_off(16 * dt + c16, key0 + 8 * g)];

        #pragma unroll
        for (int qt = 0; qt < 4; ++qt) {
            f32x4 s0 = mfma16(qfH[qt], kfH[0], zed);
            s0 = mfma16(qfH[qt], kfL[0], s0);
            s0 = mfma16(qfL[qt], kfH[0], s0);
            f32x4 s1 = mfma16(qfH[qt], kfH[1], zed);
            s1 = mfma16(qfH[qt], kfL[1], s1);
            s1 = mfma16(qfL[qt], kfH[1], s1);

            #pragma unroll
            for (int rr = 0; rr < 4; ++rr) {
                float mx = fmaxf(s0[rr], s1[rr]);
                mx = fmaxf(mx, __shfl_xor(mx, 1));
                mx = fmaxf(mx, __shfl_xor(mx, 2));
                mx = fmaxf(mx, __shfl_xor(mx, 4));
                mx = fmaxf(mx, __shfl_xor(mx, 8));
                const int idx = qt * 4 + rr;
                float mo = m[idx];
                float mn = fmaxf(mo, mx);
                float al = __expf(fmaxf(mo - mn, -87.f));
                float p0 = __expf(s0[rr] - mn);
                float p1 = __expf(s1[rr] - mn);
                l[idx] = l[idx] * al + p0 + p1;
                m[idx] = mn;
                O[qt][0][rr] *= al;
                O[qt][1][rr] *= al;
                int rw = 4 * g + rr;
                ps[sw_off(rw, c16)]      = f2bf(p0);
                ps[sw_off(rw, 16 + c16)] = f2bf(p1);
            }
            bf16x8 pf = *(const bf16x8*)&ps[sw_frag(c16, g)];
            O[qt][0] = mfma16(pf, vf[0], O[qt][0]);
            O[qt][1] = mfma16(pf, vf[1], O[qt][1]);
        }
    }

    #pragma unroll
    for (int i = 0; i < 16; ++i) {
        float s = l[i];
        s += __shfl_xor(s, 1);
        s += __shfl_xor(s, 2);
        s += __shfl_xor(s, 4);
        s += __shfl_xor(s, 8);
        l[i] = s;
    }

    #pragma unroll
    for (int qt = 0; qt < 4; ++qt) {
        #pragma unroll
        for (int rr = 0; rr < 4; ++rr) {
            float rlv = 1.f / l[qt * 4 + rr];
            int grow = (r << 8) + (w << 6) + (qt << 4) + 4 * g + rr;
            size_t base = ((size_t)grow << 7) + (h << 5);
            if constexpr (F32) {
                float* po = (float*)out + base;
                po[c16]      = O[qt][0][rr] * rlv;
                po[16 + c16] = O[qt][1][rr] * rlv;
            } else {
                ush* po = (ush*)out + base;
                po[c16]      = f2bf(O[qt][0][rr] * rlv);
                po[16 + c16] = f2bf(O[qt][1][rr] * rlv);
            }
        }
    }
}

template<bool F32>
__global__ __launch_bounds__(256) void proj_res(
    const void* __restrict__ z, const void* __restrict__ w_proj, const void* __restrict__ b_proj,
    void* __restrict__ out)
{
    if (sniff_is_f32((const unsigned int*)z) != F32) return;

    __shared__ unsigned int wu[8192];
    __shared__ float aT[128][20];

    const int t = threadIdx.x;
    const size_t row0 = (size_t)blockIdx.x * 16;

    if constexpr (!F32) {
        for (int idx = t; idx < 8192; idx += 256)
            wu[idx] = ((const unsigned int*)w_proj)[idx];
    }

    {
        const int rr = t >> 4;
        const int i8 = t & 15;
        float v[8];
        ld8<F32>(elptr<F32>((const void*)out, (row0 + rr) * 128), i8, v);
        #pragma unroll
        for (int j = 0; j < 8; ++j) aT[(i8 << 3) + j][rr] = v[j];
    }
    __syncthreads();

    const int c = t & 127;
    const int half = t >> 7;
    float acc8[8];
    const float bp = ldel<F32>(b_proj, c);
    #pragma unroll
    for (int rr = 0; rr < 8; ++rr) acc8[rr] = bp;

    #pragma unroll 1
    for (int k = 0; k < 128; ++k) {
        float wk;
        if constexpr (F32) {
            wk = ((const float*)w_proj)[k * 128 + c];
        } else {
            unsigned int u = wu[(k << 6) + (c >> 1)];
            wk = (c & 1) ? bfhi(u) : bflo(u);
        }
        const float4 a0 = *(const float4*)&aT[k][half * 8];
        const float4 a1 = *(const float4*)&aT[k][half * 8 + 4];
        acc8[0] = fmaf(a0.x, wk, acc8[0]);
        acc8[1] = fmaf(a0.y, wk, acc8[1]);
        acc8[2] = fmaf(a0.z, wk, acc8[2]);
        acc8[3] = fmaf(a0.w, wk, acc8[3]);
        acc8[4] = fmaf(a1.x, wk, acc8[4]);
        acc8[5] = fmaf(a1.y, wk, acc8[5]);
        acc8[6] = fmaf(a1.z, wk, acc8[6]);
        acc8[7] = fmaf(a1.w, wk, acc8[7]);
    }
    __syncthreads();
    float* ot = (float*)aT;
    #pragma unroll
    for (int rr = 0; rr < 8; ++rr)
        ot[(half * 8 + rr) * 128 + c] = acc8[rr];
    __syncthreads();

    {
        const int rr = t >> 4;
        const int i8 = t & 15;
        float zv[8], v[8];
        ld8<F32>(elptr<F32>(z, (row0 + rr) * 128), i8, zv);
        const float* po = &ot[rr * 128 + (i8 << 3)];
        #pragma unroll
        for (int j = 0; j < 8; ++j) v[j] = po[j] + zv[j];
        st8<F32>(elptrw<F32>(out, (row0 + rr) * 128), i8, v);
    }
}

extern "C" void kernel_launch(void* const* d_in, const int* in_sizes, int n_in,
                              void* d_out, int out_size, void* d_ws, size_t ws_size,
                              hipStream_t stream) {
    const void* z      = d_in[0];
    const void* ln_g   = d_in[1];
    const void* ln_b   = d_in[2];
    const void* w_qkv  = d_in[3];
    const void* b_qkv  = d_in[4];
    const void* w_proj = d_in[5];
    const void* b_proj = d_in[6];
    void* out = d_out;

    if (ws_size >= WS_NEED && d_ws != nullptr) {
        unsigned char* W = (unsigned char*)d_ws;
        ush*   wqSH  = (ush*)(W + 0);
        ush*   wqSL  = (ush*)(W + 98304);
        ush*   wpH   = (ush*)(W + 196608);
        ush*   wpL   = (ush*)(W + 229376);
        float* biasG = (float*)(W + 262144);
        float* csumG = (float*)(W + 263680);

        prep_w<false><<<96, 256, 0, stream>>>(z, ln_g, ln_b, w_qkv, b_qkv, w_proj, wqSH, wqSL, wpH, wpL, biasG, csumG);
        prep_w<true ><<<96, 256, 0, stream>>>(z, ln_g, ln_b, w_qkv, b_qkv, w_proj, wqSH, wqSL, wpH, wpL, biasG, csumG);
        attn_mfma3<false><<<1024, 256, 0, stream>>>(z, wqSH, wqSL, biasG, csumG, out);
        attn_mfma3<true ><<<1024, 256, 0, stream>>>(z, wqSH, wqSL, biasG, csumG, out);
        proj_mfma2<false><<<1024, 256, 0, stream>>>(z, b_proj, wpH, wpL, out);
        proj_mfma2<true ><<<1024, 256, 0, stream>>>(z, b_proj, wpH, wpL, out);
    } else {
        attn_mfma<false><<<1024, 256, 0, stream>>>(z, ln_g, ln_b, w_qkv, b_qkv, out);
        attn_mfma<true ><<<1024, 256, 0, stream>>>(z, ln_g, ln_b, w_qkv, b_qkv, out);
        proj_res<false><<<4096, 256, 0, stream>>>(z, w_proj, b_proj, out);
        proj_res<true ><<<4096, 256, 0, stream>>>(z, w_proj, b_proj, out);
    }
}

// Round 11
// 247.066 us; speedup vs baseline: 1.2607x; 1.1389x over previous
//
#include <hip/hip_runtime.h>
#include <hip/hip_bf16.h>

// PairwiseAttention: z(1,256,256,128) -> LN -> QKV -> 4-head attn (over 2nd L axis)
// -> proj + residual.  Runtime dtype sniff (fp32 vs bf16).
//
// Round N+10: BUGFIX of the 8-wave attn (round-10 absmax 1.35): per-wave ps
// scratch stride was (w<<10) in USH units = 2KB/wave -> waves 4..7 ran their
// Q/P bounce OUT OF BOUNDS of smem[57344]. Correct stride is (w<<9) = 512 ush
// = 1KB/wave (16 rows x 32 cols bf16), 8 waves = 8KB = bytes 49152..57344.
// No other change vs round 10:
//   attn_mfma4 : 512-thread/8-wave folded-LN attn (occupancy fix: round-9
//                counters showed 1 wave/SIMD, all dependency chains exposed).
//   prep_w     : unchanged. proj_mfma2: unchanged.
// Fallback to round-1 attn_mfma + proj_res when ws is too small.

using ush = unsigned short;

__device__ __forceinline__ float bflo(unsigned int u) { return __uint_as_float(u << 16); }
__device__ __forceinline__ float bfhi(unsigned int u) { return __uint_as_float(u & 0xffff0000u); }
__device__ __forceinline__ float bf2f(unsigned short u) { return __uint_as_float(((unsigned int)u) << 16); }
__device__ __forceinline__ unsigned short f2bf(float f) {
    unsigned int i = __float_as_uint(f);
    i += 0x7fffu + ((i >> 16) & 1u);           // round-to-nearest-even
    return (unsigned short)(i >> 16);
}
__device__ __forceinline__ void splitf(float x, unsigned short& h, unsigned short& l) {
    h = f2bf(x);
    l = f2bf(x - bf2f(h));
}

__device__ bool sniff_is_f32(const unsigned int* z) {
    int n = 0;
    for (int i = 0; i < 64; ++i) {
        float a = fabsf(bflo(z[i]));
        n += (int)(a > 1e4f) | (int)(a > 0.f && a < 1e-6f);
    }
    return n > 16;
}

template<bool F32> __device__ __forceinline__ float ldel(const void* p, int i) {
    if constexpr (F32) return ((const float*)p)[i];
    else               return bf2f(((const unsigned short*)p)[i]);
}
template<bool F32> __device__ __forceinline__ void ld8(const void* p, int i8, float* v) {
    if constexpr (F32) {
        const float4* q = (const float4*)p;
        float4 a = q[2 * i8], b = q[2 * i8 + 1];
        v[0]=a.x; v[1]=a.y; v[2]=a.z; v[3]=a.w; v[4]=b.x; v[5]=b.y; v[6]=b.z; v[7]=b.w;
    } else {
        uint4 u = ((const uint4*)p)[i8];
        const unsigned int* pu = (const unsigned int*)&u;
        #pragma unroll
        for (int j = 0; j < 4; ++j) { v[2*j] = bflo(pu[j]); v[2*j+1] = bfhi(pu[j]); }
    }
}
template<bool F32> __device__ __forceinline__ void st8(void* p, int i8, const float* v) {
    if constexpr (F32) {
        float4 a, b;
        a.x=v[0]; a.y=v[1]; a.z=v[2]; a.w=v[3];
        b.x=v[4]; b.y=v[5]; b.z=v[6]; b.w=v[7];
        ((float4*)p)[2 * i8] = a; ((float4*)p)[2 * i8 + 1] = b;
    } else {
        uint4 u; unsigned int* pu = (unsigned int*)&u;
        #pragma unroll
        for (int j = 0; j < 4; ++j)
            pu[j] = (unsigned int)f2bf(v[2*j]) | ((unsigned int)f2bf(v[2*j+1]) << 16);
        ((uint4*)p)[i8] = u;
    }
}
template<bool F32> __device__ __forceinline__ const void* elptr(const void* p, size_t off) {
    if constexpr (F32) return (const void*)((const float*)p + off);
    else               return (const void*)((const unsigned short*)p + off);
}
template<bool F32> __device__ __forceinline__ void* elptrw(void* p, size_t off) {
    if constexpr (F32) return (void*)((float*)p + off);
    else               return (void*)((unsigned short*)p + off);
}

// ---------------- MFMA plumbing ----------------
using bf16x8 = __attribute__((ext_vector_type(8))) short;   // 8 bf16 bits, 4 VGPR
using f32x4  = __attribute__((ext_vector_type(4))) float;

__device__ __forceinline__ f32x4 mfma16(bf16x8 a, bf16x8 b, f32x4 c) {
    return __builtin_amdgcn_mfma_f32_16x16x32_bf16(a, b, c, 0, 0, 0);
}

// [R][32]-bf16 LDS matrices with XOR-granule swizzle (verified round-1):
// sw_frag(row,g)+e == sw_off(row, 8*g+e)  (slot consistency across A and B).
__device__ __forceinline__ int sw_off (int row, int k) {
    return row * 32 + ((((k >> 3) ^ (row >> 1)) & 3) << 3) + (k & 7);
}
__device__ __forceinline__ int sw_frag(int row, int g) {
    return row * 32 + (((g ^ (row >> 1)) & 3) << 3);
}
// Vt: [32 dims][256 keys] bf16, XOR key-granule by (dim&7).
__device__ __forceinline__ int vt_off(int dim, int key) {
    return dim * 256 + (key ^ ((dim & 7) << 3));
}

// ws layout (bytes):
//   wqSH 0       (98304)   swizzled w' hi images: [(h*4+kc)*3072 + sw_off(c,kl)]
//   wqSL 98304   (98304)
//   wpH  196608  (32768)   w_proj^T hi: [c*128+k]
//   wpL  229376  (32768)
//   biasG 262144 (1536)    float[4][96]
//   csumG 263680 (1536)    float[4][96]: sum_k g[k]*W[k][gc]
#define WS_NEED 265216ull

// ---------------- prep_w: weight preprocessing, once (grid 96 x 256) ----------------
template<bool F32>
__global__ __launch_bounds__(256) void prep_w(
    const void* __restrict__ z, const void* __restrict__ ln_g, const void* __restrict__ ln_b,
    const void* __restrict__ w_qkv, const void* __restrict__ b_qkv, const void* __restrict__ w_proj,
    ush* __restrict__ wqSH, ush* __restrict__ wqSL,
    ush* __restrict__ wpH, ush* __restrict__ wpL,
    float* __restrict__ biasG, float* __restrict__ csumG)
{
    if (sniff_is_f32((const unsigned int*)z) != F32) return;
    const int gid = blockIdx.x * 256 + threadIdx.x;
    const int NT  = 96 * 256;

    // swizzled g.*W_qkv images: e = (h*4+kc)*3072 + c*32 + kl
    for (int e = gid; e < 49152; e += NT) {
        int kl = e & 31;
        int c  = (e >> 5) % 96;
        int hk = e / 3072;            // h*4+kc
        int h  = hk >> 2, kc = hk & 3;
        int k  = kc * 32 + kl;
        int gc = ((c >> 5) << 7) + (h << 5) + (c & 31);
        float wv = ldel<F32>(ln_g, k) * ldel<F32>(w_qkv, k * 384 + gc);
        ush hh, ll; splitf(wv, hh, ll);
        int o = hk * 3072 + sw_off(c, kl);
        wqSH[o] = hh; wqSL[o] = ll;
    }
    // w_proj transposed hi/lo: wp[c*128+k] = w_proj[k][c]
    for (int e = gid; e < 16384; e += NT) {
        int c = e >> 7, k = e & 127;
        float v = ldel<F32>(w_proj, k * 128 + c);
        ush hh, ll; splitf(v, hh, ll);
        wpH[e] = hh; wpL[e] = ll;
    }
    // bias[pair] = b_qkv[gc] + sum_k ln_b[k]*W[k][gc]
    // csum[pair] =             sum_k ln_g[k]*W[k][gc]   (wave-parallel dual reduce)
    if (gid < 384 * 64) {
        const int pair = gid >> 6;
        const int lane = gid & 63;
        const int h = pair / 96, c = pair % 96;
        const int gc = ((c >> 5) << 7) + (h << 5) + (c & 31);
        const float w0 = ldel<F32>(w_qkv, lane * 384 + gc);
        const float w1 = ldel<F32>(w_qkv, (lane + 64) * 384 + gc);
        float s  = ldel<F32>(ln_b, lane) * w0 + ldel<F32>(ln_b, lane + 64) * w1;
        float s2 = ldel<F32>(ln_g, lane) * w0 + ldel<F32>(ln_g, lane + 64) * w1;
        #pragma unroll
        for (int d = 1; d < 64; d <<= 1) { s += __shfl_xor(s, d); s2 += __shfl_xor(s2, d); }
        if (lane == 0) { biasG[pair] = ldel<F32>(b_qkv, gc) + s; csumG[pair] = s2; }
    }
}

// ---------------- attn_mfma4: 8-wave folded-LN attn ----------------
// grid = 1024, block = 512 (8 waves; wave w owns query rows w*32..w*32+31).
// Remap v2: xcd=bid&7, jj=bid>>3, r=(xcd<<5)|(jj>>2), h=jj&3 (bijection).
template<bool F32>
__global__ __launch_bounds__(512, 2) void attn_mfma4(
    const void* __restrict__ z, const ush* __restrict__ wqSH, const ush* __restrict__ wqSL,
    const float* __restrict__ biasG, const float* __restrict__ csumG, void* __restrict__ out)
{
    if (sniff_is_f32((const unsigned int*)z) != F32) return;

    // 56 KB: znH 16K | znL 16K | wtH 6K | wtL 6K | (flash: kH|kL|vtH alias) | ps 8x1KB
    __shared__ __align__(16) unsigned char smem[57344];
    ush* znH  = (ush*)smem;
    ush* znL  = (ush*)(smem + 16384);
    ush* wtH  = (ush*)(smem + 32768);
    ush* wtL  = (ush*)(smem + 38912);
    ush* kHs  = znH;
    ush* kLs  = znL;
    ush* vtH  = (ush*)(smem + 32768);

    const int t    = threadIdx.x;
    const int lane = t & 63;
    const int w    = t >> 6;           // wave 0..7
    const int g    = lane >> 4;
    const int c16  = lane & 15;
    const int xcd  = blockIdx.x & 7;
    const int jj   = blockIdx.x >> 3;
    const int r    = (xcd << 5) | (jj >> 2);
    const int h    = jj & 3;
    // FIX (round-10 bug): stride in USH units. 512 ush = 1KB per wave.
    // 8 waves x 1KB = bytes 49152..57344, exactly filling smem; vtH ends at 49152.
    ush* ps = (ush*)(smem + 49152) + (w << 9);

    // staging assignment: this thread stages half of token row srow
    const int rowl  = lane & 31;
    const int shalf = lane >> 5;                  // which 16-col half of the 32-k chunk
    const int srow  = (w << 5) | rowl;
    const void* zsrow = elptr<F32>(z, ((size_t)r * 256 + srow) << 7);

    float bv[6], cs[6];
    #pragma unroll
    for (int ct = 0; ct < 6; ++ct) {
        bv[ct] = biasG[h * 96 + ct * 16 + c16];
        cs[ct] = csumG[h * 96 + ct * 16 + c16];
    }

    f32x4 acc[2][6];
    #pragma unroll
    for (int qt = 0; qt < 2; ++qt)
        #pragma unroll
        for (int ct = 0; ct < 6; ++ct)
            #pragma unroll
            for (int rr = 0; rr < 4; ++rr) acc[qt][ct][rr] = 0.f;

    float sum = 0.f, sumsq = 0.f;

    #pragma unroll 1
    for (int kc = 0; kc < 4; ++kc) {
        if constexpr (!F32) {
            // raw z IS bf16: hi image = raw bits (exact), lo == 0 (skip).
            #pragma unroll
            for (int q8 = 0; q8 < 2; ++q8) {
                const int i8 = (shalf << 1) | q8;
                uint4 u = ((const uint4*)zsrow)[kc * 4 + i8];
                *(uint4*)&znH[sw_frag(srow, i8)] = u;
                const unsigned int* pu = (const unsigned int*)&u;
                #pragma unroll
                for (int j = 0; j < 4; ++j) {
                    float a = bflo(pu[j]), b = bfhi(pu[j]);
                    sum += a + b; sumsq += a * a + b * b;
                }
            }
        } else {
            float vv[8];
            #pragma unroll
            for (int q8 = 0; q8 < 2; ++q8) {
                const int i8 = (shalf << 1) | q8;
                ld8<F32>(zsrow, kc * 4 + i8, vv);
                union { ush s[8]; uint4 v4; } uh, ul;
                #pragma unroll
                for (int j = 0; j < 8; ++j) {
                    splitf(vv[j], uh.s[j], ul.s[j]);
                    sum += vv[j]; sumsq += vv[j] * vv[j];
                }
                int b2 = sw_frag(srow, i8);
                *(uint4*)&znH[b2] = uh.v4;
                *(uint4*)&znL[b2] = ul.v4;
            }
        }
        {   // stage w' chunk: LINEAR copy of prepped swizzled image (round-5 verified)
            const uint4* srcH = (const uint4*)(wqSH + (h * 4 + kc) * 3072);
            const uint4* srcL = (const uint4*)(wqSL + (h * 4 + kc) * 3072);
            #pragma unroll
            for (int i = t; i < 768; i += 512) {
                if (i < 384) ((uint4*)wtH)[i]       = srcH[i];
                else         ((uint4*)wtL)[i - 384] = srcL[i - 384];
            }
        }
        __syncthreads();

        bf16x8 bH[6], bL[6];
        #pragma unroll
        for (int ct = 0; ct < 6; ++ct) {
            int brow = ct * 16 + c16;
            bH[ct] = *(const bf16x8*)&wtH[sw_frag(brow, g)];
            bL[ct] = *(const bf16x8*)&wtL[sw_frag(brow, g)];
        }
        #pragma unroll
        for (int qt = 0; qt < 2; ++qt) {
            int arow = (w << 5) + (qt << 4) + c16;
            bf16x8 aHf = *(const bf16x8*)&znH[sw_frag(arow, g)];
            if constexpr (!F32) {
                #pragma unroll
                for (int ct = 0; ct < 6; ++ct) {
                    acc[qt][ct] = mfma16(aHf, bH[ct], acc[qt][ct]);
                    acc[qt][ct] = mfma16(aHf, bL[ct], acc[qt][ct]);
                }
            } else {
                bf16x8 aLf = *(const bf16x8*)&znL[sw_frag(arow, g)];
                #pragma unroll
                for (int ct = 0; ct < 6; ++ct) {
                    acc[qt][ct] = mfma16(aHf, bH[ct], acc[qt][ct]);
                    acc[qt][ct] = mfma16(aHf, bL[ct], acc[qt][ct]);
                    acc[qt][ct] = mfma16(aLf, bH[ct], acc[qt][ct]);
                }
            }
        }
        __syncthreads();
    }

    // combine half-row stats (partner lane handled the other 16 cols per chunk)
    sum   += __shfl_xor(sum, 32);
    sumsq += __shfl_xor(sumsq, 32);

    const float mu   = sum * (1.f / 128.f);
    const float rsig = 1.0f / sqrtf(sumsq * (1.f / 128.f) - mu * mu + 1e-5f);
    const float nb   = -mu * rsig;

    // wave-local rsig/nb exchange: lane l holds row (w<<5)|(l&31); lanes 0..31
    // and 32..63 store duplicates -> pf[j] (j<32) = row w*32+j.
    float* pf = (float*)ps;              // need 384B of the 1KB scratch
    pf[lane & 31] = rsig; pf[64 + (lane & 31)] = nb;
    __asm__ volatile("" ::: "memory");

    // epilogue fold: acc = rsig[row]*acc + nb[row]*csum[col] + bias[col]
    #pragma unroll
    for (int qt = 0; qt < 2; ++qt) {
        #pragma unroll
        for (int rr = 0; rr < 4; ++rr) {
            const int j = (qt << 4) + 4 * g + rr;    // row within wave stripe, 0..31
            const float rs = pf[j];
            const float nv = pf[64 + j];
            #pragma unroll
            for (int ct = 0; ct < 6; ++ct)
                acc[qt][ct][rr] = fmaf(rs, acc[qt][ct][rr], fmaf(nv, cs[ct], bv[ct]));
        }
    }
    __asm__ volatile("" ::: "memory");   // ps reused below (wave-synchronous)

    // K/V redistribute: wave w covers keys w*32..w*32+31
    #pragma unroll
    for (int qt = 0; qt < 2; ++qt) {
        #pragma unroll
        for (int rr = 0; rr < 4; ++rr) {
            int key = (w << 5) + (qt << 4) + 4 * g + rr;
            ush hh, ll;
            splitf(acc[qt][2][rr], hh, ll);
            kHs[sw_off(key, c16)]      = hh; kLs[sw_off(key, c16)]      = ll;
            splitf(acc[qt][3][rr], hh, ll);
            kHs[sw_off(key, 16 + c16)] = hh; kLs[sw_off(key, 16 + c16)] = ll;
            vtH[vt_off(c16,      key)] = f2bf(acc[qt][4][rr]);
            vtH[vt_off(16 + c16, key)] = f2bf(acc[qt][5][rr]);
        }
    }

    const float SCALE = 0.17677669529663689f;
    bf16x8 qfH[2], qfL[2];
    #pragma unroll
    for (int qt = 0; qt < 2; ++qt) {
        #pragma unroll
        for (int rr = 0; rr < 4; ++rr) {
            int rw = 4 * g + rr;
            ps[sw_off(rw, c16)]      = f2bf(acc[qt][0][rr] * SCALE);
            ps[sw_off(rw, 16 + c16)] = f2bf(acc[qt][1][rr] * SCALE);
        }
        qfH[qt] = *(const bf16x8*)&ps[sw_frag(c16, g)];
        #pragma unroll
        for (int rr = 0; rr < 4; ++rr) {
            int rw = 4 * g + rr;
            float q0 = acc[qt][0][rr] * SCALE;
            float q1 = acc[qt][1][rr] * SCALE;
            ps[sw_off(rw, c16)]      = f2bf(q0 - bf2f(f2bf(q0)));
            ps[sw_off(rw, 16 + c16)] = f2bf(q1 - bf2f(f2bf(q1)));
        }
        qfL[qt] = *(const bf16x8*)&ps[sw_frag(c16, g)];
    }
    __syncthreads();   // K/V visible to all waves

    float m[8], l[8];
    #pragma unroll
    for (int i = 0; i < 8; ++i) { m[i] = -3.0e38f; l[i] = 0.f; }
    f32x4 O[2][2];
    #pragma unroll
    for (int qt = 0; qt < 2; ++qt)
        #pragma unroll
        for (int dt = 0; dt < 2; ++dt)
            #pragma unroll
            for (int rr = 0; rr < 4; ++rr) O[qt][dt][rr] = 0.f;

    f32x4 zed; zed[0] = 0.f; zed[1] = 0.f; zed[2] = 0.f; zed[3] = 0.f;

    #pragma unroll 1
    for (int kb = 0; kb < 8; ++kb) {
        int key0 = kb * 32;
        bf16x8 kfH[2], kfL[2], vf[2];
        #pragma unroll
        for (int kt = 0; kt < 2; ++kt) {
            int krow = key0 + 16 * kt + c16;
            kfH[kt] = *(const bf16x8*)&kHs[sw_frag(krow, g)];
            kfL[kt] = *(const bf16x8*)&kLs[sw_frag(krow, g)];
        }
        #pragma unroll
        for (int dt = 0; dt < 2; ++dt)
            vf[dt] = *(const bf16x8*)&vtH[vt_off(16 * dt + c16, key0 + 8 * g)];

        #pragma unroll
        for (int qt = 0; qt < 2; ++qt) {
            f32x4 s0 = mfma16(qfH[qt], kfH[0], zed);
            s0 = mfma16(qfH[qt], kfL[0], s0);
            s0 = mfma16(qfL[qt], kfH[0], s0);
            f32x4 s1 = mfma16(qfH[qt], kfH[1], zed);
            s1 = mfma16(qfH[qt], kfL[1], s1);
            s1 = mfma16(qfL[qt], kfH[1], s1);

            #pragma unroll
            for (int rr = 0; rr < 4; ++rr) {
                float mx = fmaxf(s0[rr], s1[rr]);
                mx = fmaxf(mx, __shfl_xor(mx, 1));
                mx = fmaxf(mx, __shfl_xor(mx, 2));
                mx = fmaxf(mx, __shfl_xor(mx, 4));
                mx = fmaxf(mx, __shfl_xor(mx, 8));
                const int idx = qt * 4 + rr;
                float mo = m[idx];
                float mn = fmaxf(mo, mx);
                float al = __expf(fmaxf(mo - mn, -87.f));
                float p0 = __expf(s0[rr] - mn);
                float p1 = __expf(s1[rr] - mn);
                l[idx] = l[idx] * al + p0 + p1;
                m[idx] = mn;
                O[qt][0][rr] *= al;
                O[qt][1][rr] *= al;
                int rw = 4 * g + rr;
                ps[sw_off(rw, c16)]      = f2bf(p0);
                ps[sw_off(rw, 16 + c16)] = f2bf(p1);
            }
            bf16x8 pf2 = *(const bf16x8*)&ps[sw_frag(c16, g)];
            O[qt][0] = mfma16(pf2, vf[0], O[qt][0]);
            O[qt][1] = mfma16(pf2, vf[1], O[qt][1]);
        }
    }

    #pragma unroll
    for (int i = 0; i < 8; ++i) {
        float s = l[i];
        s += __shfl_xor(s, 1);
        s += __shfl_xor(s, 2);
        s += __shfl_xor(s, 4);
        s += __shfl_xor(s, 8);
        l[i] = s;
    }

    #pragma unroll
    for (int qt = 0; qt < 2; ++qt) {
        #pragma unroll
        for (int rr = 0; rr < 4; ++rr) {
            float rlv = 1.f / l[qt * 4 + rr];
            int grow = (r << 8) + (w << 5) + (qt << 4) + 4 * g + rr;
            size_t base = ((size_t)grow << 7) + (h << 5);
            if constexpr (F32) {
                float* po = (float*)out + base;
                po[c16]      = O[qt][0][rr] * rlv;
                po[16 + c16] = O[qt][1][rr] * rlv;
            } else {
                ush* po = (ush*)out + base;
                po[c16]      = f2bf(O[qt][0][rr] * rlv);
                po[16 + c16] = f2bf(O[qt][1][rr] * rlv);
            }
        }
    }
}

// ---------------- proj_mfma2: out = z + out @ w_proj + b_proj (in-place MFMA) ----------------
// grid 1024 (64 tokens each), block 256 (4 waves x 16 tokens, per-wave disjoint).
template<bool F32>
__global__ __launch_bounds__(256) void proj_mfma2(
    const void* __restrict__ z, const void* __restrict__ b_proj,
    const ush* __restrict__ wpH, const ush* __restrict__ wpL,
    void* __restrict__ out)
{
    if (sniff_is_f32((const unsigned int*)z) != F32) return;

    const int t    = threadIdx.x;
    const int lane = t & 63;
    const int w    = t >> 6;
    const int g    = lane >> 4;
    const int c16  = lane & 15;
    const int tok0 = blockIdx.x * 64 + w * 16;

    f32x4 acc[8];
    #pragma unroll
    for (int at = 0; at < 8; ++at)
        #pragma unroll
        for (int rr = 0; rr < 4; ++rr) acc[at][rr] = 0.f;

    #pragma unroll 1
    for (int kc = 0; kc < 4; ++kc) {
        const int token = tok0 + c16;
        float av[8];
        ld8<F32>(elptr<F32>((const void*)out, (size_t)token * 128 + kc * 32 + 8 * g), 0, av);
        union { ush s[8]; bf16x8 v; } hU, lU;
        #pragma unroll
        for (int j = 0; j < 8; ++j) splitf(av[j], hU.s[j], lU.s[j]);
        const bf16x8 btH = hU.v;
        const bf16x8 btL = lU.v;

        #pragma unroll
        for (int at = 0; at < 8; ++at) {
            const size_t wrow = (size_t)(at * 16 + c16) * 128 + kc * 32 + 8 * g;
            bf16x8 awH = *(const bf16x8*)&wpH[wrow];
            acc[at] = mfma16(awH, btH, acc[at]);
            if constexpr (F32) {
                bf16x8 awL = *(const bf16x8*)&wpL[wrow];
                acc[at] = mfma16(awH, btL, acc[at]);
                acc[at] = mfma16(awL, btH, acc[at]);
            }
        }
    }

    #pragma unroll
    for (int at = 0; at < 8; ++at) {
        const int c0 = at * 16 + 4 * g;
        float bp[4];
        #pragma unroll
        for (int rr = 0; rr < 4; ++rr) bp[rr] = ldel<F32>(b_proj, c0 + rr);
        const int n = tok0 + c16;
        const size_t ob = (size_t)n * 128 + c0;
        if constexpr (F32) {
            const float4 zv = *(const float4*)((const float*)z + ob);
            float4 o;
            o.x = acc[at][0] + bp[0] + zv.x;
            o.y = acc[at][1] + bp[1] + zv.y;
            o.z = acc[at][2] + bp[2] + zv.z;
            o.w = acc[at][3] + bp[3] + zv.w;
            *(float4*)((float*)out + ob) = o;
        } else {
            const uint2 zu = *(const uint2*)((const ush*)z + ob);
            float v0 = acc[at][0] + bp[0] + bflo(zu.x);
            float v1 = acc[at][1] + bp[1] + bfhi(zu.x);
            float v2 = acc[at][2] + bp[2] + bflo(zu.y);
            float v3 = acc[at][3] + bp[3] + bfhi(zu.y);
            uint2 u;
            u.x = (unsigned int)f2bf(v0) | ((unsigned int)f2bf(v1) << 16);
            u.y = (unsigned int)f2bf(v2) | ((unsigned int)f2bf(v3) << 16);
            *(uint2*)((ush*)out + ob) = u;
        }
    }
}

// ======================================================================
// ============   FALLBACK (ws too small): round-1 kernels   ============
// ======================================================================
template<bool F32>
__global__ __launch_bounds__(256) void attn_mfma(
    const void* __restrict__ z, const void* __restrict__ ln_g, const void* __restrict__ ln_b,
    const void* __restrict__ w_qkv, const void* __restrict__ b_qkv, void* __restrict__ out)
{
    if (sniff_is_f32((const unsigned int*)z) != F32) return;

    __shared__ __align__(16) unsigned char smem[53248];
    ush* znH  = (ush*)smem;
    ush* znL  = (ush*)(smem + 16384);
    ush* wtH  = (ush*)(smem + 32768);
    ush* wtL  = (ush*)(smem + 38912);
    float* biasm = (float*)(smem + 45056);
    ush* kHs  = znH;
    ush* kLs  = znL;
    ush* vtH  = (ush*)(smem + 32768);

    const int t    = threadIdx.x;
    const int lane = t & 63;
    const int w    = t >> 6;
    const int g    = lane >> 4;
    const int c16  = lane & 15;
    const int r    = blockIdx.x >> 2;
    const int h    = blockIdx.x & 3;
    ush* ps = (ush*)(smem + 49152) + (w << 9);

    if (t < 96) {
        int gc = ((t >> 5) << 7) + (h << 5) + (t & 31);
        float b0 = 0.f, b1 = 0.f;
        #pragma unroll 8
        for (int k = 0; k < 128; k += 2) {
            b0 += ldel<F32>(ln_b, k)     * ldel<F32>(w_qkv, k * 384 + gc);
            b1 += ldel<F32>(ln_b, k + 1) * ldel<F32>(w_qkv, (k + 1) * 384 + gc);
        }
        biasm[t] = ldel<F32>(b_qkv, gc) + b0 + b1;
    }

    const void* zrow = elptr<F32>(z, ((size_t)r * 256 + t) << 7);
    float sum = 0.f, sumsq = 0.f;
    #pragma unroll 1
    for (int i = 0; i < 16; ++i) {
        float v[8]; ld8<F32>(zrow, i, v);
        #pragma unroll
        for (int j = 0; j < 8; ++j) { sum += v[j]; sumsq += v[j] * v[j]; }
    }
    const float mu   = sum * (1.f / 128.f);
    const float rsig = 1.0f / sqrtf(sumsq * (1.f / 128.f) - mu * mu + 1e-5f);
    const float nb   = -mu * rsig;

    __syncthreads();

    float bv[6];
    #pragma unroll
    for (int ct = 0; ct < 6; ++ct) bv[ct] = biasm[ct * 16 + c16];

    f32x4 acc[4][6];
    #pragma unroll
    for (int qt = 0; qt < 4; ++qt)
        #pragma unroll
        for (int ct = 0; ct < 6; ++ct)
            #pragma unroll
            for (int rr = 0; rr < 4; ++rr) acc[qt][ct][rr] = 0.f;

    #pragma unroll 1
    for (int kc = 0; kc < 4; ++kc) {
        {
            float vv[8];
            #pragma unroll
            for (int i8 = 0; i8 < 4; ++i8) {
                ld8<F32>(zrow, kc * 4 + i8, vv);
                union { ush s[8]; uint4 v4; } uh, ul;
                #pragma unroll
                for (int j = 0; j < 8; ++j) {
                    float zh = fmaf(vv[j], rsig, nb);
                    splitf(zh, uh.s[j], ul.s[j]);
                }
                int b2 = sw_frag(t, i8);
                *(uint4*)&znH[b2] = uh.v4;
                *(uint4*)&znL[b2] = ul.v4;
            }
        }
        for (int idx = t; idx < 3072; idx += 256) {
            int c  = idx % 96;
            int kl = idx / 96;
            int kk = kc * 32 + kl;
            int gc = ((c >> 5) << 7) + (h << 5) + (c & 31);
            float wv = ldel<F32>(ln_g, kk) * ldel<F32>(w_qkv, kk * 384 + gc);
            ush hh, ll; splitf(wv, hh, ll);
            int o = sw_off(c, kl);
            wtH[o] = hh; wtL[o] = ll;
        }
        __syncthreads();

        bf16x8 bH[6], bL[6];
        #pragma unroll
        for (int ct = 0; ct < 6; ++ct) {
            int brow = ct * 16 + c16;
            bH[ct] = *(const bf16x8*)&wtH[sw_frag(brow, g)];
            bL[ct] = *(const bf16x8*)&wtL[sw_frag(brow, g)];
        }
        #pragma unroll
        for (int qt = 0; qt < 4; ++qt) {
            int arow = (w << 6) + (qt << 4) + c16;
            bf16x8 aHf = *(const bf16x8*)&znH[sw_frag(arow, g)];
            bf16x8 aLf = *(const bf16x8*)&znL[sw_frag(arow, g)];
            #pragma unroll
            for (int ct = 0; ct < 6; ++ct) {
                acc[qt][ct] = mfma16(aHf, bH[ct], acc[qt][ct]);
                acc[qt][ct] = mfma16(aHf, bL[ct], acc[qt][ct]);
                acc[qt][ct] = mfma16(aLf, bH[ct], acc[qt][ct]);
            }
        }
        __syncthreads();
    }

    #pragma unroll
    for (int qt = 0; qt < 4; ++qt)
        #pragma unroll
        for (int ct = 0; ct < 6; ++ct)
            #pragma unroll
            for (int rr = 0; rr < 4; ++rr) acc[qt][ct][rr] += bv[ct];

    #pragma unroll
    for (int qt = 0; qt < 4; ++qt) {
        #pragma unroll
        for (int rr = 0; rr < 4; ++rr) {
            int key = (w << 6) + (qt << 4) + 4 * g + rr;
            ush hh, ll;
            splitf(acc[qt][2][rr], hh, ll);
            kHs[sw_off(key, c16)]      = hh; kLs[sw_off(key, c16)]      = ll;
            splitf(acc[qt][3][rr], hh, ll);
            kHs[sw_off(key, 16 + c16)] = hh; kLs[sw_off(key, 16 + c16)] = ll;
            vtH[vt_off(c16,      key)] = f2bf(acc[qt][4][rr]);
            vtH[vt_off(16 + c16, key)] = f2bf(acc[qt][5][rr]);
        }
    }

    const float SCALE = 0.17677669529663689f;
    bf16x8 qfH[4], qfL[4];
    #pragma unroll
    for (int qt = 0; qt < 4; ++qt) {
        #pragma unroll
        for (int rr = 0; rr < 4; ++rr) {
            int rw = 4 * g + rr;
            ps[sw_off(rw, c16)]      = f2bf(acc[qt][0][rr] * SCALE);
            ps[sw_off(rw, 16 + c16)] = f2bf(acc[qt][1][rr] * SCALE);
        }
        qfH[qt] = *(const bf16x8*)&ps[sw_frag(c16, g)];
        #pragma unroll
        for (int rr = 0; rr < 4; ++rr) {
            int rw = 4 * g + rr;
            float q0 = acc[qt][0][rr] * SCALE;
            float q1 = acc[qt][1][rr] * SCALE;
            ps[sw_off(rw, c16)]      = f2bf(q0 - bf2f(f2bf(q0)));
            ps[sw_off(rw, 16 + c16)] = f2bf(q1 - bf2f(f2bf(q1)));
        }
        qfL[qt] = *(const bf16x8*)&ps[sw_frag(c16, g)];
    }
    __syncthreads();

    float m[16], l[16];
    #pragma unroll
    for (int i = 0; i < 16; ++i) { m[i] = -3.0e38f; l[i] = 0.f; }
    f32x4 O[4][2];
    #pragma unroll
    for (int qt = 0; qt < 4; ++qt)
        #pragma unroll
        for (int dt = 0; dt < 2; ++dt)
            #pragma unroll
            for (int rr = 0; rr < 4; ++rr) O[qt][dt][rr] = 0.f;

    f32x4 zed; zed[0] = 0.f; zed[1] = 0.f; zed[2] = 0.f; zed[3] = 0.f;

    #pragma unroll 1
    for (int kb = 0; kb < 8; ++kb) {
        int key0 = kb * 32;
        bf16x8 kfH[2], kfL[2], vf[2];
        #pragma unroll
        for (int kt = 0; kt < 2; ++kt) {
            int krow = key0 + 16 * kt + c16;
            kfH[kt] = *(const bf16x8*)&kHs[sw_frag(krow, g)];
            kfL[kt] = *(const bf16x8*)&kLs[sw_frag(krow, g)];
        }
        #pragma unroll
        for (int dt = 0; dt < 2; ++dt)
            vf[dt] = *(const bf16x8*)&vtH[vt_off(16 * dt + c16, key0 + 8 * g)];

        #pragma unroll
        for (int qt = 0; qt < 4; ++qt) {
            f32x4 s0 = mfma16(qfH[qt], kfH[0], zed);
            s0 = mfma16(qfH[qt], kfL[0], s0);
            s0 = mfma16(qfL[qt], kfH[0], s0);
            f32x4 s1 = mfma16(qfH[qt], kfH[1], zed);
            s1 = mfma16(qfH[qt], kfL[1], s1);
            s1 = mfma16(qfL[qt], kfH[1], s1);

            #pragma unroll
            for (int rr = 0; rr < 4; ++rr) {
                float mx = fmaxf(s0[rr], s1[rr]);
                mx = fmaxf(mx, __shfl_xor(mx, 1));
                mx = fmaxf(mx, __shfl_xor(mx, 2));
                mx = fmaxf(mx, __shfl_xor(mx, 4));
                mx = fmaxf(mx, __shfl_xor(mx, 8));
                const int idx = qt * 4 + rr;
                float mo = m[idx];
                float mn = fmaxf(mo, mx);
                float al = __expf(fmaxf(mo - mn, -87.f));
                float p0 = __expf(s0[rr] - mn);
                float p1 = __expf(s1[rr] - mn);
                l[idx] = l[idx] * al + p0 + p1;
                m[idx] = mn;
                O[qt][0][rr] *= al;
                O[qt][1][rr] *= al;
                int rw = 4 * g + rr;
                ps[sw_off(rw, c16)]      = f2bf(p0);
                ps[sw_off(rw, 16 + c16)] = f2bf(p1);
            }
            bf16x8 pf = *(const bf16x8*)&ps[sw_frag(c16, g)];
            O[qt][0] = mfma16(pf, vf[0], O[qt][0]);
            O[qt][1] = mfma16(pf, vf[1], O[qt][1]);
        }
    }

    #pragma unroll
    for (int i = 0; i < 16; ++i) {
        float s = l[i];
        s += __shfl_xor(s, 1);
        s += __shfl_xor(s, 2);
        s += __shfl_xor(s, 4);
        s += __shfl_xor(s, 8);
        l[i] = s;
    }

    #pragma unroll
    for (int qt = 0; qt < 4; ++qt) {
        #pragma unroll
        for (int rr = 0; rr < 4; ++rr) {
            float rlv = 1.f / l[qt * 4 + rr];
            int grow = (r << 8) + (w << 6) + (qt << 4) + 4 * g + rr;
            size_t base = ((size_t)grow << 7) + (h << 5);
            if constexpr (F32) {
                float* po = (float*)out + base;
                po[c16]      = O[qt][0][rr] * rlv;
                po[16 + c16] = O[qt][1][rr] * rlv;
            } else {
                ush* po = (ush*)out + base;
                po[c16]      = f2bf(O[qt][0][rr] * rlv);
                po[16 + c16] = f2bf(O[qt][1][rr] * rlv);
            }
        }
    }
}

template<bool F32>
__global__ __launch_bounds__(256) void proj_res(
    const void* __restrict__ z, const void* __restrict__ w_proj, const void* __restrict__ b_proj,
    void* __restrict__ out)
{
    if (sniff_is_f32((const unsigned int*)z) != F32) return;

    __shared__ unsigned int wu[8192];
    __shared__ float aT[128][20];

    const int t = threadIdx.x;
    const size_t row0 = (size_t)blockIdx.x * 16;

    if constexpr (!F32) {
        for (int idx = t; idx < 8192; idx += 256)
            wu[idx] = ((const unsigned int*)w_proj)[idx];
    }

    {
        const int rr = t >> 4;
        const int i8 = t & 15;
        float v[8];
        ld8<F32>(elptr<F32>((const void*)out, (row0 + rr) * 128), i8, v);
        #pragma unroll
        for (int j = 0; j < 8; ++j) aT[(i8 << 3) + j][rr] = v[j];
    }
    __syncthreads();

    const int c = t & 127;
    const int half = t >> 7;
    float acc8[8];
    const float bp = ldel<F32>(b_proj, c);
    #pragma unroll
    for (int rr = 0; rr < 8; ++rr) acc8[rr] = bp;

    #pragma unroll 1
    for (int k = 0; k < 128; ++k) {
        float wk;
        if constexpr (F32) {
            wk = ((const float*)w_proj)[k * 128 + c];
        } else {
            unsigned int u = wu[(k << 6) + (c >> 1)];
            wk = (c & 1) ? bfhi(u) : bflo(u);
        }
        const float4 a0 = *(const float4*)&aT[k][half * 8];
        const float4 a1 = *(const float4*)&aT[k][half * 8 + 4];
        acc8[0] = fmaf(a0.x, wk, acc8[0]);
        acc8[1] = fmaf(a0.y, wk, acc8[1]);
        acc8[2] = fmaf(a0.z, wk, acc8[2]);
        acc8[3] = fmaf(a0.w, wk, acc8[3]);
        acc8[4] = fmaf(a1.x, wk, acc8[4]);
        acc8[5] = fmaf(a1.y, wk, acc8[5]);
        acc8[6] = fmaf(a1.z, wk, acc8[6]);
        acc8[7] = fmaf(a1.w, wk, acc8[7]);
    }
    __syncthreads();
    float* ot = (float*)aT;
    #pragma unroll
    for (int rr = 0; rr < 8; ++rr)
        ot[(half * 8 + rr) * 128 + c] = acc8[rr];
    __syncthreads();

    {
        const int rr = t >> 4;
        const int i8 = t & 15;
        float zv[8], v[8];
        ld8<F32>(elptr<F32>(z, (row0 + rr) * 128), i8, zv);
        const float* po = &ot[rr * 128 + (i8 << 3)];
        #pragma unroll
        for (int j = 0; j < 8; ++j) v[j] = po[j] + zv[j];
        st8<F32>(elptrw<F32>(out, (row0 + rr) * 128), i8, v);
    }
}

extern "C" void kernel_launch(void* const* d_in, const int* in_sizes, int n_in,
                              void* d_out, int out_size, void* d_ws, size_t ws_size,
                              hipStream_t stream) {
    const void* z      = d_in[0];
    const void* ln_g   = d_in[1];
    const void* ln_b   = d_in[2];
    const void* w_qkv  = d_in[3];
    const void* b_qkv  = d_in[4];
    const void* w_proj = d_in[5];
    const void* b_proj = d_in[6];
    void* out = d_out;

    if (ws_size >= WS_NEED && d_ws != nullptr) {
        unsigned char* W = (unsigned char*)d_ws;
        ush*   wqSH  = (ush*)(W + 0);
        ush*   wqSL  = (ush*)(W + 98304);
        ush*   wpH   = (ush*)(W + 196608);
        ush*   wpL   = (ush*)(W + 229376);
        float* biasG = (float*)(W + 262144);
        float* csumG = (float*)(W + 263680);

        prep_w<false><<<96, 256, 0, stream>>>(z, ln_g, ln_b, w_qkv, b_qkv, w_proj, wqSH, wqSL, wpH, wpL, biasG, csumG);
        prep_w<true ><<<96, 256, 0, stream>>>(z, ln_g, ln_b, w_qkv, b_qkv, w_proj, wqSH, wqSL, wpH, wpL, biasG, csumG);
        attn_mfma4<false><<<1024, 512, 0, stream>>>(z, wqSH, wqSL, biasG, csumG, out);
        attn_mfma4<true ><<<1024, 512, 0, stream>>>(z, wqSH, wqSL, biasG, csumG, out);
        proj_mfma2<false><<<1024, 256, 0, stream>>>(z, b_proj, wpH, wpL, out);
        proj_mfma2<true ><<<1024, 256, 0, stream>>>(z, b_proj, wpH, wpL, out);
    } else {
        attn_mfma<false><<<1024, 256, 0, stream>>>(z, ln_g, ln_b, w_qkv, b_qkv, out);
        attn_mfma<true ><<<1024, 256, 0, stream>>>(z, ln_g, ln_b, w_qkv, b_qkv, out);
        proj_res<false><<<4096, 256, 0, stream>>>(z, w_proj, b_proj, out);
        proj_res<true ><<<4096, 256, 0, stream>>>(z, w_proj, b_proj, out);
    }
}

// Round 12
// 232.538 us; speedup vs baseline: 1.3395x; 1.0625x over previous
//
#include <hip/hip_runtime.h>
#include <hip/hip_bf16.h>

// PairwiseAttention: z(1,256,256,128) -> LN -> QKV -> 4-head attn (over 2nd L axis)
// -> proj + residual.  Runtime dtype sniff (fp32 vs bf16).
//
// Round N+11: SWAPPED-S FLASH. Round-11 counters: attn VALUBusy 46% (hottest
// pipe), dominated by serial softmax (16 shfls / (kb,qt)) from the
// S=mfma(Q,K) layout (keys on lanes). Swap to S^T=mfma(K,Q): fragments are
// layout-symmetric so ALL loads stay byte-identical; C flips to
// [key=4g+rr][query=c16]:
//   - chunk-max: in-lane 8-max + 2 shfls (xor16,32) instead of 16 shfls
//   - m/l scalars per qt (lane = one query); alpha lane-uniform
//   - P-bounce: 2 aligned uint2 LDS writes instead of 8 scattered ush
//   - PV: O^T = mfma(vf, pf) (same vf/pf fragments) -> output epilogue
//     vectorizes to float4 / uint2 (4 consecutive dims per lane)
// QKV phase, K/V redistribute, Q bounce, prep_w, proj_mfma2: unchanged.
// Fallback to round-1 attn_mfma + proj_res when ws is too small.

using ush = unsigned short;

__device__ __forceinline__ float bflo(unsigned int u) { return __uint_as_float(u << 16); }
__device__ __forceinline__ float bfhi(unsigned int u) { return __uint_as_float(u & 0xffff0000u); }
__device__ __forceinline__ float bf2f(unsigned short u) { return __uint_as_float(((unsigned int)u) << 16); }
__device__ __forceinline__ unsigned short f2bf(float f) {
    unsigned int i = __float_as_uint(f);
    i += 0x7fffu + ((i >> 16) & 1u);           // round-to-nearest-even
    return (unsigned short)(i >> 16);
}
__device__ __forceinline__ void splitf(float x, unsigned short& h, unsigned short& l) {
    h = f2bf(x);
    l = f2bf(x - bf2f(h));
}

__device__ bool sniff_is_f32(const unsigned int* z) {
    int n = 0;
    for (int i = 0; i < 64; ++i) {
        float a = fabsf(bflo(z[i]));
        n += (int)(a > 1e4f) | (int)(a > 0.f && a < 1e-6f);
    }
    return n > 16;
}

template<bool F32> __device__ __forceinline__ float ldel(const void* p, int i) {
    if constexpr (F32) return ((const float*)p)[i];
    else               return bf2f(((const unsigned short*)p)[i]);
}
template<bool F32> __device__ __forceinline__ void ld8(const void* p, int i8, float* v) {
    if constexpr (F32) {
        const float4* q = (const float4*)p;
        float4 a = q[2 * i8], b = q[2 * i8 + 1];
        v[0]=a.x; v[1]=a.y; v[2]=a.z; v[3]=a.w; v[4]=b.x; v[5]=b.y; v[6]=b.z; v[7]=b.w;
    } else {
        uint4 u = ((const uint4*)p)[i8];
        const unsigned int* pu = (const unsigned int*)&u;
        #pragma unroll
        for (int j = 0; j < 4; ++j) { v[2*j] = bflo(pu[j]); v[2*j+1] = bfhi(pu[j]); }
    }
}
template<bool F32> __device__ __forceinline__ void st8(void* p, int i8, const float* v) {
    if constexpr (F32) {
        float4 a, b;
        a.x=v[0]; a.y=v[1]; a.z=v[2]; a.w=v[3];
        b.x=v[4]; b.y=v[5]; b.z=v[6]; b.w=v[7];
        ((float4*)p)[2 * i8] = a; ((float4*)p)[2 * i8 + 1] = b;
    } else {
        uint4 u; unsigned int* pu = (unsigned int*)&u;
        #pragma unroll
        for (int j = 0; j < 4; ++j)
            pu[j] = (unsigned int)f2bf(v[2*j]) | ((unsigned int)f2bf(v[2*j+1]) << 16);
        ((uint4*)p)[i8] = u;
    }
}
template<bool F32> __device__ __forceinline__ const void* elptr(const void* p, size_t off) {
    if constexpr (F32) return (const void*)((const float*)p + off);
    else               return (const void*)((const unsigned short*)p + off);
}
template<bool F32> __device__ __forceinline__ void* elptrw(void* p, size_t off) {
    if constexpr (F32) return (void*)((float*)p + off);
    else               return (void*)((unsigned short*)p + off);
}

// ---------------- MFMA plumbing ----------------
using bf16x8 = __attribute__((ext_vector_type(8))) short;   // 8 bf16 bits, 4 VGPR
using f32x4  = __attribute__((ext_vector_type(4))) float;

__device__ __forceinline__ f32x4 mfma16(bf16x8 a, bf16x8 b, f32x4 c) {
    return __builtin_amdgcn_mfma_f32_16x16x32_bf16(a, b, c, 0, 0, 0);
}

// [R][32]-bf16 LDS matrices with XOR-granule swizzle (verified round-1):
// sw_frag(row,g)+e == sw_off(row, 8*g+e)  (slot consistency across A and B).
__device__ __forceinline__ int sw_off (int row, int k) {
    return row * 32 + ((((k >> 3) ^ (row >> 1)) & 3) << 3) + (k & 7);
}
__device__ __forceinline__ int sw_frag(int row, int g) {
    return row * 32 + (((g ^ (row >> 1)) & 3) << 3);
}
// Vt: [32 dims][256 keys] bf16, XOR key-granule by (dim&7).
__device__ __forceinline__ int vt_off(int dim, int key) {
    return dim * 256 + (key ^ ((dim & 7) << 3));
}

// ws layout (bytes):
//   wqSH 0       (98304)   swizzled w' hi images: [(h*4+kc)*3072 + sw_off(c,kl)]
//   wqSL 98304   (98304)
//   wpH  196608  (32768)   w_proj^T hi: [c*128+k]
//   wpL  229376  (32768)
//   biasG 262144 (1536)    float[4][96]
//   csumG 263680 (1536)    float[4][96]: sum_k g[k]*W[k][gc]
#define WS_NEED 265216ull

// ---------------- prep_w: weight preprocessing, once (grid 96 x 256) ----------------
template<bool F32>
__global__ __launch_bounds__(256) void prep_w(
    const void* __restrict__ z, const void* __restrict__ ln_g, const void* __restrict__ ln_b,
    const void* __restrict__ w_qkv, const void* __restrict__ b_qkv, const void* __restrict__ w_proj,
    ush* __restrict__ wqSH, ush* __restrict__ wqSL,
    ush* __restrict__ wpH, ush* __restrict__ wpL,
    float* __restrict__ biasG, float* __restrict__ csumG)
{
    if (sniff_is_f32((const unsigned int*)z) != F32) return;
    const int gid = blockIdx.x * 256 + threadIdx.x;
    const int NT  = 96 * 256;

    // swizzled g.*W_qkv images: e = (h*4+kc)*3072 + c*32 + kl
    for (int e = gid; e < 49152; e += NT) {
        int kl = e & 31;
        int c  = (e >> 5) % 96;
        int hk = e / 3072;            // h*4+kc
        int h  = hk >> 2, kc = hk & 3;
        int k  = kc * 32 + kl;
        int gc = ((c >> 5) << 7) + (h << 5) + (c & 31);
        float wv = ldel<F32>(ln_g, k) * ldel<F32>(w_qkv, k * 384 + gc);
        ush hh, ll; splitf(wv, hh, ll);
        int o = hk * 3072 + sw_off(c, kl);
        wqSH[o] = hh; wqSL[o] = ll;
    }
    // w_proj transposed hi/lo: wp[c*128+k] = w_proj[k][c]
    for (int e = gid; e < 16384; e += NT) {
        int c = e >> 7, k = e & 127;
        float v = ldel<F32>(w_proj, k * 128 + c);
        ush hh, ll; splitf(v, hh, ll);
        wpH[e] = hh; wpL[e] = ll;
    }
    // bias[pair] = b_qkv[gc] + sum_k ln_b[k]*W[k][gc]
    // csum[pair] =             sum_k ln_g[k]*W[k][gc]   (wave-parallel dual reduce)
    if (gid < 384 * 64) {
        const int pair = gid >> 6;
        const int lane = gid & 63;
        const int h = pair / 96, c = pair % 96;
        const int gc = ((c >> 5) << 7) + (h << 5) + (c & 31);
        const float w0 = ldel<F32>(w_qkv, lane * 384 + gc);
        const float w1 = ldel<F32>(w_qkv, (lane + 64) * 384 + gc);
        float s  = ldel<F32>(ln_b, lane) * w0 + ldel<F32>(ln_b, lane + 64) * w1;
        float s2 = ldel<F32>(ln_g, lane) * w0 + ldel<F32>(ln_g, lane + 64) * w1;
        #pragma unroll
        for (int d = 1; d < 64; d <<= 1) { s += __shfl_xor(s, d); s2 += __shfl_xor(s2, d); }
        if (lane == 0) { biasG[pair] = ldel<F32>(b_qkv, gc) + s; csumG[pair] = s2; }
    }
}

// ---------------- attn_mfma5: 8-wave folded-LN attn, swapped-S flash ----------------
// grid = 1024, block = 512 (8 waves; wave w owns query rows w*32..w*32+31).
// Remap v2: xcd=bid&7, jj=bid>>3, r=(xcd<<5)|(jj>>2), h=jj&3 (bijection).
template<bool F32>
__global__ __launch_bounds__(512, 2) void attn_mfma5(
    const void* __restrict__ z, const ush* __restrict__ wqSH, const ush* __restrict__ wqSL,
    const float* __restrict__ biasG, const float* __restrict__ csumG, void* __restrict__ out)
{
    if (sniff_is_f32((const unsigned int*)z) != F32) return;

    // 56 KB: znH 16K | znL 16K | wtH 6K | wtL 6K | (flash: kH|kL|vtH alias) | ps 8x1KB
    __shared__ __align__(16) unsigned char smem[57344];
    ush* znH  = (ush*)smem;
    ush* znL  = (ush*)(smem + 16384);
    ush* wtH  = (ush*)(smem + 32768);
    ush* wtL  = (ush*)(smem + 38912);
    ush* kHs  = znH;
    ush* kLs  = znL;
    ush* vtH  = (ush*)(smem + 32768);

    const int t    = threadIdx.x;
    const int lane = t & 63;
    const int w    = t >> 6;           // wave 0..7
    const int g    = lane >> 4;
    const int c16  = lane & 15;
    const int xcd  = blockIdx.x & 7;
    const int jj   = blockIdx.x >> 3;
    const int r    = (xcd << 5) | (jj >> 2);
    const int h    = jj & 3;
    // 512 ush = 1KB per wave; 8 waves = bytes 49152..57344 (vtH ends at 49152).
    ush* ps = (ush*)(smem + 49152) + (w << 9);

    // staging assignment: this thread stages half of token row srow
    const int rowl  = lane & 31;
    const int shalf = lane >> 5;                  // which 16-col half of the 32-k chunk
    const int srow  = (w << 5) | rowl;
    const void* zsrow = elptr<F32>(z, ((size_t)r * 256 + srow) << 7);

    float bv[6], cs[6];
    #pragma unroll
    for (int ct = 0; ct < 6; ++ct) {
        bv[ct] = biasG[h * 96 + ct * 16 + c16];
        cs[ct] = csumG[h * 96 + ct * 16 + c16];
    }

    f32x4 acc[2][6];
    #pragma unroll
    for (int qt = 0; qt < 2; ++qt)
        #pragma unroll
        for (int ct = 0; ct < 6; ++ct)
            #pragma unroll
            for (int rr = 0; rr < 4; ++rr) acc[qt][ct][rr] = 0.f;

    float sum = 0.f, sumsq = 0.f;

    #pragma unroll 1
    for (int kc = 0; kc < 4; ++kc) {
        if constexpr (!F32) {
            // raw z IS bf16: hi image = raw bits (exact), lo == 0 (skip).
            #pragma unroll
            for (int q8 = 0; q8 < 2; ++q8) {
                const int i8 = (shalf << 1) | q8;
                uint4 u = ((const uint4*)zsrow)[kc * 4 + i8];
                *(uint4*)&znH[sw_frag(srow, i8)] = u;
                const unsigned int* pu = (const unsigned int*)&u;
                #pragma unroll
                for (int j = 0; j < 4; ++j) {
                    float a = bflo(pu[j]), b = bfhi(pu[j]);
                    sum += a + b; sumsq += a * a + b * b;
                }
            }
        } else {
            float vv[8];
            #pragma unroll
            for (int q8 = 0; q8 < 2; ++q8) {
                const int i8 = (shalf << 1) | q8;
                ld8<F32>(zsrow, kc * 4 + i8, vv);
                union { ush s[8]; uint4 v4; } uh, ul;
                #pragma unroll
                for (int j = 0; j < 8; ++j) {
                    splitf(vv[j], uh.s[j], ul.s[j]);
                    sum += vv[j]; sumsq += vv[j] * vv[j];
                }
                int b2 = sw_frag(srow, i8);
                *(uint4*)&znH[b2] = uh.v4;
                *(uint4*)&znL[b2] = ul.v4;
            }
        }
        {   // stage w' chunk: LINEAR copy of prepped swizzled image (round-5 verified)
            const uint4* srcH = (const uint4*)(wqSH + (h * 4 + kc) * 3072);
            const uint4* srcL = (const uint4*)(wqSL + (h * 4 + kc) * 3072);
            #pragma unroll
            for (int i = t; i < 768; i += 512) {
                if (i < 384) ((uint4*)wtH)[i]       = srcH[i];
                else         ((uint4*)wtL)[i - 384] = srcL[i - 384];
            }
        }
        __syncthreads();

        bf16x8 bH[6], bL[6];
        #pragma unroll
        for (int ct = 0; ct < 6; ++ct) {
            int brow = ct * 16 + c16;
            bH[ct] = *(const bf16x8*)&wtH[sw_frag(brow, g)];
            bL[ct] = *(const bf16x8*)&wtL[sw_frag(brow, g)];
        }
        #pragma unroll
        for (int qt = 0; qt < 2; ++qt) {
            int arow = (w << 5) + (qt << 4) + c16;
            bf16x8 aHf = *(const bf16x8*)&znH[sw_frag(arow, g)];
            if constexpr (!F32) {
                #pragma unroll
                for (int ct = 0; ct < 6; ++ct) {
                    acc[qt][ct] = mfma16(aHf, bH[ct], acc[qt][ct]);
                    acc[qt][ct] = mfma16(aHf, bL[ct], acc[qt][ct]);
                }
            } else {
                bf16x8 aLf = *(const bf16x8*)&znL[sw_frag(arow, g)];
                #pragma unroll
                for (int ct = 0; ct < 6; ++ct) {
                    acc[qt][ct] = mfma16(aHf, bH[ct], acc[qt][ct]);
                    acc[qt][ct] = mfma16(aHf, bL[ct], acc[qt][ct]);
                    acc[qt][ct] = mfma16(aLf, bH[ct], acc[qt][ct]);
                }
            }
        }
        __syncthreads();
    }

    // combine half-row stats (partner lane handled the other 16 cols per chunk)
    sum   += __shfl_xor(sum, 32);
    sumsq += __shfl_xor(sumsq, 32);

    const float mu   = sum * (1.f / 128.f);
    const float rsig = 1.0f / sqrtf(sumsq * (1.f / 128.f) - mu * mu + 1e-5f);
    const float nb   = -mu * rsig;

    // wave-local rsig/nb exchange: lane l holds row (w<<5)|(l&31)
    float* pf0 = (float*)ps;
    pf0[lane & 31] = rsig; pf0[64 + (lane & 31)] = nb;
    __asm__ volatile("" ::: "memory");

    // epilogue fold: acc = rsig[row]*acc + nb[row]*csum[col] + bias[col]
    #pragma unroll
    for (int qt = 0; qt < 2; ++qt) {
        #pragma unroll
        for (int rr = 0; rr < 4; ++rr) {
            const int j = (qt << 4) + 4 * g + rr;    // row within wave stripe, 0..31
            const float rs = pf0[j];
            const float nv = pf0[64 + j];
            #pragma unroll
            for (int ct = 0; ct < 6; ++ct)
                acc[qt][ct][rr] = fmaf(rs, acc[qt][ct][rr], fmaf(nv, cs[ct], bv[ct]));
        }
    }
    __asm__ volatile("" ::: "memory");   // ps reused below (wave-synchronous)

    // K/V redistribute: wave w covers keys w*32..w*32+31
    #pragma unroll
    for (int qt = 0; qt < 2; ++qt) {
        #pragma unroll
        for (int rr = 0; rr < 4; ++rr) {
            int key = (w << 5) + (qt << 4) + 4 * g + rr;
            ush hh, ll;
            splitf(acc[qt][2][rr], hh, ll);
            kHs[sw_off(key, c16)]      = hh; kLs[sw_off(key, c16)]      = ll;
            splitf(acc[qt][3][rr], hh, ll);
            kHs[sw_off(key, 16 + c16)] = hh; kLs[sw_off(key, 16 + c16)] = ll;
            vtH[vt_off(c16,      key)] = f2bf(acc[qt][4][rr]);
            vtH[vt_off(16 + c16, key)] = f2bf(acc[qt][5][rr]);
        }
    }

    const float SCALE = 0.17677669529663689f;
    bf16x8 qfH[2], qfL[2];
    #pragma unroll
    for (int qt = 0; qt < 2; ++qt) {
        #pragma unroll
        for (int rr = 0; rr < 4; ++rr) {
            int rw = 4 * g + rr;
            ps[sw_off(rw, c16)]      = f2bf(acc[qt][0][rr] * SCALE);
            ps[sw_off(rw, 16 + c16)] = f2bf(acc[qt][1][rr] * SCALE);
        }
        qfH[qt] = *(const bf16x8*)&ps[sw_frag(c16, g)];
        #pragma unroll
        for (int rr = 0; rr < 4; ++rr) {
            int rw = 4 * g + rr;
            float q0 = acc[qt][0][rr] * SCALE;
            float q1 = acc[qt][1][rr] * SCALE;
            ps[sw_off(rw, c16)]      = f2bf(q0 - bf2f(f2bf(q0)));
            ps[sw_off(rw, 16 + c16)] = f2bf(q1 - bf2f(f2bf(q1)));
        }
        qfL[qt] = *(const bf16x8*)&ps[sw_frag(c16, g)];
    }
    __syncthreads();   // K/V visible to all waves

    // ---- swapped-S flash: S^T = mfma(K,Q) -> [key=4g+rr][query=c16] ----
    float m[2], l[2];
    #pragma unroll
    for (int i = 0; i < 2; ++i) { m[i] = -3.0e38f; l[i] = 0.f; }
    f32x4 O[2][2];                      // O^T frag: [dim=4g+rr (+16dt)][query=c16]
    #pragma unroll
    for (int qt = 0; qt < 2; ++qt)
        #pragma unroll
        for (int dt = 0; dt < 2; ++dt)
            #pragma unroll
            for (int rr = 0; rr < 4; ++rr) O[qt][dt][rr] = 0.f;

    f32x4 zed; zed[0] = 0.f; zed[1] = 0.f; zed[2] = 0.f; zed[3] = 0.f;

    // P-bounce write addresses (row = query c16; cols 4g..4g+3 and 16+4g..16+4g+3):
    // sw_off(c16, 4g)   = c16*32 + ((( (g>>1)   ^ (c16>>1)) & 3) << 3) + ((g&1)<<2)
    // sw_off(c16, 16+4g)= c16*32 + (((((g>>1)+2)^ (c16>>1)) & 3) << 3) + ((g&1)<<2)
    const int wr0 = c16 * 32 + (((( (g >> 1)    ) ^ (c16 >> 1)) & 3) << 3) + ((g & 1) << 2);
    const int wr1 = c16 * 32 + (((( (g >> 1) + 2) ^ (c16 >> 1)) & 3) << 3) + ((g & 1) << 2);

    #pragma unroll 1
    for (int kb = 0; kb < 8; ++kb) {
        int key0 = kb * 32;
        bf16x8 kfH[2], kfL[2], vf[2];
        #pragma unroll
        for (int kt = 0; kt < 2; ++kt) {
            int krow = key0 + 16 * kt + c16;
            kfH[kt] = *(const bf16x8*)&kHs[sw_frag(krow, g)];
            kfL[kt] = *(const bf16x8*)&kLs[sw_frag(krow, g)];
        }
        #pragma unroll
        for (int dt = 0; dt < 2; ++dt)
            vf[dt] = *(const bf16x8*)&vtH[vt_off(16 * dt + c16, key0 + 8 * g)];

        #pragma unroll
        for (int qt = 0; qt < 2; ++qt) {
            f32x4 s0 = mfma16(kfH[0], qfH[qt], zed);
            s0 = mfma16(kfH[0], qfL[qt], s0);
            s0 = mfma16(kfL[0], qfH[qt], s0);
            f32x4 s1 = mfma16(kfH[1], qfH[qt], zed);
            s1 = mfma16(kfH[1], qfL[qt], s1);
            s1 = mfma16(kfL[1], qfH[qt], s1);

            // chunk max for this query (c16): in-lane 8-max + 2 shfls across g
            float pmax = fmaxf(fmaxf(fmaxf(s0[0], s0[1]), fmaxf(s0[2], s0[3])),
                               fmaxf(fmaxf(s1[0], s1[1]), fmaxf(s1[2], s1[3])));
            pmax = fmaxf(pmax, __shfl_xor(pmax, 16));
            pmax = fmaxf(pmax, __shfl_xor(pmax, 32));

            const float mo = m[qt];
            const float mn = fmaxf(mo, pmax);
            const float al = __expf(fmaxf(mo - mn, -87.f));   // safe vs -3e38 sentinel
            float p0[4], p1[4], psum = 0.f;
            #pragma unroll
            for (int rr = 0; rr < 4; ++rr) {
                p0[rr] = __expf(s0[rr] - mn);
                p1[rr] = __expf(s1[rr] - mn);
                psum += p0[rr] + p1[rr];
            }
            l[qt] = l[qt] * al + psum;
            m[qt] = mn;
            #pragma unroll
            for (int rr = 0; rr < 4; ++rr) { O[qt][0][rr] *= al; O[qt][1][rr] *= al; }

            // P-bounce: row=query c16, 2 aligned uint2 writes (wave-synchronous)
            uint2 u01, u23;
            u01.x = (unsigned int)f2bf(p0[0]) | ((unsigned int)f2bf(p0[1]) << 16);
            u01.y = (unsigned int)f2bf(p0[2]) | ((unsigned int)f2bf(p0[3]) << 16);
            u23.x = (unsigned int)f2bf(p1[0]) | ((unsigned int)f2bf(p1[1]) << 16);
            u23.y = (unsigned int)f2bf(p1[2]) | ((unsigned int)f2bf(p1[3]) << 16);
            *(uint2*)&ps[wr0] = u01;
            *(uint2*)&ps[wr1] = u23;
            __asm__ volatile("" ::: "memory");
            bf16x8 pfr = *(const bf16x8*)&ps[sw_frag(c16, g)];
            __asm__ volatile("" ::: "memory");

            // PV: O^T = V^T(A) x P(B); vf fragment unchanged
            O[qt][0] = mfma16(vf[0], pfr, O[qt][0]);
            O[qt][1] = mfma16(vf[1], pfr, O[qt][1]);
        }
    }

    // finalize: l partials (each lane covered its 8 keys/chunk) -> sum across g
    #pragma unroll
    for (int qt = 0; qt < 2; ++qt) {
        float s = l[qt];
        s += __shfl_xor(s, 16);
        s += __shfl_xor(s, 32);
        const float rlv = 1.f / s;
        const int token = (r << 8) + (w << 5) + (qt << 4) + c16;
        #pragma unroll
        for (int dt = 0; dt < 2; ++dt) {
            const size_t ob = ((size_t)token << 7) + (h << 5) + (dt << 4) + 4 * g;
            if constexpr (F32) {
                float4 o;
                o.x = O[qt][dt][0] * rlv;
                o.y = O[qt][dt][1] * rlv;
                o.z = O[qt][dt][2] * rlv;
                o.w = O[qt][dt][3] * rlv;
                *(float4*)((float*)out + ob) = o;
            } else {
                uint2 u;
                u.x = (unsigned int)f2bf(O[qt][dt][0] * rlv) | ((unsigned int)f2bf(O[qt][dt][1] * rlv) << 16);
                u.y = (unsigned int)f2bf(O[qt][dt][2] * rlv) | ((unsigned int)f2bf(O[qt][dt][3] * rlv) << 16);
                *(uint2*)((ush*)out + ob) = u;
            }
        }
    }
}

// ---------------- proj_mfma2: out = z + out @ w_proj + b_proj (in-place MFMA) ----------------
// grid 1024 (64 tokens each), block 256 (4 waves x 16 tokens, per-wave disjoint).
template<bool F32>
__global__ __launch_bounds__(256) void proj_mfma2(
    const void* __restrict__ z, const void* __restrict__ b_proj,
    const ush* __restrict__ wpH, const ush* __restrict__ wpL,
    void* __restrict__ out)
{
    if (sniff_is_f32((const unsigned int*)z) != F32) return;

    const int t    = threadIdx.x;
    const int lane = t & 63;
    const int w    = t >> 6;
    const int g    = lane >> 4;
    const int c16  = lane & 15;
    const int tok0 = blockIdx.x * 64 + w * 16;

    f32x4 acc[8];
    #pragma unroll
    for (int at = 0; at < 8; ++at)
        #pragma unroll
        for (int rr = 0; rr < 4; ++rr) acc[at][rr] = 0.f;

    #pragma unroll 1
    for (int kc = 0; kc < 4; ++kc) {
        const int token = tok0 + c16;
        float av[8];
        ld8<F32>(elptr<F32>((const void*)out, (size_t)token * 128 + kc * 32 + 8 * g), 0, av);
        union { ush s[8]; bf16x8 v; } hU, lU;
        #pragma unroll
        for (int j = 0; j < 8; ++j) splitf(av[j], hU.s[j], lU.s[j]);
        const bf16x8 btH = hU.v;
        const bf16x8 btL = lU.v;

        #pragma unroll
        for (int at = 0; at < 8; ++at) {
            const size_t wrow = (size_t)(at * 16 + c16) * 128 + kc * 32 + 8 * g;
            bf16x8 awH = *(const bf16x8*)&wpH[wrow];
            acc[at] = mfma16(awH, btH, acc[at]);
            if constexpr (F32) {
                bf16x8 awL = *(const bf16x8*)&wpL[wrow];
                acc[at] = mfma16(awH, btL, acc[at]);
                acc[at] = mfma16(awL, btH, acc[at]);
            }
        }
    }

    #pragma unroll
    for (int at = 0; at < 8; ++at) {
        const int c0 = at * 16 + 4 * g;
        float bp[4];
        #pragma unroll
        for (int rr = 0; rr < 4; ++rr) bp[rr] = ldel<F32>(b_proj, c0 + rr);
        const int n = tok0 + c16;
        const size_t ob = (size_t)n * 128 + c0;
        if constexpr (F32) {
            const float4 zv = *(const float4*)((const float*)z + ob);
            float4 o;
            o.x = acc[at][0] + bp[0] + zv.x;
            o.y = acc[at][1] + bp[1] + zv.y;
            o.z = acc[at][2] + bp[2] + zv.z;
            o.w = acc[at][3] + bp[3] + zv.w;
            *(float4*)((float*)out + ob) = o;
        } else {
            const uint2 zu = *(const uint2*)((const ush*)z + ob);
            float v0 = acc[at][0] + bp[0] + bflo(zu.x);
            float v1 = acc[at][1] + bp[1] + bfhi(zu.x);
            float v2 = acc[at][2] + bp[2] + bflo(zu.y);
            float v3 = acc[at][3] + bp[3] + bfhi(zu.y);
            uint2 u;
            u.x = (unsigned int)f2bf(v0) | ((unsigned int)f2bf(v1) << 16);
            u.y = (unsigned int)f2bf(v2) | ((unsigned int)f2bf(v3) << 16);
            *(uint2*)((ush*)out + ob) = u;
        }
    }
}

// ======================================================================
// ============   FALLBACK (ws too small): round-1 kernels   ============
// ======================================================================
template<bool F32>
__global__ __launch_bounds__(256) void attn_mfma(
    const void* __restrict__ z, const void* __restrict__ ln_g, const void* __restrict__ ln_b,
    const void* __restrict__ w_qkv, const void* __restrict__ b_qkv, void* __restrict__ out)
{
    if (sniff_is_f32((const unsigned int*)z) != F32) return;

    __shared__ __align__(16) unsigned char smem[53248];
    ush* znH  = (ush*)smem;
    ush* znL  = (ush*)(smem + 16384);
    ush* wtH  = (ush*)(smem + 32768);
    ush* wtL  = (ush*)(smem + 38912);
    float* biasm = (float*)(smem + 45056);
    ush* kHs  = znH;
    ush* kLs  = znL;
    ush* vtH  = (ush*)(smem + 32768);

    const int t    = threadIdx.x;
    const int lane = t & 63;
    const int w    = t >> 6;
    const int g    = lane >> 4;
    const int c16  = lane & 15;
    const int r    = blockIdx.x >> 2;
    const int h    = blockIdx.x & 3;
    ush* ps = (ush*)(smem + 49152) + (w << 9);

    if (t < 96) {
        int gc = ((t >> 5) << 7) + (h << 5) + (t & 31);
        float b0 = 0.f, b1 = 0.f;
        #pragma unroll 8
        for (int k = 0; k < 128; k += 2) {
            b0 += ldel<F32>(ln_b, k)     * ldel<F32>(w_qkv, k * 384 + gc);
            b1 += ldel<F32>(ln_b, k + 1) * ldel<F32>(w_qkv, (k + 1) * 384 + gc);
        }
        biasm[t] = ldel<F32>(b_qkv, gc) + b0 + b1;
    }

    const void* zrow = elptr<F32>(z, ((size_t)r * 256 + t) << 7);
    float sum = 0.f, sumsq = 0.f;
    #pragma unroll 1
    for (int i = 0; i < 16; ++i) {
        float v[8]; ld8<F32>(zrow, i, v);
        #pragma unroll
        for (int j = 0; j < 8; ++j) { sum += v[j]; sumsq += v[j] * v[j]; }
    }
    const float mu   = sum * (1.f / 128.f);
    const float rsig = 1.0f / sqrtf(sumsq * (1.f / 128.f) - mu * mu + 1e-5f);
    const float nb   = -mu * rsig;

    __syncthreads();

    float bv[6];
    #pragma unroll
    for (int ct = 0; ct < 6; ++ct) bv[ct] = biasm[ct * 16 + c16];

    f32x4 acc[4][6];
    #pragma unroll
    for (int qt = 0; qt < 4; ++qt)
        #pragma unroll
        for (int ct = 0; ct < 6; ++ct)
            #pragma unroll
            for (int rr = 0; rr < 4; ++rr) acc[qt][ct][rr] = 0.f;

    #pragma unroll 1
    for (int kc = 0; kc < 4; ++kc) {
        {
            float vv[8];
            #pragma unroll
            for (int i8 = 0; i8 < 4; ++i8) {
                ld8<F32>(zrow, kc * 4 + i8, vv);
                union { ush s[8]; uint4 v4; } uh, ul;
                #pragma unroll
                for (int j = 0; j < 8; ++j) {
                    float zh = fmaf(vv[j], rsig, nb);
                    splitf(zh, uh.s[j], ul.s[j]);
                }
                int b2 = sw_frag(t, i8);
                *(uint4*)&znH[b2] = uh.v4;
                *(uint4*)&znL[b2] = ul.v4;
            }
        }
        for (int idx = t; idx < 3072; idx += 256) {
            int c  = idx % 96;
            int kl = idx / 96;
            int kk = kc * 32 + kl;
            int gc = ((c >> 5) << 7) + (h << 5) + (c & 31);
            float wv = ldel<F32>(ln_g, kk) * ldel<F32>(w_qkv, kk * 384 + gc);
            ush hh, ll; splitf(wv, hh, ll);
            int o = sw_off(c, kl);
            wtH[o] = hh; wtL[o] = ll;
        }
        __syncthreads();

        bf16x8 bH[6], bL[6];
        #pragma unroll
        for (int ct = 0; ct < 6; ++ct) {
            int brow = ct * 16 + c16;
            bH[ct] = *(const bf16x8*)&wtH[sw_frag(brow, g)];
            bL[ct] = *(const bf16x8*)&wtL[sw_frag(brow, g)];
        }
        #pragma unroll
        for (int qt = 0; qt < 4; ++qt) {
            int arow = (w << 6) + (qt << 4) + c16;
            bf16x8 aHf = *(const bf16x8*)&znH[sw_frag(arow, g)];
            bf16x8 aLf = *(const bf16x8*)&znL[sw_frag(arow, g)];
            #pragma unroll
            for (int ct = 0; ct < 6; ++ct) {
                acc[qt][ct] = mfma16(aHf, bH[ct], acc[qt][ct]);
                acc[qt][ct] = mfma16(aHf, bL[ct], acc[qt][ct]);
                acc[qt][ct] = mfma16(aLf, bH[ct], acc[qt][ct]);
            }
        }
        __syncthreads();
    }

    #pragma unroll
    for (int qt = 0; qt < 4; ++qt)
        #pragma unroll
        for (int ct = 0; ct < 6; ++ct)
            #pragma unroll
            for (int rr = 0; rr < 4; ++rr) acc[qt][ct][rr] += bv[ct];

    #pragma unroll
    for (int qt = 0; qt < 4; ++qt) {
        #pragma unroll
        for (int rr = 0; rr < 4; ++rr) {
            int key = (w << 6) + (qt << 4) + 4 * g + rr;
            ush hh, ll;
            splitf(acc[qt][2][rr], hh, ll);
            kHs[sw_off(key, c16)]      = hh; kLs[sw_off(key, c16)]      = ll;
            splitf(acc[qt][3][rr], hh, ll);
            kHs[sw_off(key, 16 + c16)] = hh; kLs[sw_off(key, 16 + c16)] = ll;
            vtH[vt_off(c16,      key)] = f2bf(acc[qt][4][rr]);
            vtH[vt_off(16 + c16, key)] = f2bf(acc[qt][5][rr]);
        }
    }

    const float SCALE = 0.17677669529663689f;
    bf16x8 qfH[4], qfL[4];
    #pragma unroll
    for (int qt = 0; qt < 4; ++qt) {
        #pragma unroll
        for (int rr = 0; rr < 4; ++rr) {
            int rw = 4 * g + rr;
            ps[sw_off(rw, c16)]      = f2bf(acc[qt][0][rr] * SCALE);
            ps[sw_off(rw, 16 + c16)] = f2bf(acc[qt][1][rr] * SCALE);
        }
        qfH[qt] = *(const bf16x8*)&ps[sw_frag(c16, g)];
        #pragma unroll
        for (int rr = 0; rr < 4; ++rr) {
            int rw = 4 * g + rr;
            float q0 = acc[qt][0][rr] * SCALE;
            float q1 = acc[qt][1][rr] * SCALE;
            ps[sw_off(rw, c16)]      = f2bf(q0 - bf2f(f2bf(q0)));
            ps[sw_off(rw, 16 + c16)] = f2bf(q1 - bf2f(f2bf(q1)));
        }
        qfL[qt] = *(const bf16x8*)&ps[sw_frag(c16, g)];
    }
    __syncthreads();

    float m[16], l[16];
    #pragma unroll
    for (int i = 0; i < 16; ++i) { m[i] = -3.0e38f; l[i] = 0.f; }
    f32x4 O[4][2];
    #pragma unroll
    for (int qt = 0; qt < 4; ++qt)
        #pragma unroll
        for (int dt = 0; dt < 2; ++dt)
            #pragma unroll
            for (int rr = 0; rr < 4; ++rr) O[qt][dt][rr] = 0.f;

    f32x4 zed; zed[0] = 0.f; zed[1] = 0.f; zed[2] = 0.f; zed[3] = 0.f;

    #pragma unroll 1
    for (int kb = 0; kb < 8; ++kb) {
        int key0 = kb * 32;
        bf16x8 kfH[2], kfL[2], vf[2];
        #pragma unroll
        for (int kt = 0; kt < 2; ++kt) {
            int krow = key0 + 16 * kt + c16;
            kfH[kt] = *(const bf16x8*)&kHs[sw_frag(krow, g)];
            kfL[kt] = *(const bf16x8*)&kLs[sw_frag(krow, g)];
        }
        #pragma unroll
        for (int dt = 0; dt < 2; ++dt)
            vf[dt] = *(const bf16x8*)&vtH[vt_off(16 * dt + c16, key0 + 8 * g)];

        #pragma unroll
        for (int qt = 0; qt < 4; ++qt) {
            f32x4 s0 = mfma16(qfH[qt], kfH[0], zed);
            s0 = mfma16(qfH[qt], kfL[0], s0);
            s0 = mfma16(qfL[qt], kfH[0], s0);
            f32x4 s1 = mfma16(qfH[qt], kfH[1], zed);
            s1 = mfma16(qfH[qt], kfL[1], s1);
            s1 = mfma16(qfL[qt], kfH[1], s1);

            #pragma unroll
            for (int rr = 0; rr < 4; ++rr) {
                float mx = fmaxf(s0[rr], s1[rr]);
                mx = fmaxf(mx, __shfl_xor(mx, 1));
                mx = fmaxf(mx, __shfl_xor(mx, 2));
                mx = fmaxf(mx, __shfl_xor(mx, 4));
                mx = fmaxf(mx, __shfl_xor(mx, 8));
                const int idx = qt * 4 + rr;
                float mo = m[idx];
                float mn = fmaxf(mo, mx);
                float al = __expf(fmaxf(mo - mn, -87.f));
                float p0 = __expf(s0[rr] - mn);
                float p1 = __expf(s1[rr] - mn);
                l[idx] = l[idx] * al + p0 + p1;
                m[idx] = mn;
                O[qt][0][rr] *= al;
                O[qt][1][rr] *= al;
                int rw = 4 * g + rr;
                ps[sw_off(rw, c16)]      = f2bf(p0);
                ps[sw_off(rw, 16 + c16)] = f2bf(p1);
            }
            bf16x8 pf = *(const bf16x8*)&ps[sw_frag(c16, g)];
            O[qt][0] = mfma16(pf, vf[0], O[qt][0]);
            O[qt][1] = mfma16(pf, vf[1], O[qt][1]);
        }
    }

    #pragma unroll
    for (int i = 0; i < 16; ++i) {
        float s = l[i];
        s += __shfl_xor(s, 1);
        s += __shfl_xor(s, 2);
        s += __shfl_xor(s, 4);
        s += __shfl_xor(s, 8);
        l[i] = s;
    }

    #pragma unroll
    for (int qt = 0; qt < 4; ++qt) {
        #pragma unroll
        for (int rr = 0; rr < 4; ++rr) {
            float rlv = 1.f / l[qt * 4 + rr];
            int grow = (r << 8) + (w << 6) + (qt << 4) + 4 * g + rr;
            size_t base = ((size_t)grow << 7) + (h << 5);
            if constexpr (F32) {
                float* po = (float*)out + base;
                po[c16]      = O[qt][0][rr] * rlv;
                po[16 + c16] = O[qt][1][rr] * rlv;
            } else {
                ush* po = (ush*)out + base;
                po[c16]      = f2bf(O[qt][0][rr] * rlv);
                po[16 + c16] = f2bf(O[qt][1][rr] * rlv);
            }
        }
    }
}

template<bool F32>
__global__ __launch_bounds__(256) void proj_res(
    const void* __restrict__ z, const void* __restrict__ w_proj, const void* __restrict__ b_proj,
    void* __restrict__ out)
{
    if (sniff_is_f32((const unsigned int*)z) != F32) return;

    __shared__ unsigned int wu[8192];
    __shared__ float aT[128][20];

    const int t = threadIdx.x;
    const size_t row0 = (size_t)blockIdx.x * 16;

    if constexpr (!F32) {
        for (int idx = t; idx < 8192; idx += 256)
            wu[idx] = ((const unsigned int*)w_proj)[idx];
    }

    {
        const int rr = t >> 4;
        const int i8 = t & 15;
        float v[8];
        ld8<F32>(elptr<F32>((const void*)out, (row0 + rr) * 128), i8, v);
        #pragma unroll
        for (int j = 0; j < 8; ++j) aT[(i8 << 3) + j][rr] = v[j];
    }
    __syncthreads();

    const int c = t & 127;
    const int half = t >> 7;
    float acc8[8];
    const float bp = ldel<F32>(b_proj, c);
    #pragma unroll
    for (int rr = 0; rr < 8; ++rr) acc8[rr] = bp;

    #pragma unroll 1
    for (int k = 0; k < 128; ++k) {
        float wk;
        if constexpr (F32) {
            wk = ((const float*)w_proj)[k * 128 + c];
        } else {
            unsigned int u = wu[(k << 6) + (c >> 1)];
            wk = (c & 1) ? bfhi(u) : bflo(u);
        }
        const float4 a0 = *(const float4*)&aT[k][half * 8];
        const float4 a1 = *(const float4*)&aT[k][half * 8 + 4];
        acc8[0] = fmaf(a0.x, wk, acc8[0]);
        acc8[1] = fmaf(a0.y, wk, acc8[1]);
        acc8[2] = fmaf(a0.z, wk, acc8[2]);
        acc8[3] = fmaf(a0.w, wk, acc8[3]);
        acc8[4] = fmaf(a1.x, wk, acc8[4]);
        acc8[5] = fmaf(a1.y, wk, acc8[5]);
        acc8[6] = fmaf(a1.z, wk, acc8[6]);
        acc8[7] = fmaf(a1.w, wk, acc8[7]);
    }
    __syncthreads();
    float* ot = (float*)aT;
    #pragma unroll
    for (int rr = 0; rr < 8; ++rr)
        ot[(half * 8 + rr) * 128 + c] = acc8[rr];
    __syncthreads();

    {
        const int rr = t >> 4;
        const int i8 = t & 15;
        float zv[8], v[8];
        ld8<F32>(elptr<F32>(z, (row0 + rr) * 128), i8, zv);
        const float* po = &ot[rr * 128 + (i8 << 3)];
        #pragma unroll
        for (int j = 0; j < 8; ++j) v[j] = po[j] + zv[j];
        st8<F32>(elptrw<F32>(out, (row0 + rr) * 128), i8, v);
    }
}

extern "C" void kernel_launch(void* const* d_in, const int* in_sizes, int n_in,
                              void* d_out, int out_size, void* d_ws, size_t ws_size,
                              hipStream_t stream) {
    const void* z      = d_in[0];
    const void* ln_g   = d_in[1];
    const void* ln_b   = d_in[2];
    const void* w_qkv  = d_in[3];
    const void* b_qkv  = d_in[4];
    const void* w_proj = d_in[5];
    const void* b_proj = d_in[6];
    void* out = d_out;

    if (ws_size >= WS_NEED && d_ws != nullptr) {
        unsigned char* W = (unsigned char*)d_ws;
        ush*   wqSH  = (ush*)(W + 0);
        ush*   wqSL  = (ush*)(W + 98304);
        ush*   wpH   = (ush*)(W + 196608);
        ush*   wpL   = (ush*)(W + 229376);
        float* biasG = (float*)(W + 262144);
        float* csumG = (float*)(W + 263680);

        prep_w<false><<<96, 256, 0, stream>>>(z, ln_g, ln_b, w_qkv, b_qkv, w_proj, wqSH, wqSL, wpH, wpL, biasG, csumG);
        prep_w<true ><<<96, 256, 0, stream>>>(z, ln_g, ln_b, w_qkv, b_qkv, w_proj, wqSH, wqSL, wpH, wpL, biasG, csumG);
        attn_mfma5<false><<<1024, 512, 0, stream>>>(z, wqSH, wqSL, biasG, csumG, out);
        attn_mfma5<true ><<<1024, 512, 0, stream>>>(z, wqSH, wqSL, biasG, csumG, out);
        proj_mfma2<false><<<1024, 256, 0, stream>>>(z, b_proj, wpH, wpL, out);
        proj_mfma2<true ><<<1024, 256, 0, stream>>>(z, b_proj, wpH, wpL, out);
    } else {
        attn_mfma<false><<<1024, 256, 0, stream>>>(z, ln_g, ln_b, w_qkv, b_qkv, out);
        attn_mfma<true ><<<1024, 256, 0, stream>>>(z, ln_g, ln_b, w_qkv, b_qkv, out);
        proj_res<false><<<4096, 256, 0, stream>>>(z, w_proj, b_proj, out);
        proj_res<true ><<<4096, 256, 0, stream>>>(z, w_proj, b_proj, out);
    }
}

// Round 13
// 231.114 us; speedup vs baseline: 1.3477x; 1.0062x over previous
//
#include <hip/hip_runtime.h>
#include <hip/hip_bf16.h>

// PairwiseAttention: z(1,256,256,128) -> LN -> QKV -> 4-head attn (over 2nd L axis)
// -> proj + residual.  Runtime dtype sniff (fp32 vs bf16).
//
// Round N+12: PROJ REWRITE (by subtraction proj ~110us = largest component).
//   proj_mfma3 : (a) bf16 path loads attn-out RAW as bf16x8 (hi==raw bits,
//                lo==0 -> the ld8+splitf VALU chains were pure waste, same
//                insight as round-9's z staging); (b) kc loop fully unrolled
//                (ILP across the 4 dependent load->MFMA rounds); (c) grid
//                4096 x 64 threads (1 wave, 16 tokens) -> 16 independent
//                waves/CU for the scheduler. In-place safety unchanged:
//                wave reads only its own tokens, all reads precede writes.
//   attn_mfma5 : unchanged (round-12 verified: swapped-S flash, 98us).
//   prep_w     : unchanged.
// Fallback to round-1 attn_mfma + proj_res when ws is too small.

using ush = unsigned short;

__device__ __forceinline__ float bflo(unsigned int u) { return __uint_as_float(u << 16); }
__device__ __forceinline__ float bfhi(unsigned int u) { return __uint_as_float(u & 0xffff0000u); }
__device__ __forceinline__ float bf2f(unsigned short u) { return __uint_as_float(((unsigned int)u) << 16); }
__device__ __forceinline__ unsigned short f2bf(float f) {
    unsigned int i = __float_as_uint(f);
    i += 0x7fffu + ((i >> 16) & 1u);           // round-to-nearest-even
    return (unsigned short)(i >> 16);
}
__device__ __forceinline__ void splitf(float x, unsigned short& h, unsigned short& l) {
    h = f2bf(x);
    l = f2bf(x - bf2f(h));
}

__device__ bool sniff_is_f32(const unsigned int* z) {
    int n = 0;
    for (int i = 0; i < 64; ++i) {
        float a = fabsf(bflo(z[i]));
        n += (int)(a > 1e4f) | (int)(a > 0.f && a < 1e-6f);
    }
    return n > 16;
}

template<bool F32> __device__ __forceinline__ float ldel(const void* p, int i) {
    if constexpr (F32) return ((const float*)p)[i];
    else               return bf2f(((const unsigned short*)p)[i]);
}
template<bool F32> __device__ __forceinline__ void ld8(const void* p, int i8, float* v) {
    if constexpr (F32) {
        const float4* q = (const float4*)p;
        float4 a = q[2 * i8], b = q[2 * i8 + 1];
        v[0]=a.x; v[1]=a.y; v[2]=a.z; v[3]=a.w; v[4]=b.x; v[5]=b.y; v[6]=b.z; v[7]=b.w;
    } else {
        uint4 u = ((const uint4*)p)[i8];
        const unsigned int* pu = (const unsigned int*)&u;
        #pragma unroll
        for (int j = 0; j < 4; ++j) { v[2*j] = bflo(pu[j]); v[2*j+1] = bfhi(pu[j]); }
    }
}
template<bool F32> __device__ __forceinline__ void st8(void* p, int i8, const float* v) {
    if constexpr (F32) {
        float4 a, b;
        a.x=v[0]; a.y=v[1]; a.z=v[2]; a.w=v[3];
        b.x=v[4]; b.y=v[5]; b.z=v[6]; b.w=v[7];
        ((float4*)p)[2 * i8] = a; ((float4*)p)[2 * i8 + 1] = b;
    } else {
        uint4 u; unsigned int* pu = (unsigned int*)&u;
        #pragma unroll
        for (int j = 0; j < 4; ++j)
            pu[j] = (unsigned int)f2bf(v[2*j]) | ((unsigned int)f2bf(v[2*j+1]) << 16);
        ((uint4*)p)[i8] = u;
    }
}
template<bool F32> __device__ __forceinline__ const void* elptr(const void* p, size_t off) {
    if constexpr (F32) return (const void*)((const float*)p + off);
    else               return (const void*)((const unsigned short*)p + off);
}
template<bool F32> __device__ __forceinline__ void* elptrw(void* p, size_t off) {
    if constexpr (F32) return (void*)((float*)p + off);
    else               return (void*)((unsigned short*)p + off);
}

// ---------------- MFMA plumbing ----------------
using bf16x8 = __attribute__((ext_vector_type(8))) short;   // 8 bf16 bits, 4 VGPR
using f32x4  = __attribute__((ext_vector_type(4))) float;

__device__ __forceinline__ f32x4 mfma16(bf16x8 a, bf16x8 b, f32x4 c) {
    return __builtin_amdgcn_mfma_f32_16x16x32_bf16(a, b, c, 0, 0, 0);
}

// [R][32]-bf16 LDS matrices with XOR-granule swizzle (verified round-1):
// sw_frag(row,g)+e == sw_off(row, 8*g+e)  (slot consistency across A and B).
__device__ __forceinline__ int sw_off (int row, int k) {
    return row * 32 + ((((k >> 3) ^ (row >> 1)) & 3) << 3) + (k & 7);
}
__device__ __forceinline__ int sw_frag(int row, int g) {
    return row * 32 + (((g ^ (row >> 1)) & 3) << 3);
}
// Vt: [32 dims][256 keys] bf16, XOR key-granule by (dim&7).
__device__ __forceinline__ int vt_off(int dim, int key) {
    return dim * 256 + (key ^ ((dim & 7) << 3));
}

// ws layout (bytes):
//   wqSH 0       (98304)   swizzled w' hi images: [(h*4+kc)*3072 + sw_off(c,kl)]
//   wqSL 98304   (98304)
//   wpH  196608  (32768)   w_proj^T hi: [c*128+k]
//   wpL  229376  (32768)
//   biasG 262144 (1536)    float[4][96]
//   csumG 263680 (1536)    float[4][96]: sum_k g[k]*W[k][gc]
#define WS_NEED 265216ull

// ---------------- prep_w: weight preprocessing, once (grid 96 x 256) ----------------
template<bool F32>
__global__ __launch_bounds__(256) void prep_w(
    const void* __restrict__ z, const void* __restrict__ ln_g, const void* __restrict__ ln_b,
    const void* __restrict__ w_qkv, const void* __restrict__ b_qkv, const void* __restrict__ w_proj,
    ush* __restrict__ wqSH, ush* __restrict__ wqSL,
    ush* __restrict__ wpH, ush* __restrict__ wpL,
    float* __restrict__ biasG, float* __restrict__ csumG)
{
    if (sniff_is_f32((const unsigned int*)z) != F32) return;
    const int gid = blockIdx.x * 256 + threadIdx.x;
    const int NT  = 96 * 256;

    // swizzled g.*W_qkv images: e = (h*4+kc)*3072 + c*32 + kl
    for (int e = gid; e < 49152; e += NT) {
        int kl = e & 31;
        int c  = (e >> 5) % 96;
        int hk = e / 3072;            // h*4+kc
        int h  = hk >> 2, kc = hk & 3;
        int k  = kc * 32 + kl;
        int gc = ((c >> 5) << 7) + (h << 5) + (c & 31);
        float wv = ldel<F32>(ln_g, k) * ldel<F32>(w_qkv, k * 384 + gc);
        ush hh, ll; splitf(wv, hh, ll);
        int o = hk * 3072 + sw_off(c, kl);
        wqSH[o] = hh; wqSL[o] = ll;
    }
    // w_proj transposed hi/lo: wp[c*128+k] = w_proj[k][c]
    for (int e = gid; e < 16384; e += NT) {
        int c = e >> 7, k = e & 127;
        float v = ldel<F32>(w_proj, k * 128 + c);
        ush hh, ll; splitf(v, hh, ll);
        wpH[e] = hh; wpL[e] = ll;
    }
    // bias[pair] = b_qkv[gc] + sum_k ln_b[k]*W[k][gc]
    // csum[pair] =             sum_k ln_g[k]*W[k][gc]   (wave-parallel dual reduce)
    if (gid < 384 * 64) {
        const int pair = gid >> 6;
        const int lane = gid & 63;
        const int h = pair / 96, c = pair % 96;
        const int gc = ((c >> 5) << 7) + (h << 5) + (c & 31);
        const float w0 = ldel<F32>(w_qkv, lane * 384 + gc);
        const float w1 = ldel<F32>(w_qkv, (lane + 64) * 384 + gc);
        float s  = ldel<F32>(ln_b, lane) * w0 + ldel<F32>(ln_b, lane + 64) * w1;
        float s2 = ldel<F32>(ln_g, lane) * w0 + ldel<F32>(ln_g, lane + 64) * w1;
        #pragma unroll
        for (int d = 1; d < 64; d <<= 1) { s += __shfl_xor(s, d); s2 += __shfl_xor(s2, d); }
        if (lane == 0) { biasG[pair] = ldel<F32>(b_qkv, gc) + s; csumG[pair] = s2; }
    }
}

// ---------------- attn_mfma5: 8-wave folded-LN attn, swapped-S flash (r12 verified) ----------------
// grid = 1024, block = 512 (8 waves; wave w owns query rows w*32..w*32+31).
// Remap v2: xcd=bid&7, jj=bid>>3, r=(xcd<<5)|(jj>>2), h=jj&3 (bijection).
template<bool F32>
__global__ __launch_bounds__(512, 2) void attn_mfma5(
    const void* __restrict__ z, const ush* __restrict__ wqSH, const ush* __restrict__ wqSL,
    const float* __restrict__ biasG, const float* __restrict__ csumG, void* __restrict__ out)
{
    if (sniff_is_f32((const unsigned int*)z) != F32) return;

    // 56 KB: znH 16K | znL 16K | wtH 6K | wtL 6K | (flash: kH|kL|vtH alias) | ps 8x1KB
    __shared__ __align__(16) unsigned char smem[57344];
    ush* znH  = (ush*)smem;
    ush* znL  = (ush*)(smem + 16384);
    ush* wtH  = (ush*)(smem + 32768);
    ush* wtL  = (ush*)(smem + 38912);
    ush* kHs  = znH;
    ush* kLs  = znL;
    ush* vtH  = (ush*)(smem + 32768);

    const int t    = threadIdx.x;
    const int lane = t & 63;
    const int w    = t >> 6;           // wave 0..7
    const int g    = lane >> 4;
    const int c16  = lane & 15;
    const int xcd  = blockIdx.x & 7;
    const int jj   = blockIdx.x >> 3;
    const int r    = (xcd << 5) | (jj >> 2);
    const int h    = jj & 3;
    // 512 ush = 1KB per wave; 8 waves = bytes 49152..57344 (vtH ends at 49152).
    ush* ps = (ush*)(smem + 49152) + (w << 9);

    // staging assignment: this thread stages half of token row srow
    const int rowl  = lane & 31;
    const int shalf = lane >> 5;                  // which 16-col half of the 32-k chunk
    const int srow  = (w << 5) | rowl;
    const void* zsrow = elptr<F32>(z, ((size_t)r * 256 + srow) << 7);

    float bv[6], cs[6];
    #pragma unroll
    for (int ct = 0; ct < 6; ++ct) {
        bv[ct] = biasG[h * 96 + ct * 16 + c16];
        cs[ct] = csumG[h * 96 + ct * 16 + c16];
    }

    f32x4 acc[2][6];
    #pragma unroll
    for (int qt = 0; qt < 2; ++qt)
        #pragma unroll
        for (int ct = 0; ct < 6; ++ct)
            #pragma unroll
            for (int rr = 0; rr < 4; ++rr) acc[qt][ct][rr] = 0.f;

    float sum = 0.f, sumsq = 0.f;

    #pragma unroll 1
    for (int kc = 0; kc < 4; ++kc) {
        if constexpr (!F32) {
            // raw z IS bf16: hi image = raw bits (exact), lo == 0 (skip).
            #pragma unroll
            for (int q8 = 0; q8 < 2; ++q8) {
                const int i8 = (shalf << 1) | q8;
                uint4 u = ((const uint4*)zsrow)[kc * 4 + i8];
                *(uint4*)&znH[sw_frag(srow, i8)] = u;
                const unsigned int* pu = (const unsigned int*)&u;
                #pragma unroll
                for (int j = 0; j < 4; ++j) {
                    float a = bflo(pu[j]), b = bfhi(pu[j]);
                    sum += a + b; sumsq += a * a + b * b;
                }
            }
        } else {
            float vv[8];
            #pragma unroll
            for (int q8 = 0; q8 < 2; ++q8) {
                const int i8 = (shalf << 1) | q8;
                ld8<F32>(zsrow, kc * 4 + i8, vv);
                union { ush s[8]; uint4 v4; } uh, ul;
                #pragma unroll
                for (int j = 0; j < 8; ++j) {
                    splitf(vv[j], uh.s[j], ul.s[j]);
                    sum += vv[j]; sumsq += vv[j] * vv[j];
                }
                int b2 = sw_frag(srow, i8);
                *(uint4*)&znH[b2] = uh.v4;
                *(uint4*)&znL[b2] = ul.v4;
            }
        }
        {   // stage w' chunk: LINEAR copy of prepped swizzled image (round-5 verified)
            const uint4* srcH = (const uint4*)(wqSH + (h * 4 + kc) * 3072);
            const uint4* srcL = (const uint4*)(wqSL + (h * 4 + kc) * 3072);
            #pragma unroll
            for (int i = t; i < 768; i += 512) {
                if (i < 384) ((uint4*)wtH)[i]       = srcH[i];
                else         ((uint4*)wtL)[i - 384] = srcL[i - 384];
            }
        }
        __syncthreads();

        bf16x8 bH[6], bL[6];
        #pragma unroll
        for (int ct = 0; ct < 6; ++ct) {
            int brow = ct * 16 + c16;
            bH[ct] = *(const bf16x8*)&wtH[sw_frag(brow, g)];
            bL[ct] = *(const bf16x8*)&wtL[sw_frag(brow, g)];
        }
        #pragma unroll
        for (int qt = 0; qt < 2; ++qt) {
            int arow = (w << 5) + (qt << 4) + c16;
            bf16x8 aHf = *(const bf16x8*)&znH[sw_frag(arow, g)];
            if constexpr (!F32) {
                #pragma unroll
                for (int ct = 0; ct < 6; ++ct) {
                    acc[qt][ct] = mfma16(aHf, bH[ct], acc[qt][ct]);
                    acc[qt][ct] = mfma16(aHf, bL[ct], acc[qt][ct]);
                }
            } else {
                bf16x8 aLf = *(const bf16x8*)&znL[sw_frag(arow, g)];
                #pragma unroll
                for (int ct = 0; ct < 6; ++ct) {
                    acc[qt][ct] = mfma16(aHf, bH[ct], acc[qt][ct]);
                    acc[qt][ct] = mfma16(aHf, bL[ct], acc[qt][ct]);
                    acc[qt][ct] = mfma16(aLf, bH[ct], acc[qt][ct]);
                }
            }
        }
        __syncthreads();
    }

    // combine half-row stats (partner lane handled the other 16 cols per chunk)
    sum   += __shfl_xor(sum, 32);
    sumsq += __shfl_xor(sumsq, 32);

    const float mu   = sum * (1.f / 128.f);
    const float rsig = 1.0f / sqrtf(sumsq * (1.f / 128.f) - mu * mu + 1e-5f);
    const float nb   = -mu * rsig;

    // wave-local rsig/nb exchange: lane l holds row (w<<5)|(l&31)
    float* pf0 = (float*)ps;
    pf0[lane & 31] = rsig; pf0[64 + (lane & 31)] = nb;
    __asm__ volatile("" ::: "memory");

    // epilogue fold: acc = rsig[row]*acc + nb[row]*csum[col] + bias[col]
    #pragma unroll
    for (int qt = 0; qt < 2; ++qt) {
        #pragma unroll
        for (int rr = 0; rr < 4; ++rr) {
            const int j = (qt << 4) + 4 * g + rr;    // row within wave stripe, 0..31
            const float rs = pf0[j];
            const float nv = pf0[64 + j];
            #pragma unroll
            for (int ct = 0; ct < 6; ++ct)
                acc[qt][ct][rr] = fmaf(rs, acc[qt][ct][rr], fmaf(nv, cs[ct], bv[ct]));
        }
    }
    __asm__ volatile("" ::: "memory");   // ps reused below (wave-synchronous)

    // K/V redistribute: wave w covers keys w*32..w*32+31
    #pragma unroll
    for (int qt = 0; qt < 2; ++qt) {
        #pragma unroll
        for (int rr = 0; rr < 4; ++rr) {
            int key = (w << 5) + (qt << 4) + 4 * g + rr;
            ush hh, ll;
            splitf(acc[qt][2][rr], hh, ll);
            kHs[sw_off(key, c16)]      = hh; kLs[sw_off(key, c16)]      = ll;
            splitf(acc[qt][3][rr], hh, ll);
            kHs[sw_off(key, 16 + c16)] = hh; kLs[sw_off(key, 16 + c16)] = ll;
            vtH[vt_off(c16,      key)] = f2bf(acc[qt][4][rr]);
            vtH[vt_off(16 + c16, key)] = f2bf(acc[qt][5][rr]);
        }
    }

    const float SCALE = 0.17677669529663689f;
    bf16x8 qfH[2], qfL[2];
    #pragma unroll
    for (int qt = 0; qt < 2; ++qt) {
        #pragma unroll
        for (int rr = 0; rr < 4; ++rr) {
            int rw = 4 * g + rr;
            ps[sw_off(rw, c16)]      = f2bf(acc[qt][0][rr] * SCALE);
            ps[sw_off(rw, 16 + c16)] = f2bf(acc[qt][1][rr] * SCALE);
        }
        qfH[qt] = *(const bf16x8*)&ps[sw_frag(c16, g)];
        #pragma unroll
        for (int rr = 0; rr < 4; ++rr) {
            int rw = 4 * g + rr;
            float q0 = acc[qt][0][rr] * SCALE;
            float q1 = acc[qt][1][rr] * SCALE;
            ps[sw_off(rw, c16)]      = f2bf(q0 - bf2f(f2bf(q0)));
            ps[sw_off(rw, 16 + c16)] = f2bf(q1 - bf2f(f2bf(q1)));
        }
        qfL[qt] = *(const bf16x8*)&ps[sw_frag(c16, g)];
    }
    __syncthreads();   // K/V visible to all waves

    // ---- swapped-S flash: S^T = mfma(K,Q) -> [key=4g+rr][query=c16] ----
    float m[2], l[2];
    #pragma unroll
    for (int i = 0; i < 2; ++i) { m[i] = -3.0e38f; l[i] = 0.f; }
    f32x4 O[2][2];                      // O^T frag: [dim=4g+rr (+16dt)][query=c16]
    #pragma unroll
    for (int qt = 0; qt < 2; ++qt)
        #pragma unroll
        for (int dt = 0; dt < 2; ++dt)
            #pragma unroll
            for (int rr = 0; rr < 4; ++rr) O[qt][dt][rr] = 0.f;

    f32x4 zed; zed[0] = 0.f; zed[1] = 0.f; zed[2] = 0.f; zed[3] = 0.f;

    // P-bounce write addresses (row = query c16; cols 4g..4g+3 and 16+4g..16+4g+3)
    const int wr0 = c16 * 32 + (((( (g >> 1)    ) ^ (c16 >> 1)) & 3) << 3) + ((g & 1) << 2);
    const int wr1 = c16 * 32 + (((( (g >> 1) + 2) ^ (c16 >> 1)) & 3) << 3) + ((g & 1) << 2);

    #pragma unroll 1
    for (int kb = 0; kb < 8; ++kb) {
        int key0 = kb * 32;
        bf16x8 kfH[2], kfL[2], vf[2];
        #pragma unroll
        for (int kt = 0; kt < 2; ++kt) {
            int krow = key0 + 16 * kt + c16;
            kfH[kt] = *(const bf16x8*)&kHs[sw_frag(krow, g)];
            kfL[kt] = *(const bf16x8*)&kLs[sw_frag(krow, g)];
        }
        #pragma unroll
        for (int dt = 0; dt < 2; ++dt)
            vf[dt] = *(const bf16x8*)&vtH[vt_off(16 * dt + c16, key0 + 8 * g)];

        #pragma unroll
        for (int qt = 0; qt < 2; ++qt) {
            f32x4 s0 = mfma16(kfH[0], qfH[qt], zed);
            s0 = mfma16(kfH[0], qfL[qt], s0);
            s0 = mfma16(kfL[0], qfH[qt], s0);
            f32x4 s1 = mfma16(kfH[1], qfH[qt], zed);
            s1 = mfma16(kfH[1], qfL[qt], s1);
            s1 = mfma16(kfL[1], qfH[qt], s1);

            // chunk max for this query (c16): in-lane 8-max + 2 shfls across g
            float pmax = fmaxf(fmaxf(fmaxf(s0[0], s0[1]), fmaxf(s0[2], s0[3])),
                               fmaxf(fmaxf(s1[0], s1[1]), fmaxf(s1[2], s1[3])));
            pmax = fmaxf(pmax, __shfl_xor(pmax, 16));
            pmax = fmaxf(pmax, __shfl_xor(pmax, 32));

            const float mo = m[qt];
            const float mn = fmaxf(mo, pmax);
            const float al = __expf(fmaxf(mo - mn, -87.f));   // safe vs -3e38 sentinel
            float p0[4], p1[4], psum = 0.f;
            #pragma unroll
            for (int rr = 0; rr < 4; ++rr) {
                p0[rr] = __expf(s0[rr] - mn);
                p1[rr] = __expf(s1[rr] - mn);
                psum += p0[rr] + p1[rr];
            }
            l[qt] = l[qt] * al + psum;
            m[qt] = mn;
            #pragma unroll
            for (int rr = 0; rr < 4; ++rr) { O[qt][0][rr] *= al; O[qt][1][rr] *= al; }

            // P-bounce: row=query c16, 2 aligned uint2 writes (wave-synchronous)
            uint2 u01, u23;
            u01.x = (unsigned int)f2bf(p0[0]) | ((unsigned int)f2bf(p0[1]) << 16);
            u01.y = (unsigned int)f2bf(p0[2]) | ((unsigned int)f2bf(p0[3]) << 16);
            u23.x = (unsigned int)f2bf(p1[0]) | ((unsigned int)f2bf(p1[1]) << 16);
            u23.y = (unsigned int)f2bf(p1[2]) | ((unsigned int)f2bf(p1[3]) << 16);
            *(uint2*)&ps[wr0] = u01;
            *(uint2*)&ps[wr1] = u23;
            __asm__ volatile("" ::: "memory");
            bf16x8 pfr = *(const bf16x8*)&ps[sw_frag(c16, g)];
            __asm__ volatile("" ::: "memory");

            // PV: O^T = V^T(A) x P(B); vf fragment unchanged
            O[qt][0] = mfma16(vf[0], pfr, O[qt][0]);
            O[qt][1] = mfma16(vf[1], pfr, O[qt][1]);
        }
    }

    // finalize: l partials (each lane covered its 8 keys/chunk) -> sum across g
    #pragma unroll
    for (int qt = 0; qt < 2; ++qt) {
        float s = l[qt];
        s += __shfl_xor(s, 16);
        s += __shfl_xor(s, 32);
        const float rlv = 1.f / s;
        const int token = (r << 8) + (w << 5) + (qt << 4) + c16;
        #pragma unroll
        for (int dt = 0; dt < 2; ++dt) {
            const size_t ob = ((size_t)token << 7) + (h << 5) + (dt << 4) + 4 * g;
            if constexpr (F32) {
                float4 o;
                o.x = O[qt][dt][0] * rlv;
                o.y = O[qt][dt][1] * rlv;
                o.z = O[qt][dt][2] * rlv;
                o.w = O[qt][dt][3] * rlv;
                *(float4*)((float*)out + ob) = o;
            } else {
                uint2 u;
                u.x = (unsigned int)f2bf(O[qt][dt][0] * rlv) | ((unsigned int)f2bf(O[qt][dt][1] * rlv) << 16);
                u.y = (unsigned int)f2bf(O[qt][dt][2] * rlv) | ((unsigned int)f2bf(O[qt][dt][3] * rlv) << 16);
                *(uint2*)((ush*)out + ob) = u;
            }
        }
    }
}

// ---------------- proj_mfma3: out = z + out @ w_proj + b_proj (in-place MFMA) ----------------
// grid 4096 (16 tokens each), block 64 (1 wave). bf16 path: RAW bf16x8 loads of
// attn-out (hi==bits, lo==0 -> no conversion VALU). kc fully unrolled for ILP.
// In-place safe: wave reads only its own 16 tokens; all reads precede writes.
template<bool F32>
__global__ __launch_bounds__(64) void proj_mfma3(
    const void* __restrict__ z, const void* __restrict__ b_proj,
    const ush* __restrict__ wpH, const ush* __restrict__ wpL,
    void* __restrict__ out)
{
    if (sniff_is_f32((const unsigned int*)z) != F32) return;

    const int lane = threadIdx.x & 63;
    const int g    = lane >> 4;
    const int c16  = lane & 15;
    const int tok0 = blockIdx.x * 16;
    const int token = tok0 + c16;

    f32x4 acc[8];
    #pragma unroll
    for (int at = 0; at < 8; ++at)
        #pragma unroll
        for (int rr = 0; rr < 4; ++rr) acc[at][rr] = 0.f;

    #pragma unroll
    for (int kc = 0; kc < 4; ++kc) {
        bf16x8 btH, btL;
        if constexpr (!F32) {
            // attn-out is bf16 in `out`: raw bits ARE the hi operand; lo == 0.
            btH = *(const bf16x8*)((const ush*)out + (size_t)token * 128 + kc * 32 + 8 * g);
        } else {
            float av[8];
            ld8<F32>(elptr<F32>((const void*)out, (size_t)token * 128 + kc * 32 + 8 * g), 0, av);
            union { ush s[8]; bf16x8 v; } hU, lU;
            #pragma unroll
            for (int j = 0; j < 8; ++j) splitf(av[j], hU.s[j], lU.s[j]);
            btH = hU.v; btL = lU.v;
        }

        #pragma unroll
        for (int at = 0; at < 8; ++at) {
            const size_t wrow = (size_t)(at * 16 + c16) * 128 + kc * 32 + 8 * g;
            bf16x8 awH = *(const bf16x8*)&wpH[wrow];
            acc[at] = mfma16(awH, btH, acc[at]);
            if constexpr (F32) {
                bf16x8 awL = *(const bf16x8*)&wpL[wrow];
                acc[at] = mfma16(awH, btL, acc[at]);
                acc[at] = mfma16(awL, btH, acc[at]);
            }
        }
    }

    #pragma unroll
    for (int at = 0; at < 8; ++at) {
        const int c0 = at * 16 + 4 * g;
        float bp[4];
        #pragma unroll
        for (int rr = 0; rr < 4; ++rr) bp[rr] = ldel<F32>(b_proj, c0 + rr);
        const size_t ob = (size_t)token * 128 + c0;
        if constexpr (F32) {
            const float4 zv = *(const float4*)((const float*)z + ob);
            float4 o;
            o.x = acc[at][0] + bp[0] + zv.x;
            o.y = acc[at][1] + bp[1] + zv.y;
            o.z = acc[at][2] + bp[2] + zv.z;
            o.w = acc[at][3] + bp[3] + zv.w;
            *(float4*)((float*)out + ob) = o;
        } else {
            const uint2 zu = *(const uint2*)((const ush*)z + ob);
            float v0 = acc[at][0] + bp[0] + bflo(zu.x);
            float v1 = acc[at][1] + bp[1] + bfhi(zu.x);
            float v2 = acc[at][2] + bp[2] + bflo(zu.y);
            float v3 = acc[at][3] + bp[3] + bfhi(zu.y);
            uint2 u;
            u.x = (unsigned int)f2bf(v0) | ((unsigned int)f2bf(v1) << 16);
            u.y = (unsigned int)f2bf(v2) | ((unsigned int)f2bf(v3) << 16);
            *(uint2*)((ush*)out + ob) = u;
        }
    }
}

// ======================================================================
// ============   FALLBACK (ws too small): round-1 kernels   ============
// ======================================================================
template<bool F32>
__global__ __launch_bounds__(256) void attn_mfma(
    const void* __restrict__ z, const void* __restrict__ ln_g, const void* __restrict__ ln_b,
    const void* __restrict__ w_qkv, const void* __restrict__ b_qkv, void* __restrict__ out)
{
    if (sniff_is_f32((const unsigned int*)z) != F32) return;

    __shared__ __align__(16) unsigned char smem[53248];
    ush* znH  = (ush*)smem;
    ush* znL  = (ush*)(smem + 16384);
    ush* wtH  = (ush*)(smem + 32768);
    ush* wtL  = (ush*)(smem + 38912);
    float* biasm = (float*)(smem + 45056);
    ush* kHs  = znH;
    ush* kLs  = znL;
    ush* vtH  = (ush*)(smem + 32768);

    const int t    = threadIdx.x;
    const int lane = t & 63;
    const int w    = t >> 6;
    const int g    = lane >> 4;
    const int c16  = lane & 15;
    const int r    = blockIdx.x >> 2;
    const int h    = blockIdx.x & 3;
    ush* ps = (ush*)(smem + 49152) + (w << 9);

    if (t < 96) {
        int gc = ((t >> 5) << 7) + (h << 5) + (t & 31);
        float b0 = 0.f, b1 = 0.f;
        #pragma unroll 8
        for (int k = 0; k < 128; k += 2) {
            b0 += ldel<F32>(ln_b, k)     * ldel<F32>(w_qkv, k * 384 + gc);
            b1 += ldel<F32>(ln_b, k + 1) * ldel<F32>(w_qkv, (k + 1) * 384 + gc);
        }
        biasm[t] = ldel<F32>(b_qkv, gc) + b0 + b1;
    }

    const void* zrow = elptr<F32>(z, ((size_t)r * 256 + t) << 7);
    float sum = 0.f, sumsq = 0.f;
    #pragma unroll 1
    for (int i = 0; i < 16; ++i) {
        float v[8]; ld8<F32>(zrow, i, v);
        #pragma unroll
        for (int j = 0; j < 8; ++j) { sum += v[j]; sumsq += v[j] * v[j]; }
    }
    const float mu   = sum * (1.f / 128.f);
    const float rsig = 1.0f / sqrtf(sumsq * (1.f / 128.f) - mu * mu + 1e-5f);
    const float nb   = -mu * rsig;

    __syncthreads();

    float bv[6];
    #pragma unroll
    for (int ct = 0; ct < 6; ++ct) bv[ct] = biasm[ct * 16 + c16];

    f32x4 acc[4][6];
    #pragma unroll
    for (int qt = 0; qt < 4; ++qt)
        #pragma unroll
        for (int ct = 0; ct < 6; ++ct)
            #pragma unroll
            for (int rr = 0; rr < 4; ++rr) acc[qt][ct][rr] = 0.f;

    #pragma unroll 1
    for (int kc = 0; kc < 4; ++kc) {
        {
            float vv[8];
            #pragma unroll
            for (int i8 = 0; i8 < 4; ++i8) {
                ld8<F32>(zrow, kc * 4 + i8, vv);
                union { ush s[8]; uint4 v4; } uh, ul;
                #pragma unroll
                for (int j = 0; j < 8; ++j) {
                    float zh = fmaf(vv[j], rsig, nb);
                    splitf(zh, uh.s[j], ul.s[j]);
                }
                int b2 = sw_frag(t, i8);
                *(uint4*)&znH[b2] = uh.v4;
                *(uint4*)&znL[b2] = ul.v4;
            }
        }
        for (int idx = t; idx < 3072; idx += 256) {
            int c  = idx % 96;
            int kl = idx / 96;
            int kk = kc * 32 + kl;
            int gc = ((c >> 5) << 7) + (h << 5) + (c & 31);
            float wv = ldel<F32>(ln_g, kk) * ldel<F32>(w_qkv, kk * 384 + gc);
            ush hh, ll; splitf(wv, hh, ll);
            int o = sw_off(c, kl);
            wtH[o] = hh; wtL[o] = ll;
        }
        __syncthreads();

        bf16x8 bH[6], bL[6];
        #pragma unroll
        for (int ct = 0; ct < 6; ++ct) {
            int brow = ct * 16 + c16;
            bH[ct] = *(const bf16x8*)&wtH[sw_frag(brow, g)];
            bL[ct] = *(const bf16x8*)&wtL[sw_frag(brow, g)];
        }
        #pragma unroll
        for (int qt = 0; qt < 4; ++qt) {
            int arow = (w << 6) + (qt << 4) + c16;
            bf16x8 aHf = *(const bf16x8*)&znH[sw_frag(arow, g)];
            bf16x8 aLf = *(const bf16x8*)&znL[sw_frag(arow, g)];
            #pragma unroll
            for (int ct = 0; ct < 6; ++ct) {
                acc[qt][ct] = mfma16(aHf, bH[ct], acc[qt][ct]);
                acc[qt][ct] = mfma16(aHf, bL[ct], acc[qt][ct]);
                acc[qt][ct] = mfma16(aLf, bH[ct], acc[qt][ct]);
            }
        }
        __syncthreads();
    }

    #pragma unroll
    for (int qt = 0; qt < 4; ++qt)
        #pragma unroll
        for (int ct = 0; ct < 6; ++ct)
            #pragma unroll
            for (int rr = 0; rr < 4; ++rr) acc[qt][ct][rr] += bv[ct];

    #pragma unroll
    for (int qt = 0; qt < 4; ++qt) {
        #pragma unroll
        for (int rr = 0; rr < 4; ++rr) {
            int key = (w << 6) + (qt << 4) + 4 * g + rr;
            ush hh, ll;
            splitf(acc[qt][2][rr], hh, ll);
            kHs[sw_off(key, c16)]      = hh; kLs[sw_off(key, c16)]      = ll;
            splitf(acc[qt][3][rr], hh, ll);
            kHs[sw_off(key, 16 + c16)] = hh; kLs[sw_off(key, 16 + c16)] = ll;
            vtH[vt_off(c16,      key)] = f2bf(acc[qt][4][rr]);
            vtH[vt_off(16 + c16, key)] = f2bf(acc[qt][5][rr]);
        }
    }

    const float SCALE = 0.17677669529663689f;
    bf16x8 qfH[4], qfL[4];
    #pragma unroll
    for (int qt = 0; qt < 4; ++qt) {
        #pragma unroll
        for (int rr = 0; rr < 4; ++rr) {
            int rw = 4 * g + rr;
            ps[sw_off(rw, c16)]      = f2bf(acc[qt][0][rr] * SCALE);
            ps[sw_off(rw, 16 + c16)] = f2bf(acc[qt][1][rr] * SCALE);
        }
        qfH[qt] = *(const bf16x8*)&ps[sw_frag(c16, g)];
        #pragma unroll
        for (int rr = 0; rr < 4; ++rr) {
            int rw = 4 * g + rr;
            float q0 = acc[qt][0][rr] * SCALE;
            float q1 = acc[qt][1][rr] * SCALE;
            ps[sw_off(rw, c16)]      = f2bf(q0 - bf2f(f2bf(q0)));
            ps[sw_off(rw, 16 + c16)] = f2bf(q1 - bf2f(f2bf(q1)));
        }
        qfL[qt] = *(const bf16x8*)&ps[sw_frag(c16, g)];
    }
    __syncthreads();

    float m[16], l[16];
    #pragma unroll
    for (int i = 0; i < 16; ++i) { m[i] = -3.0e38f; l[i] = 0.f; }
    f32x4 O[4][2];
    #pragma unroll
    for (int qt = 0; qt < 4; ++qt)
        #pragma unroll
        for (int dt = 0; dt < 2; ++dt)
            #pragma unroll
            for (int rr = 0; rr < 4; ++rr) O[qt][dt][rr] = 0.f;

    f32x4 zed; zed[0] = 0.f; zed[1] = 0.f; zed[2] = 0.f; zed[3] = 0.f;

    #pragma unroll 1
    for (int kb = 0; kb < 8; ++kb) {
        int key0 = kb * 32;
        bf16x8 kfH[2], kfL[2], vf[2];
        #pragma unroll
        for (int kt = 0; kt < 2; ++kt) {
            int krow = key0 + 16 * kt + c16;
            kfH[kt] = *(const bf16x8*)&kHs[sw_frag(krow, g)];
            kfL[kt] = *(const bf16x8*)&kLs[sw_frag(krow, g)];
        }
        #pragma unroll
        for (int dt = 0; dt < 2; ++dt)
            vf[dt] = *(const bf16x8*)&vtH[vt_off(16 * dt + c16, key0 + 8 * g)];

        #pragma unroll
        for (int qt = 0; qt < 4; ++qt) {
            f32x4 s0 = mfma16(qfH[qt], kfH[0], zed);
            s0 = mfma16(qfH[qt], kfL[0], s0);
            s0 = mfma16(qfL[qt], kfH[0], s0);
            f32x4 s1 = mfma16(qfH[qt], kfH[1], zed);
            s1 = mfma16(qfH[qt], kfL[1], s1);
            s1 = mfma16(qfL[qt], kfH[1], s1);

            #pragma unroll
            for (int rr = 0; rr < 4; ++rr) {
                float mx = fmaxf(s0[rr], s1[rr]);
                mx = fmaxf(mx, __shfl_xor(mx, 1));
                mx = fmaxf(mx, __shfl_xor(mx, 2));
                mx = fmaxf(mx, __shfl_xor(mx, 4));
                mx = fmaxf(mx, __shfl_xor(mx, 8));
                const int idx = qt * 4 + rr;
                float mo = m[idx];
                float mn = fmaxf(mo, mx);
                float al = __expf(fmaxf(mo - mn, -87.f));
                float p0 = __expf(s0[rr] - mn);
                float p1 = __expf(s1[rr] - mn);
                l[idx] = l[idx] * al + p0 + p1;
                m[idx] = mn;
                O[qt][0][rr] *= al;
                O[qt][1][rr] *= al;
                int rw = 4 * g + rr;
                ps[sw_off(rw, c16)]      = f2bf(p0);
                ps[sw_off(rw, 16 + c16)] = f2bf(p1);
            }
            bf16x8 pf = *(const bf16x8*)&ps[sw_frag(c16, g)];
            O[qt][0] = mfma16(pf, vf[0], O[qt][0]);
            O[qt][1] = mfma16(pf, vf[1], O[qt][1]);
        }
    }

    #pragma unroll
    for (int i = 0; i < 16; ++i) {
        float s = l[i];
        s += __shfl_xor(s, 1);
        s += __shfl_xor(s, 2);
        s += __shfl_xor(s, 4);
        s += __shfl_xor(s, 8);
        l[i] = s;
    }

    #pragma unroll
    for (int qt = 0; qt < 4; ++qt) {
        #pragma unroll
        for (int rr = 0; rr < 4; ++rr) {
            float rlv = 1.f / l[qt * 4 + rr];
            int grow = (r << 8) + (w << 6) + (qt << 4) + 4 * g + rr;
            size_t base = ((size_t)grow << 7) + (h << 5);
            if constexpr (F32) {
                float* po = (float*)out + base;
                po[c16]      = O[qt][0][rr] * rlv;
                po[16 + c16] = O[qt][1][rr] * rlv;
            } else {
                ush* po = (ush*)out + base;
                po[c16]      = f2bf(O[qt][0][rr] * rlv);
                po[16 + c16] = f2bf(O[qt][1][rr] * rlv);
            }
        }
    }
}

template<bool F32>
__global__ __launch_bounds__(256) void proj_res(
    const void* __restrict__ z, const void* __restrict__ w_proj, const void* __restrict__ b_proj,
    void* __restrict__ out)
{
    if (sniff_is_f32((const unsigned int*)z) != F32) return;

    __shared__ unsigned int wu[8192];
    __shared__ float aT[128][20];

    const int t = threadIdx.x;
    const size_t row0 = (size_t)blockIdx.x * 16;

    if constexpr (!F32) {
        for (int idx = t; idx < 8192; idx += 256)
            wu[idx] = ((const unsigned int*)w_proj)[idx];
    }

    {
        const int rr = t >> 4;
        const int i8 = t & 15;
        float v[8];
        ld8<F32>(elptr<F32>((const void*)out, (row0 + rr) * 128), i8, v);
        #pragma unroll
        for (int j = 0; j < 8; ++j) aT[(i8 << 3) + j][rr] = v[j];
    }
    __syncthreads();

    const int c = t & 127;
    const int half = t >> 7;
    float acc8[8];
    const float bp = ldel<F32>(b_proj, c);
    #pragma unroll
    for (int rr = 0; rr < 8; ++rr) acc8[rr] = bp;

    #pragma unroll 1
    for (int k = 0; k < 128; ++k) {
        float wk;
        if constexpr (F32) {
            wk = ((const float*)w_proj)[k * 128 + c];
        } else {
            unsigned int u = wu[(k << 6) + (c >> 1)];
            wk = (c & 1) ? bfhi(u) : bflo(u);
        }
        const float4 a0 = *(const float4*)&aT[k][half * 8];
        const float4 a1 = *(const float4*)&aT[k][half * 8 + 4];
        acc8[0] = fmaf(a0.x, wk, acc8[0]);
        acc8[1] = fmaf(a0.y, wk, acc8[1]);
        acc8[2] = fmaf(a0.z, wk, acc8[2]);
        acc8[3] = fmaf(a0.w, wk, acc8[3]);
        acc8[4] = fmaf(a1.x, wk, acc8[4]);
        acc8[5] = fmaf(a1.y, wk, acc8[5]);
        acc8[6] = fmaf(a1.z, wk, acc8[6]);
        acc8[7] = fmaf(a1.w, wk, acc8[7]);
    }
    __syncthreads();
    float* ot = (float*)aT;
    #pragma unroll
    for (int rr = 0; rr < 8; ++rr)
        ot[(half * 8 + rr) * 128 + c] = acc8[rr];
    __syncthreads();

    {
        const int rr = t >> 4;
        const int i8 = t & 15;
        float zv[8], v[8];
        ld8<F32>(elptr<F32>(z, (row0 + rr) * 128), i8, zv);
        const float* po = &ot[rr * 128 + (i8 << 3)];
        #pragma unroll
        for (int j = 0; j < 8; ++j) v[j] = po[j] + zv[j];
        st8<F32>(elptrw<F32>(out, (row0 + rr) * 128), i8, v);
    }
}

extern "C" void kernel_launch(void* const* d_in, const int* in_sizes, int n_in,
                              void* d_out, int out_size, void* d_ws, size_t ws_size,
                              hipStream_t stream) {
    const void* z      = d_in[0];
    const void* ln_g   = d_in[1];
    const void* ln_b   = d_in[2];
    const void* w_qkv  = d_in[3];
    const void* b_qkv  = d_in[4];
    const void* w_proj = d_in[5];
    const void* b_proj = d_in[6];
    void* out = d_out;

    if (ws_size >= WS_NEED && d_ws != nullptr) {
        unsigned char* W = (unsigned char*)d_ws;
        ush*   wqSH  = (ush*)(W + 0);
        ush*   wqSL  = (ush*)(W + 98304);
        ush*   wpH   = (ush*)(W + 196608);
        ush*   wpL   = (ush*)(W + 229376);
        float* biasG = (float*)(W + 262144);
        float* csumG = (float*)(W + 263680);

        prep_w<false><<<96, 256, 0, stream>>>(z, ln_g, ln_b, w_qkv, b_qkv, w_proj, wqSH, wqSL, wpH, wpL, biasG, csumG);
        prep_w<true ><<<96, 256, 0, stream>>>(z, ln_g, ln_b, w_qkv, b_qkv, w_proj, wqSH, wqSL, wpH, wpL, biasG, csumG);
        attn_mfma5<false><<<1024, 512, 0, stream>>>(z, wqSH, wqSL, biasG, csumG, out);
        attn_mfma5<true ><<<1024, 512, 0, stream>>>(z, wqSH, wqSL, biasG, csumG, out);
        proj_mfma3<false><<<4096, 64, 0, stream>>>(z, b_proj, wpH, wpL, out);
        proj_mfma3<true ><<<4096, 64, 0, stream>>>(z, b_proj, wpH, wpL, out);
    } else {
        attn_mfma<false><<<1024, 256, 0, stream>>>(z, ln_g, ln_b, w_qkv, b_qkv, out);
        attn_mfma<true ><<<1024, 256, 0, stream>>>(z, ln_g, ln_b, w_qkv, b_qkv, out);
        proj_res<false><<<4096, 256, 0, stream>>>(z, w_proj, b_proj, out);
        proj_res<true ><<<4096, 256, 0, stream>>>(z, w_proj, b_proj, out);
    }
}